// Round 11
// baseline (389.296 us; speedup 1.0000x reference)
//
#include <hip/hip_runtime.h>
#include <hip/hip_bf16.h>

#define N_NODES 100000
#define N_EDGES 1600000
#define N_ESL   1700000   // edges + self loops
#define VOCAB   1000
#define D_IN    64
#define D_H     128
#define NEG_SLOPE 0.2f

// dst-bucket binning
#define BSH   7
#define NB    782          // ceil(100000/128)
#define CAP   3072         // per-bucket capacity (mean 2174, sigma ~47)
#define CHUNK 16384

// canonical fp32 weight-table offsets (elements)
#define CO_EMB   0
#define CO_W1    64000
#define CO_AS1   72192
#define CO_AD1   72320
#define CO_B1    72448
#define CO_W2    72576
#define CO_AS2   88960
#define CO_AD2   89088
#define CO_B2    89216
#define CO_WFC   89344
#define CO_BFC   89600
#define CO_TOTAL 89601

__device__ __forceinline__ float us2f(unsigned short h){ union{unsigned v; float f;} c; c.v = ((unsigned)h)<<16; return c.f; }
__device__ __forceinline__ float gelu_f(float v){ return 0.5f*v*(1.0f + erff(v*0.7071067811865475f)); }
__device__ __forceinline__ float4 ldf4(const float* p){ return *reinterpret_cast<const float4*>(p); }
__device__ __forceinline__ void stf4(float* p, float4 v){ *reinterpret_cast<float4*>(p) = v; }

__device__ __forceinline__ float wred_sum(float v){
  #pragma unroll
  for (int m=32;m;m>>=1) v += __shfl_xor(v,m,64);
  return v;
}

// Detect whether float inputs are bf16-packed (flag=1) or fp32 (flag=0).
__global__ __launch_bounds__(64) void k_detect(const unsigned* __restrict__ w, int* __restrict__ flag){
  int t = threadIdx.x;
  float cnt = 0.f;
  #pragma unroll
  for (int i=0;i<2;++i){
    unsigned v = w[t + 64*i];
    unsigned e = (v >> 7) & 0xFFu;
    cnt += (e >= 110u && e <= 126u) ? 1.f : 0.f;
  }
  cnt = wred_sum(cnt);
  if (t==0) *flag = (cnt >= 64.f) ? 1 : 0;
}

// Blocks 0..350: canonicalize the 11 float inputs into the fp32 table cw.
// Block 351: prevec -- va2 = W2 @ a_src2 ; vd2 = W2 @ a_dst2 (reads RAW inputs).
// Arg mapping: p0=emb p1=W1 p2=as1 p3=ad1 p4=b1 p5=W2 p6=as2 p7=ad2 p8=b2 p9=Wfc p10=bfc.
__global__ __launch_bounds__(256) void k_setup(const void* p0, const void* p1, const void* p2, const void* p3,
    const void* p4, const void* p5, const void* p6, const void* p7, const void* p8,
    const void* p9, const void* p10, const int* __restrict__ flag, float* __restrict__ c,
    float* __restrict__ va2, float* __restrict__ vd2){
  int b = blockIdx.x;
  if (b == 351){
    int t = threadIdx.x;
    int r = t & 127;
    int f = *flag;
    const float* w2f = (const float*)p5;                 // p5 = W2  (FIXED: was p4=b1)
    const unsigned short* w2h = (const unsigned short*)p5;
    const float* af = (const float*)((t < 128) ? p6 : p7);              // as2 / ad2
    const unsigned short* ah = (const unsigned short*)((t < 128) ? p6 : p7);
    float s = 0.f;
    for (int j=0;j<D_H;++j){
      float wv = f ? us2f(w2h[r*D_H+j]) : w2f[r*D_H+j];
      float av = f ? us2f(ah[j]) : af[j];
      s = fmaf(wv, av, s);
    }
    if (t < 128) va2[r] = s; else vd2[r] = s;
    return;
  }
  int i = b*256 + threadIdx.x;
  if (i >= CO_TOTAL) return;
  const void* src; int off;
  if      (i < CO_W1 ){ src=p0;  off=i;          }
  else if (i < CO_AS1){ src=p1;  off=i-CO_W1;    }
  else if (i < CO_AD1){ src=p2;  off=i-CO_AS1;   }
  else if (i < CO_B1 ){ src=p3;  off=i-CO_AD1;   }
  else if (i < CO_W2 ){ src=p4;  off=i-CO_B1;    }
  else if (i < CO_AS2){ src=p5;  off=i-CO_W2;    }
  else if (i < CO_AD2){ src=p6;  off=i-CO_AS2;   }
  else if (i < CO_B2 ){ src=p7;  off=i-CO_AD2;   }
  else if (i < CO_WFC){ src=p8;  off=i-CO_B2;    }
  else if (i < CO_BFC){ src=p9;  off=i-CO_WFC;   }
  else               { src=p10; off=i-CO_BFC;   }
  float v = (*flag) ? us2f(((const unsigned short*)src)[off]) : ((const float*)src)[off];
  c[i] = v;
}

// table1[v][:] = emb[v] @ W1 ; as1[v]/ad1[v] = attention dots
__global__ __launch_bounds__(64) void k_table1(const float* __restrict__ cw,
    float* __restrict__ table1, float* __restrict__ as1, float* __restrict__ ad1){
  const float* emb = cw + CO_EMB;
  const float* W1  = cw + CO_W1;
  int v = blockIdx.x; int t = threadIdx.x;
  __shared__ float er[D_IN];
  er[t] = emb[v*D_IN + t];
  __syncthreads();
  int d0 = t, d1 = t + 64;
  float a0 = 0.f, a1 = 0.f;
  for (int k=0;k<D_IN;++k){
    float e = er[k];
    a0 = fmaf(e, W1[k*D_H+d0], a0);
    a1 = fmaf(e, W1[k*D_H+d1], a1);
  }
  table1[v*D_H+d0] = a0; table1[v*D_H+d1] = a1;
  float ps = a0*cw[CO_AS1+d0] + a1*cw[CO_AS1+d1];
  float pd = a0*cw[CO_AD1+d0] + a1*cw[CO_AD1+d1];
  ps = wred_sum(ps); pd = wred_sum(pd);
  if (t==0){ as1[v]=ps; ad1[v]=pd; }
}

__global__ void k_nodelog(const int* __restrict__ x, const float* __restrict__ as1,
    const float* __restrict__ ad1, float* __restrict__ sA1, float* __restrict__ dA1){
  int i = blockIdx.x*blockDim.x + threadIdx.x;
  if (i < N_NODES){ int xs = x[i]; sA1[i] = as1[xs]; dA1[i] = ad1[xs]; }
}

// ---- bucketed CSR build ----
// N_EDGES and CHUNK are multiples of 4, so every aligned int4 group is
// entirely real-edge or entirely self-loop.
__global__ __launch_bounds__(256) void k_bin(const int* __restrict__ src,
    const int* __restrict__ dst, int* __restrict__ gcur, unsigned* __restrict__ ebuf){
  __shared__ int hist[NB];
  __shared__ int cur[NB];
  int tid = threadIdx.x;
  int base0 = blockIdx.x * CHUNK;
  int n = N_ESL - base0; if (n > CHUNK) n = CHUNK;
  for (int i=tid; i<NB; i+=256) hist[i] = 0;
  __syncthreads();
  for (int k = tid*4; k < n; k += 1024){
    int e = base0 + k;
    int4 d4;
    if (e + 4 <= N_EDGES) d4 = *reinterpret_cast<const int4*>(dst + e);
    else d4 = make_int4(e-N_EDGES, e+1-N_EDGES, e+2-N_EDGES, e+3-N_EDGES);
    atomicAdd(&hist[d4.x>>BSH], 1);
    atomicAdd(&hist[d4.y>>BSH], 1);
    atomicAdd(&hist[d4.z>>BSH], 1);
    atomicAdd(&hist[d4.w>>BSH], 1);
  }
  __syncthreads();
  for (int b=tid; b<NB; b+=256){
    int c = hist[b];
    cur[b] = c ? atomicAdd(&gcur[b], c) : 0;
  }
  __syncthreads();
  for (int k = tid*4; k < n; k += 1024){
    int e = base0 + k;
    int4 d4, s4;
    if (e + 4 <= N_EDGES){
      d4 = *reinterpret_cast<const int4*>(dst + e);
      s4 = *reinterpret_cast<const int4*>(src + e);
    } else {
      d4 = make_int4(e-N_EDGES, e+1-N_EDGES, e+2-N_EDGES, e+3-N_EDGES);
      s4 = d4;
    }
    int p0 = atomicAdd(&cur[d4.x>>BSH], 1);
    if (p0 < CAP) ebuf[(size_t)(d4.x>>BSH)*CAP + p0] = (unsigned)(((d4.x & 127) << 17) | s4.x);
    int p1 = atomicAdd(&cur[d4.y>>BSH], 1);
    if (p1 < CAP) ebuf[(size_t)(d4.y>>BSH)*CAP + p1] = (unsigned)(((d4.y & 127) << 17) | s4.y);
    int p2 = atomicAdd(&cur[d4.z>>BSH], 1);
    if (p2 < CAP) ebuf[(size_t)(d4.z>>BSH)*CAP + p2] = (unsigned)(((d4.z & 127) << 17) | s4.z);
    int p3 = atomicAdd(&cur[d4.w>>BSH], 1);
    if (p3 < CAP) ebuf[(size_t)(d4.w>>BSH)*CAP + p3] = (unsigned)(((d4.w & 127) << 17) | s4.w);
  }
}

__global__ __launch_bounds__(1024) void k_bscan(const int* __restrict__ gcur, int* __restrict__ csrbase){
  int t = threadIdx.x, lane = t & 63, wid = t >> 6;
  int c = (t < NB) ? gcur[t] : 0;
  if (c > CAP) c = CAP;
  int v = c;
  #pragma unroll
  for (int m=1;m<64;m<<=1){ int u = __shfl_up(v,m,64); if (lane>=m) v += u; }
  __shared__ int wsum[16], woff[16];
  if (lane==63) wsum[wid] = v;
  __syncthreads();
  if (t==0){ int run=0; for (int w=0;w<16;++w){ woff[w]=run; run+=wsum[w]; } }
  __syncthreads();
  v += woff[wid];
  if (t < NB) csrbase[t] = v - c;
}

__global__ __launch_bounds__(256) void k_group(const unsigned* __restrict__ ebuf,
    const int* __restrict__ gcur, const int* __restrict__ csrbase,
    int* __restrict__ csr, int* __restrict__ rowoff, int* __restrict__ rowcnt){
  __shared__ unsigned stage[CAP];
  __shared__ int hist[128], cur[128];
  __shared__ int wtot;
  int b = blockIdx.x, tid = threadIdx.x;
  int n = gcur[b]; if (n > CAP) n = CAP;
  int nodeBase = b << BSH;
  int cbase = csrbase[b];
  if (tid < 128) hist[tid] = 0;
  __syncthreads();
  int nv = n & ~3;
  for (int k = tid*4; k < nv; k += 1024){
    uint4 q = *reinterpret_cast<const uint4*>(ebuf + (size_t)b*CAP + k);
    stage[k]   = q.x; atomicAdd(&hist[q.x >> 17], 1);
    stage[k+1] = q.y; atomicAdd(&hist[q.y >> 17], 1);
    stage[k+2] = q.z; atomicAdd(&hist[q.z >> 17], 1);
    stage[k+3] = q.w; atomicAdd(&hist[q.w >> 17], 1);
  }
  for (int k = nv + tid; k < n; k += 256){
    unsigned p = ebuf[(size_t)b*CAP + k];
    stage[k] = p;
    atomicAdd(&hist[p >> 17], 1);
  }
  __syncthreads();
  // parallel exclusive scan of hist[0..127] (two waves + carry)
  int v128 = 0;
  if (tid < 128){
    int lane = tid & 63;
    v128 = hist[tid];
    #pragma unroll
    for (int m=1;m<64;m<<=1){ int u = __shfl_up(v128,m,64); if (lane>=m) v128 += u; }
    if (tid == 63) wtot = v128;
  }
  __syncthreads();
  if (tid < 128){
    int incl = v128 + ((tid >= 64) ? wtot : 0);
    int excl = incl - hist[tid];
    int d = nodeBase + tid;
    if (d < N_NODES){ rowoff[d] = cbase + excl; rowcnt[d] = hist[tid]; }
    cur[tid] = excl;
  }
  __syncthreads();
  for (int k=tid; k<n; k+=256){
    unsigned p = stage[k];
    int pos = atomicAdd(&cur[p >> 17], 1);
    csr[cbase + pos] = (int)(p & 0x1FFFFu);
  }
}

// One wave per dst node. MODE 0: layer-1 (gather table1[x[s]]; store h1g + sA2/dA2 dots).
// MODE 1: layer-2 raw (gather hbuf[s]; store raw weighted sum). MODE 2: layer-2 direct.
// Weight loop: each 32-lane half owns a contiguous sub-range; 8 independent
// float4 loads in flight per lane to cover L2/L3 latency.
template<int MODE>
__global__ __launch_bounds__(256) void k_agg(const int* __restrict__ rowoff,
    const int* __restrict__ rowcnt, const int* __restrict__ csr_src, const int* __restrict__ x,
    const float* __restrict__ sa, const float* __restrict__ danode,
    const float* __restrict__ feat, const float* __restrict__ cw,
    const float* __restrict__ va2, const float* __restrict__ vd2,
    float* __restrict__ out_h, float* __restrict__ p_lo, float* __restrict__ p_hi){
  int lane = threadIdx.x & 63;
  int node = blockIdx.x*4 + (threadIdx.x >> 6);
  if (node >= N_NODES) return;
  int start = rowoff[node];
  int nj = rowcnt[node];
  int end = start + nj;
  float dA = danode[node];

  float mx, inv;
  float w_sav = 0.f; int rb_sav = 0;
  if (nj <= 64){
    int p = start + lane;
    bool act = p < end;
    int s = 0; float l = -1e30f;
    if (act){
      s = csr_src[p];
      l = sa[s] + dA; l = (l > 0.f) ? l : NEG_SLOPE*l;
      rb_sav = (MODE == 0 ? x[s] : s) * D_H;
    }
    float m = l, ss = act ? 1.0f : 0.0f;
    #pragma unroll
    for (int off=32; off; off>>=1){
      float mo = __shfl_xor(m, off, 64);
      float so = __shfl_xor(ss, off, 64);
      float mn = fmaxf(m, mo);
      ss = ss*expf(m-mn) + so*expf(mo-mn);
      m = mn;
    }
    mx = m; inv = 1.0f/(ss + 1e-16f);
    w_sav = act ? expf(l - mx)*inv : 0.f;
  } else {
    float m = -1e30f, ss = 0.f;
    for (int p = start + lane; p < end; p += 64){
      int s = csr_src[p];
      float l = sa[s] + dA; l = (l > 0.f) ? l : NEG_SLOPE*l;
      float mn = fmaxf(m, l);
      ss = ss*expf(m-mn) + expf(l-mn);
      m = mn;
    }
    #pragma unroll
    for (int off=32; off; off>>=1){
      float mo = __shfl_xor(m, off, 64);
      float so = __shfl_xor(ss, off, 64);
      float mn = fmaxf(m, mo);
      ss = ss*expf(m-mn) + so*expf(mo-mn);
      m = mn;
    }
    mx = m; inv = 1.0f/(ss + 1e-16f);
  }

  int c0 = (lane & 31)*4, half = lane >> 5;
  float a0=0.f, a1=0.f, a2=0.f, a3=0.f;
  for (int t0 = start; t0 < end; t0 += 64){
    float w; int rb;
    if (nj <= 64){ w = w_sav; rb = rb_sav; }
    else {
      int p = t0 + lane;
      w = 0.f; rb = 0;
      if (p < end){
        int s = csr_src[p];
        float l = sa[s] + dA; l = (l > 0.f) ? l : NEG_SLOPE*l;
        w = expf(l - mx)*inv;
        rb = (MODE == 0 ? x[s] : s) * D_H;
      }
    }
    int cnt = end - t0; if (cnt > 64) cnt = 64;
    int mid = (cnt + 1) >> 1;
    int lo = half ? mid : 0;
    int hi = half ? cnt : mid;
    for (int j = lo; j < hi; j += 8){
      float wv[8]; int rv[8];
      #pragma unroll
      for (int u=0; u<8; ++u){
        int idx = (j+u < hi) ? (j+u) : (hi-1);   // clamp: shfl must run on all lanes
        wv[u] = __shfl(w,  idx, 64);
        rv[u] = __shfl(rb, idx, 64);
        if (j+u >= hi) wv[u] = 0.f;
      }
      float4 f[8];
      #pragma unroll
      for (int u=0; u<8; ++u){
        f[u] = make_float4(0.f,0.f,0.f,0.f);
        if (j+u < hi) f[u] = ldf4(feat + rv[u] + c0);   // half-uniform guard: no BW waste
      }
      #pragma unroll
      for (int u=0; u<8; ++u){
        a0 = fmaf(wv[u], f[u].x, a0); a1 = fmaf(wv[u], f[u].y, a1);
        a2 = fmaf(wv[u], f[u].z, a2); a3 = fmaf(wv[u], f[u].w, a3);
      }
    }
  }
  a0 += __shfl_xor(a0,32,64); a1 += __shfl_xor(a1,32,64);
  a2 += __shfl_xor(a2,32,64); a3 += __shfl_xor(a3,32,64);

  if (MODE == 0){
    float o0 = gelu_f(a0 + cw[CO_B1+c0]);
    float o1 = gelu_f(a1 + cw[CO_B1+c0+1]);
    float o2 = gelu_f(a2 + cw[CO_B1+c0+2]);
    float o3 = gelu_f(a3 + cw[CO_B1+c0+3]);
    if (!half) stf4(out_h + (size_t)node*D_H + c0, make_float4(o0,o1,o2,o3));
    float pl = o0*va2[c0] + o1*va2[c0+1] + o2*va2[c0+2] + o3*va2[c0+3];
    float ph = o0*vd2[c0] + o1*vd2[c0+1] + o2*vd2[c0+2] + o3*vd2[c0+3];
    #pragma unroll
    for (int off=16; off; off>>=1){ pl += __shfl_xor(pl,off,64); ph += __shfl_xor(ph,off,64); }
    if (lane == 0){ p_lo[node] = pl; p_hi[node] = ph; }   // = sA2, dA2
  } else if (MODE == 1){
    if (!half) stf4(out_h + (size_t)node*D_H + c0, make_float4(a0,a1,a2,a3));
  } else {
    float o0 = gelu_f(a0 + cw[CO_B2+c0]);
    float o1 = gelu_f(a1 + cw[CO_B2+c0+1]);
    float o2 = gelu_f(a2 + cw[CO_B2+c0+2]);
    float o3 = gelu_f(a3 + cw[CO_B2+c0+3]);
    float pl = o0*cw[CO_WFC+c0]     + o1*cw[CO_WFC+c0+1]
             + o2*cw[CO_WFC+c0+2]   + o3*cw[CO_WFC+c0+3];
    float ph = o0*cw[CO_WFC+D_H+c0]   + o1*cw[CO_WFC+D_H+c0+1]
             + o2*cw[CO_WFC+D_H+c0+2] + o3*cw[CO_WFC+D_H+c0+3];
    #pragma unroll
    for (int off=16; off; off>>=1){ pl += __shfl_xor(pl,off,64); ph += __shfl_xor(ph,off,64); }
    if (lane == 0){ p_lo[node] = pl; p_hi[node] = ph; }
  }
}

// Path a: p_lo/p_hi = gelu(agg2@W2 + b2) . Wfc halves. (LDS-staged matmul)
__global__ __launch_bounds__(256) void k_post(const float* __restrict__ agg2,
    const float* __restrict__ cw, float* __restrict__ p_lo, float* __restrict__ p_hi){
  __shared__ float xr[64][D_H];   // 32 KB
  __shared__ float W[64][D_H];    // 32 KB
  const float* W2 = cw + CO_W2;
  int tid = threadIdx.x;
  int cg = tid & 31;
  int rg = tid >> 5;
  int base = blockIdx.x * 64;

  for (int i = tid; i < 64*D_H/4; i += 256){
    int row = i >> 5, c4 = (i & 31) * 4;
    int rr = base + row;
    float4 v = (rr < N_NODES) ? ldf4(agg2 + (size_t)rr*D_H + c4) : make_float4(0.f,0.f,0.f,0.f);
    stf4(&xr[row][c4], v);
  }

  float4 acc[8];
  #pragma unroll
  for (int rs=0; rs<8; ++rs) acc[rs] = make_float4(0.f,0.f,0.f,0.f);

  #pragma unroll
  for (int hk = 0; hk < 2; ++hk){
    __syncthreads();
    for (int i = tid; i < 64*D_H/4; i += 256){
      int k = i >> 5, c4 = (i & 31) * 4;
      stf4(&W[k][c4], ldf4(W2 + (size_t)(hk*64 + k)*D_H + c4));
    }
    __syncthreads();
    for (int k = 0; k < 64; ++k){
      float4 wv = ldf4(&W[k][cg*4]);
      int kk = hk*64 + k;
      #pragma unroll
      for (int rs = 0; rs < 8; ++rs){
        float xv = xr[rs*8 + rg][kk];
        acc[rs].x = fmaf(xv, wv.x, acc[rs].x);
        acc[rs].y = fmaf(xv, wv.y, acc[rs].y);
        acc[rs].z = fmaf(xv, wv.z, acc[rs].z);
        acc[rs].w = fmaf(xv, wv.w, acc[rs].w);
      }
    }
  }

  float4 b2v = ldf4(cw + CO_B2  + cg*4);
  float4 wlo = ldf4(cw + CO_WFC + cg*4);
  float4 whi = ldf4(cw + CO_WFC + D_H + cg*4);
  #pragma unroll
  for (int rs = 0; rs < 8; ++rs){
    int rr = base + rs*8 + rg;
    float o0 = gelu_f(acc[rs].x + b2v.x);
    float o1 = gelu_f(acc[rs].y + b2v.y);
    float o2 = gelu_f(acc[rs].z + b2v.z);
    float o3 = gelu_f(acc[rs].w + b2v.w);
    float pl = o0*wlo.x + o1*wlo.y + o2*wlo.z + o3*wlo.w;
    float ph = o0*whi.x + o1*whi.y + o2*whi.z + o3*whi.w;
    #pragma unroll
    for (int off=16; off; off>>=1){ pl += __shfl_xor(pl,off,64); ph += __shfl_xor(ph,off,64); }
    if (cg == 0 && rr < N_NODES){ p_lo[rr] = pl; p_hi[rr] = ph; }
  }
}

// Path b fallback: hbuf = hbuf @ W2 in place per 64-row block.
__global__ __launch_bounds__(256) void k_matmul2(float* __restrict__ hbuf, const float* __restrict__ cw){
  const float* W2 = cw + CO_W2;
  __shared__ float xr[16][D_H];
  int tid = threadIdx.x;
  int col = tid & 127, half = tid >> 7;
  int base = blockIdx.x * 64;
  for (int t0=0; t0<64; t0+=16){
    int r0 = base + t0;
    for (int i=tid; i<16*D_H; i+=256){
      int rr = r0 + (i>>7);
      xr[i>>7][i&127] = (rr < N_NODES) ? hbuf[(size_t)rr*D_H + (i&127)] : 0.f;
    }
    __syncthreads();
    float acc[8];
    #pragma unroll
    for (int r=0;r<8;++r) acc[r] = 0.f;
    int rb = half*8;
    for (int k=0;k<D_H;++k){
      float wv = W2[k*D_H + col];
      #pragma unroll
      for (int r=0;r<8;++r) acc[r] = fmaf(xr[rb+r][k], wv, acc[r]);
    }
    #pragma unroll
    for (int r=0;r<8;++r){
      int rr = r0 + rb + r;
      if (rr < N_NODES) hbuf[(size_t)rr*D_H + col] = acc[r];
    }
    __syncthreads();
  }
}

// 4 edges per thread, vectorized int4 reads of src/dst.
__global__ void k_final(const int* __restrict__ src, const int* __restrict__ dst,
    const float* __restrict__ p_lo, const float* __restrict__ p_hi,
    const float* __restrict__ cw, const int* __restrict__ flag, void* __restrict__ out){
  int q = blockIdx.x*blockDim.x + threadIdx.x;
  int e0 = q*4;
  if (e0 >= N_EDGES) return;
  float bfc = cw[CO_BFC];
  if (e0 + 4 <= N_EDGES){
    int4 s4 = *reinterpret_cast<const int4*>(src + e0);
    int4 d4 = *reinterpret_cast<const int4*>(dst + e0);
    float4 v;
    v.x = gelu_f(p_lo[s4.x] + p_hi[d4.x] + bfc);
    v.y = gelu_f(p_lo[s4.y] + p_hi[d4.y] + bfc);
    v.z = gelu_f(p_lo[s4.z] + p_hi[d4.z] + bfc);
    v.w = gelu_f(p_lo[s4.w] + p_hi[d4.w] + bfc);
    if (*flag){
      __hip_bfloat16* o = (__hip_bfloat16*)out + e0;
      o[0]=__float2bfloat16(v.x); o[1]=__float2bfloat16(v.y);
      o[2]=__float2bfloat16(v.z); o[3]=__float2bfloat16(v.w);
    } else {
      stf4((float*)out + e0, v);
    }
  } else {
    for (int e = e0; e < N_EDGES; ++e){
      float v = gelu_f(p_lo[src[e]] + p_hi[dst[e]] + bfc);
      if (*flag) ((__hip_bfloat16*)out)[e] = __float2bfloat16(v);
      else       ((float*)out)[e] = v;
    }
  }
}

extern "C" void kernel_launch(void* const* d_in, const int* in_sizes, int n_in,
                              void* d_out, int out_size, void* d_ws, size_t ws_size,
                              hipStream_t stream){
  (void)in_sizes; (void)n_in; (void)out_size;
  const int* x  = (const int*)d_in[0];
  const int* ei = (const int*)d_in[1];
  const int* src = ei;
  const int* dst = ei + N_EDGES;

  // ---- workspace layout ----
  char* base = (char*)d_ws;
  size_t off = 0;
  auto A = [&](size_t bytes)->size_t{ size_t r = off; off = (off + bytes + 255) & ~(size_t)255; return r; };
  size_t o_flag   = A(4);
  size_t o_cw     = A((size_t)CO_TOTAL*4);
  size_t o_va2    = A(D_H*4);
  size_t o_vd2    = A(D_H*4);
  size_t o_table1 = A((size_t)VOCAB*D_H*4);
  size_t o_as1    = A(VOCAB*4);
  size_t o_ad1    = A(VOCAB*4);
  size_t o_sA1    = A((size_t)N_NODES*4);
  size_t o_dA1    = A((size_t)N_NODES*4);
  size_t o_sA2    = A((size_t)N_NODES*4);
  size_t o_dA2    = A((size_t)N_NODES*4);
  size_t o_rowoff = A((size_t)N_NODES*4);
  size_t o_rowcnt = A((size_t)N_NODES*4);
  size_t o_plo    = A((size_t)N_NODES*4);
  size_t o_phi    = A((size_t)N_NODES*4);
  size_t o_gcur   = A((size_t)NB*4);
  size_t o_cbase  = A((size_t)NB*4);
  size_t o_csr    = A((size_t)N_ESL*4);
  size_t o_big    = A((size_t)N_NODES*D_H*4);   // ebuf (9.6MB) then hbuf (51.2MB)
  size_t need_b   = off;
  size_t o_agg2   = A((size_t)N_NODES*D_H*4);
  size_t need_a   = off;

  int*   flag   = (int*)(base + o_flag);
  float* cw     = (float*)(base + o_cw);
  float* va2    = (float*)(base + o_va2);
  float* vd2    = (float*)(base + o_vd2);
  float* table1 = (float*)(base + o_table1);
  float* as1    = (float*)(base + o_as1);
  float* ad1    = (float*)(base + o_ad1);
  float* sA1    = (float*)(base + o_sA1);
  float* dA1    = (float*)(base + o_dA1);
  float* sA2    = (float*)(base + o_sA2);
  float* dA2    = (float*)(base + o_dA2);
  int*   rowoff = (int*)(base + o_rowoff);
  int*   rowcnt = (int*)(base + o_rowcnt);
  float* plo    = (float*)(base + o_plo);
  float* phi    = (float*)(base + o_phi);
  int*   gcur   = (int*)(base + o_gcur);
  int*   cbase  = (int*)(base + o_cbase);
  int*   csr    = (int*)(base + o_csr);
  float* hbuf   = (float*)(base + o_big);
  unsigned* ebuf= (unsigned*)(base + o_big);    // dead before hbuf is written
  float* agg2   = (float*)(base + o_agg2);

  if (ws_size < need_b) return;         // signature: out stays 0
  bool patha = (ws_size >= need_a);

  k_detect<<<1, 64, 0, stream>>>((const unsigned*)d_in[2], flag);
  k_setup<<<352, 256, 0, stream>>>(d_in[2], d_in[3], d_in[4], d_in[5],
      d_in[6], d_in[7], d_in[8], d_in[9], d_in[10], d_in[11], d_in[12], flag, cw, va2, vd2);
  k_table1<<<VOCAB, 64, 0, stream>>>(cw, table1, as1, ad1);
  k_nodelog<<<(N_NODES+255)/256, 256, 0, stream>>>(x, as1, ad1, sA1, dA1);

  // bucketed CSR build
  hipMemsetAsync(gcur, 0, (size_t)NB*4, stream);
  k_bin<<<(N_ESL+CHUNK-1)/CHUNK, 256, 0, stream>>>(src, dst, gcur, ebuf);
  k_bscan<<<1, 1024, 0, stream>>>(gcur, cbase);
  k_group<<<NB, 256, 0, stream>>>(ebuf, gcur, cbase, csr, rowoff, rowcnt);

  int nagg = (N_NODES+3)/4;
  // layer 1: h1g -> hbuf (overwrites ebuf region), plus sA2/dA2 via va2/vd2
  k_agg<0><<<nagg, 256, 0, stream>>>(rowoff, rowcnt, csr, x, sA1, dA1, table1, cw, va2, vd2, hbuf, sA2, dA2);
  if (patha){
    k_agg<1><<<nagg, 256, 0, stream>>>(rowoff, rowcnt, csr, x, sA2, dA2, hbuf, cw, va2, vd2, agg2, nullptr, nullptr);
    k_post<<<(N_NODES+63)/64, 256, 0, stream>>>(agg2, cw, plo, phi);
  } else {
    k_matmul2<<<(N_NODES+63)/64, 256, 0, stream>>>(hbuf, cw);
    k_agg<2><<<nagg, 256, 0, stream>>>(rowoff, rowcnt, csr, x, sA2, dA2, hbuf, cw, va2, vd2, nullptr, plo, phi);
  }
  k_final<<<(N_EDGES/4+255)/256, 256, 0, stream>>>(src, dst, plo, phi, cw, flag, d_out);
}

// Round 12
// 370.581 us; speedup vs baseline: 1.0505x; 1.0505x over previous
//
#include <hip/hip_runtime.h>
#include <hip/hip_bf16.h>

#define N_NODES 100000
#define N_EDGES 1600000
#define N_ESL   1700000   // edges + self loops
#define VOCAB   1000
#define D_IN    64
#define D_H     128
#define NEG_SLOPE 0.2f

// dst-bucket binning
#define BSH   7
#define NB    782          // ceil(100000/128)
#define CAP   3072         // per-bucket capacity (mean 2174, sigma ~47)
#define CHUNK 16384

// canonical fp32 weight-table offsets (elements)
#define CO_EMB   0
#define CO_W1    64000
#define CO_AS1   72192
#define CO_AD1   72320
#define CO_B1    72448
#define CO_W2    72576
#define CO_AS2   88960
#define CO_AD2   89088
#define CO_B2    89216
#define CO_WFC   89344
#define CO_BFC   89600
#define CO_TOTAL 89601

__device__ __forceinline__ float us2f(unsigned short h){ union{unsigned v; float f;} c; c.v = ((unsigned)h)<<16; return c.f; }
__device__ __forceinline__ float gelu_f(float v){ return 0.5f*v*(1.0f + erff(v*0.7071067811865475f)); }
__device__ __forceinline__ float4 ldf4(const float* p){ return *reinterpret_cast<const float4*>(p); }
__device__ __forceinline__ void stf4(float* p, float4 v){ *reinterpret_cast<float4*>(p) = v; }

__device__ __forceinline__ float wred_sum(float v){
  #pragma unroll
  for (int m=32;m;m>>=1) v += __shfl_xor(v,m,64);
  return v;
}

// Detect whether float inputs are bf16-packed (flag=1) or fp32 (flag=0).
__global__ __launch_bounds__(64) void k_detect(const unsigned* __restrict__ w, int* __restrict__ flag){
  int t = threadIdx.x;
  float cnt = 0.f;
  #pragma unroll
  for (int i=0;i<2;++i){
    unsigned v = w[t + 64*i];
    unsigned e = (v >> 7) & 0xFFu;
    cnt += (e >= 110u && e <= 126u) ? 1.f : 0.f;
  }
  cnt = wred_sum(cnt);
  if (t==0) *flag = (cnt >= 64.f) ? 1 : 0;
}

// Blocks 0..350: canonicalize the 11 float inputs into the fp32 table cw.
// Block 351: prevec -- va2 = W2 @ a_src2 ; vd2 = W2 @ a_dst2 (reads RAW inputs).
// Arg mapping: p0=emb p1=W1 p2=as1 p3=ad1 p4=b1 p5=W2 p6=as2 p7=ad2 p8=b2 p9=Wfc p10=bfc.
__global__ __launch_bounds__(256) void k_setup(const void* p0, const void* p1, const void* p2, const void* p3,
    const void* p4, const void* p5, const void* p6, const void* p7, const void* p8,
    const void* p9, const void* p10, const int* __restrict__ flag, float* __restrict__ c,
    float* __restrict__ va2, float* __restrict__ vd2){
  int b = blockIdx.x;
  if (b == 351){
    int t = threadIdx.x;
    int r = t & 127;
    int f = *flag;
    const float* w2f = (const float*)p5;                 // p5 = W2
    const unsigned short* w2h = (const unsigned short*)p5;
    const float* af = (const float*)((t < 128) ? p6 : p7);              // as2 / ad2
    const unsigned short* ah = (const unsigned short*)((t < 128) ? p6 : p7);
    float s = 0.f;
    for (int j=0;j<D_H;++j){
      float wv = f ? us2f(w2h[r*D_H+j]) : w2f[r*D_H+j];
      float av = f ? us2f(ah[j]) : af[j];
      s = fmaf(wv, av, s);
    }
    if (t < 128) va2[r] = s; else vd2[r] = s;
    return;
  }
  int i = b*256 + threadIdx.x;
  if (i >= CO_TOTAL) return;
  const void* src; int off;
  if      (i < CO_W1 ){ src=p0;  off=i;          }
  else if (i < CO_AS1){ src=p1;  off=i-CO_W1;    }
  else if (i < CO_AD1){ src=p2;  off=i-CO_AS1;   }
  else if (i < CO_B1 ){ src=p3;  off=i-CO_AD1;   }
  else if (i < CO_W2 ){ src=p4;  off=i-CO_B1;    }
  else if (i < CO_AS2){ src=p5;  off=i-CO_W2;    }
  else if (i < CO_AD2){ src=p6;  off=i-CO_AS2;   }
  else if (i < CO_B2 ){ src=p7;  off=i-CO_AD2;   }
  else if (i < CO_WFC){ src=p8;  off=i-CO_B2;    }
  else if (i < CO_BFC){ src=p9;  off=i-CO_WFC;   }
  else               { src=p10; off=i-CO_BFC;   }
  float v = (*flag) ? us2f(((const unsigned short*)src)[off]) : ((const float*)src)[off];
  c[i] = v;
}

// table1[v][:] = emb[v] @ W1 ; as1[v]/ad1[v] = attention dots
__global__ __launch_bounds__(64) void k_table1(const float* __restrict__ cw,
    float* __restrict__ table1, float* __restrict__ as1, float* __restrict__ ad1){
  const float* emb = cw + CO_EMB;
  const float* W1  = cw + CO_W1;
  int v = blockIdx.x; int t = threadIdx.x;
  __shared__ float er[D_IN];
  er[t] = emb[v*D_IN + t];
  __syncthreads();
  int d0 = t, d1 = t + 64;
  float a0 = 0.f, a1 = 0.f;
  for (int k=0;k<D_IN;++k){
    float e = er[k];
    a0 = fmaf(e, W1[k*D_H+d0], a0);
    a1 = fmaf(e, W1[k*D_H+d1], a1);
  }
  table1[v*D_H+d0] = a0; table1[v*D_H+d1] = a1;
  float ps = a0*cw[CO_AS1+d0] + a1*cw[CO_AS1+d1];
  float pd = a0*cw[CO_AD1+d0] + a1*cw[CO_AD1+d1];
  ps = wred_sum(ps); pd = wred_sum(pd);
  if (t==0){ as1[v]=ps; ad1[v]=pd; }
}

__global__ void k_nodelog(const int* __restrict__ x, const float* __restrict__ as1,
    const float* __restrict__ ad1, float* __restrict__ sA1, float* __restrict__ dA1){
  int i = blockIdx.x*blockDim.x + threadIdx.x;
  if (i < N_NODES){ int xs = x[i]; sA1[i] = as1[xs]; dA1[i] = ad1[xs]; }
}

// ---- bucketed CSR build ----
// N_EDGES and CHUNK are multiples of 4, so every aligned int4 group is
// entirely real-edge or entirely self-loop.
__global__ __launch_bounds__(256) void k_bin(const int* __restrict__ src,
    const int* __restrict__ dst, int* __restrict__ gcur, unsigned* __restrict__ ebuf){
  __shared__ int hist[NB];
  __shared__ int cur[NB];
  int tid = threadIdx.x;
  int base0 = blockIdx.x * CHUNK;
  int n = N_ESL - base0; if (n > CHUNK) n = CHUNK;
  for (int i=tid; i<NB; i+=256) hist[i] = 0;
  __syncthreads();
  for (int k = tid*4; k < n; k += 1024){
    int e = base0 + k;
    int4 d4;
    if (e + 4 <= N_EDGES) d4 = *reinterpret_cast<const int4*>(dst + e);
    else d4 = make_int4(e-N_EDGES, e+1-N_EDGES, e+2-N_EDGES, e+3-N_EDGES);
    atomicAdd(&hist[d4.x>>BSH], 1);
    atomicAdd(&hist[d4.y>>BSH], 1);
    atomicAdd(&hist[d4.z>>BSH], 1);
    atomicAdd(&hist[d4.w>>BSH], 1);
  }
  __syncthreads();
  for (int b=tid; b<NB; b+=256){
    int c = hist[b];
    cur[b] = c ? atomicAdd(&gcur[b], c) : 0;
  }
  __syncthreads();
  for (int k = tid*4; k < n; k += 1024){
    int e = base0 + k;
    int4 d4, s4;
    if (e + 4 <= N_EDGES){
      d4 = *reinterpret_cast<const int4*>(dst + e);
      s4 = *reinterpret_cast<const int4*>(src + e);
    } else {
      d4 = make_int4(e-N_EDGES, e+1-N_EDGES, e+2-N_EDGES, e+3-N_EDGES);
      s4 = d4;
    }
    int p0 = atomicAdd(&cur[d4.x>>BSH], 1);
    if (p0 < CAP) ebuf[(size_t)(d4.x>>BSH)*CAP + p0] = (unsigned)(((d4.x & 127) << 17) | s4.x);
    int p1 = atomicAdd(&cur[d4.y>>BSH], 1);
    if (p1 < CAP) ebuf[(size_t)(d4.y>>BSH)*CAP + p1] = (unsigned)(((d4.y & 127) << 17) | s4.y);
    int p2 = atomicAdd(&cur[d4.z>>BSH], 1);
    if (p2 < CAP) ebuf[(size_t)(d4.z>>BSH)*CAP + p2] = (unsigned)(((d4.z & 127) << 17) | s4.z);
    int p3 = atomicAdd(&cur[d4.w>>BSH], 1);
    if (p3 < CAP) ebuf[(size_t)(d4.w>>BSH)*CAP + p3] = (unsigned)(((d4.w & 127) << 17) | s4.w);
  }
}

__global__ __launch_bounds__(1024) void k_bscan(const int* __restrict__ gcur, int* __restrict__ csrbase){
  int t = threadIdx.x, lane = t & 63, wid = t >> 6;
  int c = (t < NB) ? gcur[t] : 0;
  if (c > CAP) c = CAP;
  int v = c;
  #pragma unroll
  for (int m=1;m<64;m<<=1){ int u = __shfl_up(v,m,64); if (lane>=m) v += u; }
  __shared__ int wsum[16], woff[16];
  if (lane==63) wsum[wid] = v;
  __syncthreads();
  if (t==0){ int run=0; for (int w=0;w<16;++w){ woff[w]=run; run+=wsum[w]; } }
  __syncthreads();
  v += woff[wid];
  if (t < NB) csrbase[t] = v - c;
}

__global__ __launch_bounds__(256) void k_group(const unsigned* __restrict__ ebuf,
    const int* __restrict__ gcur, const int* __restrict__ csrbase,
    int* __restrict__ csr, int* __restrict__ rowoff, int* __restrict__ rowcnt){
  __shared__ unsigned stage[CAP];
  __shared__ int hist[128], cur[128];
  __shared__ int wtot;
  int b = blockIdx.x, tid = threadIdx.x;
  int n = gcur[b]; if (n > CAP) n = CAP;
  int nodeBase = b << BSH;
  int cbase = csrbase[b];
  if (tid < 128) hist[tid] = 0;
  __syncthreads();
  int nv = n & ~3;
  for (int k = tid*4; k < nv; k += 1024){
    uint4 q = *reinterpret_cast<const uint4*>(ebuf + (size_t)b*CAP + k);
    stage[k]   = q.x; atomicAdd(&hist[q.x >> 17], 1);
    stage[k+1] = q.y; atomicAdd(&hist[q.y >> 17], 1);
    stage[k+2] = q.z; atomicAdd(&hist[q.z >> 17], 1);
    stage[k+3] = q.w; atomicAdd(&hist[q.w >> 17], 1);
  }
  for (int k = nv + tid; k < n; k += 256){
    unsigned p = ebuf[(size_t)b*CAP + k];
    stage[k] = p;
    atomicAdd(&hist[p >> 17], 1);
  }
  __syncthreads();
  // parallel exclusive scan of hist[0..127] (two waves + carry)
  int v128 = 0;
  if (tid < 128){
    int lane = tid & 63;
    v128 = hist[tid];
    #pragma unroll
    for (int m=1;m<64;m<<=1){ int u = __shfl_up(v128,m,64); if (lane>=m) v128 += u; }
    if (tid == 63) wtot = v128;
  }
  __syncthreads();
  if (tid < 128){
    int incl = v128 + ((tid >= 64) ? wtot : 0);
    int excl = incl - hist[tid];
    int d = nodeBase + tid;
    if (d < N_NODES){ rowoff[d] = cbase + excl; rowcnt[d] = hist[tid]; }
    cur[tid] = excl;
  }
  __syncthreads();
  for (int k=tid; k<n; k+=256){
    unsigned p = stage[k];
    int pos = atomicAdd(&cur[p >> 17], 1);
    csr[cbase + pos] = (int)(p & 0x1FFFFu);
  }
}

// One wave per dst node. MODE 0: layer-1 (gather table1[x[s]]; store h1g + sA2/dA2 dots).
// MODE 1: layer-2 raw (gather hbuf[s]; store raw weighted sum). MODE 2: layer-2 direct.
// Weight loop (round-9 form, measured best): each 32-lane half owns a contiguous
// sub-range with 4 independent float4 loads in flight.
template<int MODE>
__global__ __launch_bounds__(256) void k_agg(const int* __restrict__ rowoff,
    const int* __restrict__ rowcnt, const int* __restrict__ csr_src, const int* __restrict__ x,
    const float* __restrict__ sa, const float* __restrict__ danode,
    const float* __restrict__ feat, const float* __restrict__ cw,
    const float* __restrict__ va2, const float* __restrict__ vd2,
    float* __restrict__ out_h, float* __restrict__ p_lo, float* __restrict__ p_hi){
  int lane = threadIdx.x & 63;
  int node = blockIdx.x*4 + (threadIdx.x >> 6);
  if (node >= N_NODES) return;
  int start = rowoff[node];
  int nj = rowcnt[node];
  int end = start + nj;
  float dA = danode[node];

  float mx, inv;
  float w_sav = 0.f; int rb_sav = 0;
  if (nj <= 64){
    int p = start + lane;
    bool act = p < end;
    int s = 0; float l = -1e30f;
    if (act){
      s = csr_src[p];
      l = sa[s] + dA; l = (l > 0.f) ? l : NEG_SLOPE*l;
      rb_sav = (MODE == 0 ? x[s] : s) * D_H;
    }
    float m = l, ss = act ? 1.0f : 0.0f;
    #pragma unroll
    for (int off=32; off; off>>=1){
      float mo = __shfl_xor(m, off, 64);
      float so = __shfl_xor(ss, off, 64);
      float mn = fmaxf(m, mo);
      ss = ss*expf(m-mn) + so*expf(mo-mn);
      m = mn;
    }
    mx = m; inv = 1.0f/(ss + 1e-16f);
    w_sav = act ? expf(l - mx)*inv : 0.f;
  } else {
    float m = -1e30f, ss = 0.f;
    for (int p = start + lane; p < end; p += 64){
      int s = csr_src[p];
      float l = sa[s] + dA; l = (l > 0.f) ? l : NEG_SLOPE*l;
      float mn = fmaxf(m, l);
      ss = ss*expf(m-mn) + expf(l-mn);
      m = mn;
    }
    #pragma unroll
    for (int off=32; off; off>>=1){
      float mo = __shfl_xor(m, off, 64);
      float so = __shfl_xor(ss, off, 64);
      float mn = fmaxf(m, mo);
      ss = ss*expf(m-mn) + so*expf(mo-mn);
      m = mn;
    }
    mx = m; inv = 1.0f/(ss + 1e-16f);
  }

  int c0 = (lane & 31)*4, half = lane >> 5;
  float a0=0.f, a1=0.f, a2=0.f, a3=0.f;
  for (int t0 = start; t0 < end; t0 += 64){
    float w; int rb;
    if (nj <= 64){ w = w_sav; rb = rb_sav; }
    else {
      int p = t0 + lane;
      w = 0.f; rb = 0;
      if (p < end){
        int s = csr_src[p];
        float l = sa[s] + dA; l = (l > 0.f) ? l : NEG_SLOPE*l;
        w = expf(l - mx)*inv;
        rb = (MODE == 0 ? x[s] : s) * D_H;
      }
    }
    int cnt = end - t0; if (cnt > 64) cnt = 64;
    // split: half0 -> [0, mid), half1 -> [mid, cnt); 4 loads in flight each
    int mid = (cnt + 1) >> 1;
    int lo = half ? mid : 0;
    int hi = half ? cnt : mid;
    for (int j = lo; j < hi; j += 4){
      int nh = hi - j;
      float w0 = __shfl(w,  j,   64), w1 = __shfl(w,  j+1, 64);
      float w2 = __shfl(w,  j+2, 64), w3 = __shfl(w,  j+3, 64);
      int   r0 = __shfl(rb, j,   64), r1 = __shfl(rb, j+1, 64);
      int   r2 = __shfl(rb, j+2, 64), r3 = __shfl(rb, j+3, 64);
      float4 f0 = make_float4(0.f,0.f,0.f,0.f), f1 = f0, f2 = f0, f3 = f0;
      f0 = ldf4(feat + r0 + c0);
      if (nh > 1) f1 = ldf4(feat + r1 + c0);
      if (nh > 2) f2 = ldf4(feat + r2 + c0);
      if (nh > 3) f3 = ldf4(feat + r3 + c0);
      a0 = fmaf(w0, f0.x, a0); a1 = fmaf(w0, f0.y, a1);
      a2 = fmaf(w0, f0.z, a2); a3 = fmaf(w0, f0.w, a3);
      a0 = fmaf(w1, f1.x, a0); a1 = fmaf(w1, f1.y, a1);
      a2 = fmaf(w1, f1.z, a2); a3 = fmaf(w1, f1.w, a3);
      a0 = fmaf(w2, f2.x, a0); a1 = fmaf(w2, f2.y, a1);
      a2 = fmaf(w2, f2.z, a2); a3 = fmaf(w2, f2.w, a3);
      a0 = fmaf(w3, f3.x, a0); a1 = fmaf(w3, f3.y, a1);
      a2 = fmaf(w3, f3.z, a2); a3 = fmaf(w3, f3.w, a3);
    }
  }
  a0 += __shfl_xor(a0,32,64); a1 += __shfl_xor(a1,32,64);
  a2 += __shfl_xor(a2,32,64); a3 += __shfl_xor(a3,32,64);

  if (MODE == 0){
    float o0 = gelu_f(a0 + cw[CO_B1+c0]);
    float o1 = gelu_f(a1 + cw[CO_B1+c0+1]);
    float o2 = gelu_f(a2 + cw[CO_B1+c0+2]);
    float o3 = gelu_f(a3 + cw[CO_B1+c0+3]);
    if (!half) stf4(out_h + (size_t)node*D_H + c0, make_float4(o0,o1,o2,o3));
    float pl = o0*va2[c0] + o1*va2[c0+1] + o2*va2[c0+2] + o3*va2[c0+3];
    float ph = o0*vd2[c0] + o1*vd2[c0+1] + o2*vd2[c0+2] + o3*vd2[c0+3];
    #pragma unroll
    for (int off=16; off; off>>=1){ pl += __shfl_xor(pl,off,64); ph += __shfl_xor(ph,off,64); }
    if (lane == 0){ p_lo[node] = pl; p_hi[node] = ph; }   // = sA2, dA2
  } else if (MODE == 1){
    if (!half) stf4(out_h + (size_t)node*D_H + c0, make_float4(a0,a1,a2,a3));
  } else {
    float o0 = gelu_f(a0 + cw[CO_B2+c0]);
    float o1 = gelu_f(a1 + cw[CO_B2+c0+1]);
    float o2 = gelu_f(a2 + cw[CO_B2+c0+2]);
    float o3 = gelu_f(a3 + cw[CO_B2+c0+3]);
    float pl = o0*cw[CO_WFC+c0]     + o1*cw[CO_WFC+c0+1]
             + o2*cw[CO_WFC+c0+2]   + o3*cw[CO_WFC+c0+3];
    float ph = o0*cw[CO_WFC+D_H+c0]   + o1*cw[CO_WFC+D_H+c0+1]
             + o2*cw[CO_WFC+D_H+c0+2] + o3*cw[CO_WFC+D_H+c0+3];
    #pragma unroll
    for (int off=16; off; off>>=1){ pl += __shfl_xor(pl,off,64); ph += __shfl_xor(ph,off,64); }
    if (lane == 0){ p_lo[node] = pl; p_hi[node] = ph; }
  }
}

// Path a: p_lo/p_hi = gelu(agg2@W2 + b2) . Wfc halves. (LDS-staged matmul)
__global__ __launch_bounds__(256) void k_post(const float* __restrict__ agg2,
    const float* __restrict__ cw, float* __restrict__ p_lo, float* __restrict__ p_hi){
  __shared__ float xr[64][D_H];   // 32 KB
  __shared__ float W[64][D_H];    // 32 KB
  const float* W2 = cw + CO_W2;
  int tid = threadIdx.x;
  int cg = tid & 31;
  int rg = tid >> 5;
  int base = blockIdx.x * 64;

  for (int i = tid; i < 64*D_H/4; i += 256){
    int row = i >> 5, c4 = (i & 31) * 4;
    int rr = base + row;
    float4 v = (rr < N_NODES) ? ldf4(agg2 + (size_t)rr*D_H + c4) : make_float4(0.f,0.f,0.f,0.f);
    stf4(&xr[row][c4], v);
  }

  float4 acc[8];
  #pragma unroll
  for (int rs=0; rs<8; ++rs) acc[rs] = make_float4(0.f,0.f,0.f,0.f);

  #pragma unroll
  for (int hk = 0; hk < 2; ++hk){
    __syncthreads();
    for (int i = tid; i < 64*D_H/4; i += 256){
      int k = i >> 5, c4 = (i & 31) * 4;
      stf4(&W[k][c4], ldf4(W2 + (size_t)(hk*64 + k)*D_H + c4));
    }
    __syncthreads();
    for (int k = 0; k < 64; ++k){
      float4 wv = ldf4(&W[k][cg*4]);
      int kk = hk*64 + k;
      #pragma unroll
      for (int rs = 0; rs < 8; ++rs){
        float xv = xr[rs*8 + rg][kk];
        acc[rs].x = fmaf(xv, wv.x, acc[rs].x);
        acc[rs].y = fmaf(xv, wv.y, acc[rs].y);
        acc[rs].z = fmaf(xv, wv.z, acc[rs].z);
        acc[rs].w = fmaf(xv, wv.w, acc[rs].w);
      }
    }
  }

  float4 b2v = ldf4(cw + CO_B2  + cg*4);
  float4 wlo = ldf4(cw + CO_WFC + cg*4);
  float4 whi = ldf4(cw + CO_WFC + D_H + cg*4);
  #pragma unroll
  for (int rs = 0; rs < 8; ++rs){
    int rr = base + rs*8 + rg;
    float o0 = gelu_f(acc[rs].x + b2v.x);
    float o1 = gelu_f(acc[rs].y + b2v.y);
    float o2 = gelu_f(acc[rs].z + b2v.z);
    float o3 = gelu_f(acc[rs].w + b2v.w);
    float pl = o0*wlo.x + o1*wlo.y + o2*wlo.z + o3*wlo.w;
    float ph = o0*whi.x + o1*whi.y + o2*whi.z + o3*whi.w;
    #pragma unroll
    for (int off=16; off; off>>=1){ pl += __shfl_xor(pl,off,64); ph += __shfl_xor(ph,off,64); }
    if (cg == 0 && rr < N_NODES){ p_lo[rr] = pl; p_hi[rr] = ph; }
  }
}

// Path b fallback: hbuf = hbuf @ W2 in place per 64-row block.
__global__ __launch_bounds__(256) void k_matmul2(float* __restrict__ hbuf, const float* __restrict__ cw){
  const float* W2 = cw + CO_W2;
  __shared__ float xr[16][D_H];
  int tid = threadIdx.x;
  int col = tid & 127, half = tid >> 7;
  int base = blockIdx.x * 64;
  for (int t0=0; t0<64; t0+=16){
    int r0 = base + t0;
    for (int i=tid; i<16*D_H; i+=256){
      int rr = r0 + (i>>7);
      xr[i>>7][i&127] = (rr < N_NODES) ? hbuf[(size_t)rr*D_H + (i&127)] : 0.f;
    }
    __syncthreads();
    float acc[8];
    #pragma unroll
    for (int r=0;r<8;++r) acc[r] = 0.f;
    int rb = half*8;
    for (int k=0;k<D_H;++k){
      float wv = W2[k*D_H + col];
      #pragma unroll
      for (int r=0;r<8;++r) acc[r] = fmaf(xr[rb+r][k], wv, acc[r]);
    }
    #pragma unroll
    for (int r=0;r<8;++r){
      int rr = r0 + rb + r;
      if (rr < N_NODES) hbuf[(size_t)rr*D_H + col] = acc[r];
    }
    __syncthreads();
  }
}

// 4 edges per thread, vectorized int4 reads of src/dst.
__global__ void k_final(const int* __restrict__ src, const int* __restrict__ dst,
    const float* __restrict__ p_lo, const float* __restrict__ p_hi,
    const float* __restrict__ cw, const int* __restrict__ flag, void* __restrict__ out){
  int q = blockIdx.x*blockDim.x + threadIdx.x;
  int e0 = q*4;
  if (e0 >= N_EDGES) return;
  float bfc = cw[CO_BFC];
  if (e0 + 4 <= N_EDGES){
    int4 s4 = *reinterpret_cast<const int4*>(src + e0);
    int4 d4 = *reinterpret_cast<const int4*>(dst + e0);
    float4 v;
    v.x = gelu_f(p_lo[s4.x] + p_hi[d4.x] + bfc);
    v.y = gelu_f(p_lo[s4.y] + p_hi[d4.y] + bfc);
    v.z = gelu_f(p_lo[s4.z] + p_hi[d4.z] + bfc);
    v.w = gelu_f(p_lo[s4.w] + p_hi[d4.w] + bfc);
    if (*flag){
      __hip_bfloat16* o = (__hip_bfloat16*)out + e0;
      o[0]=__float2bfloat16(v.x); o[1]=__float2bfloat16(v.y);
      o[2]=__float2bfloat16(v.z); o[3]=__float2bfloat16(v.w);
    } else {
      stf4((float*)out + e0, v);
    }
  } else {
    for (int e = e0; e < N_EDGES; ++e){
      float v = gelu_f(p_lo[src[e]] + p_hi[dst[e]] + bfc);
      if (*flag) ((__hip_bfloat16*)out)[e] = __float2bfloat16(v);
      else       ((float*)out)[e] = v;
    }
  }
}

extern "C" void kernel_launch(void* const* d_in, const int* in_sizes, int n_in,
                              void* d_out, int out_size, void* d_ws, size_t ws_size,
                              hipStream_t stream){
  (void)in_sizes; (void)n_in; (void)out_size;
  const int* x  = (const int*)d_in[0];
  const int* ei = (const int*)d_in[1];
  const int* src = ei;
  const int* dst = ei + N_EDGES;

  // ---- workspace layout ----
  char* base = (char*)d_ws;
  size_t off = 0;
  auto A = [&](size_t bytes)->size_t{ size_t r = off; off = (off + bytes + 255) & ~(size_t)255; return r; };
  size_t o_flag   = A(4);
  size_t o_cw     = A((size_t)CO_TOTAL*4);
  size_t o_va2    = A(D_H*4);
  size_t o_vd2    = A(D_H*4);
  size_t o_table1 = A((size_t)VOCAB*D_H*4);
  size_t o_as1    = A(VOCAB*4);
  size_t o_ad1    = A(VOCAB*4);
  size_t o_sA1    = A((size_t)N_NODES*4);
  size_t o_dA1    = A((size_t)N_NODES*4);
  size_t o_sA2    = A((size_t)N_NODES*4);
  size_t o_dA2    = A((size_t)N_NODES*4);
  size_t o_rowoff = A((size_t)N_NODES*4);
  size_t o_rowcnt = A((size_t)N_NODES*4);
  size_t o_plo    = A((size_t)N_NODES*4);
  size_t o_phi    = A((size_t)N_NODES*4);
  size_t o_gcur   = A((size_t)NB*4);
  size_t o_cbase  = A((size_t)NB*4);
  size_t o_csr    = A((size_t)N_ESL*4);
  size_t o_big    = A((size_t)N_NODES*D_H*4);   // ebuf (9.6MB) then hbuf (51.2MB)
  size_t need_b   = off;
  size_t o_agg2   = A((size_t)N_NODES*D_H*4);
  size_t need_a   = off;

  int*   flag   = (int*)(base + o_flag);
  float* cw     = (float*)(base + o_cw);
  float* va2    = (float*)(base + o_va2);
  float* vd2    = (float*)(base + o_vd2);
  float* table1 = (float*)(base + o_table1);
  float* as1    = (float*)(base + o_as1);
  float* ad1    = (float*)(base + o_ad1);
  float* sA1    = (float*)(base + o_sA1);
  float* dA1    = (float*)(base + o_dA1);
  float* sA2    = (float*)(base + o_sA2);
  float* dA2    = (float*)(base + o_dA2);
  int*   rowoff = (int*)(base + o_rowoff);
  int*   rowcnt = (int*)(base + o_rowcnt);
  float* plo    = (float*)(base + o_plo);
  float* phi    = (float*)(base + o_phi);
  int*   gcur   = (int*)(base + o_gcur);
  int*   cbase  = (int*)(base + o_cbase);
  int*   csr    = (int*)(base + o_csr);
  float* hbuf   = (float*)(base + o_big);
  unsigned* ebuf= (unsigned*)(base + o_big);    // dead before hbuf is written
  float* agg2   = (float*)(base + o_agg2);

  if (ws_size < need_b) return;         // signature: out stays 0
  bool patha = (ws_size >= need_a);

  k_detect<<<1, 64, 0, stream>>>((const unsigned*)d_in[2], flag);
  k_setup<<<352, 256, 0, stream>>>(d_in[2], d_in[3], d_in[4], d_in[5],
      d_in[6], d_in[7], d_in[8], d_in[9], d_in[10], d_in[11], d_in[12], flag, cw, va2, vd2);
  k_table1<<<VOCAB, 64, 0, stream>>>(cw, table1, as1, ad1);
  k_nodelog<<<(N_NODES+255)/256, 256, 0, stream>>>(x, as1, ad1, sA1, dA1);

  // bucketed CSR build
  hipMemsetAsync(gcur, 0, (size_t)NB*4, stream);
  k_bin<<<(N_ESL+CHUNK-1)/CHUNK, 256, 0, stream>>>(src, dst, gcur, ebuf);
  k_bscan<<<1, 1024, 0, stream>>>(gcur, cbase);
  k_group<<<NB, 256, 0, stream>>>(ebuf, gcur, cbase, csr, rowoff, rowcnt);

  int nagg = (N_NODES+3)/4;
  // layer 1: h1g -> hbuf (overwrites ebuf region), plus sA2/dA2 via va2/vd2
  k_agg<0><<<nagg, 256, 0, stream>>>(rowoff, rowcnt, csr, x, sA1, dA1, table1, cw, va2, vd2, hbuf, sA2, dA2);
  if (patha){
    k_agg<1><<<nagg, 256, 0, stream>>>(rowoff, rowcnt, csr, x, sA2, dA2, hbuf, cw, va2, vd2, agg2, nullptr, nullptr);
    k_post<<<(N_NODES+63)/64, 256, 0, stream>>>(agg2, cw, plo, phi);
  } else {
    k_matmul2<<<(N_NODES+63)/64, 256, 0, stream>>>(hbuf, cw);
    k_agg<2><<<nagg, 256, 0, stream>>>(rowoff, rowcnt, csr, x, sA2, dA2, hbuf, cw, va2, vd2, nullptr, plo, phi);
  }
  k_final<<<(N_EDGES/4+255)/256, 256, 0, stream>>>(src, dst, plo, phi, cw, flag, d_out);
}

// Round 14
// 363.058 us; speedup vs baseline: 1.0723x; 1.0207x over previous
//
#include <hip/hip_runtime.h>
#include <hip/hip_bf16.h>

#define N_NODES 100000
#define N_EDGES 1600000
#define N_ESL   1700000   // edges + self loops
#define VOCAB   1000
#define D_IN    64
#define D_H     128
#define NEG_SLOPE 0.2f

// dst-bucket binning
#define BSH   7
#define NB    782          // ceil(100000/128)
#define CAP   3072         // per-bucket capacity (mean 2174, sigma ~47)
#define CHUNK 16384

// canonical fp32 weight-table offsets (elements)
#define CO_EMB   0
#define CO_W1    64000
#define CO_AS1   72192
#define CO_AD1   72320
#define CO_B1    72448
#define CO_W2    72576
#define CO_AS2   88960
#define CO_AD2   89088
#define CO_B2    89216
#define CO_WFC   89344
#define CO_BFC   89600
#define CO_TOTAL 89601

__device__ __forceinline__ float us2f(unsigned short h){ union{unsigned v; float f;} c; c.v = ((unsigned)h)<<16; return c.f; }
__device__ __forceinline__ float gelu_f(float v){ return 0.5f*v*(1.0f + erff(v*0.7071067811865475f)); }
__device__ __forceinline__ float4 ldf4(const float* p){ return *reinterpret_cast<const float4*>(p); }
__device__ __forceinline__ void stf4(float* p, float4 v){ *reinterpret_cast<float4*>(p) = v; }

__device__ __forceinline__ float wred_sum(float v){
  #pragma unroll
  for (int m=32;m;m>>=1) v += __shfl_xor(v,m,64);
  return v;
}

// Detect whether float inputs are bf16-packed (flag=1) or fp32 (flag=0).
__global__ __launch_bounds__(64) void k_detect(const unsigned* __restrict__ w, int* __restrict__ flag){
  int t = threadIdx.x;
  float cnt = 0.f;
  #pragma unroll
  for (int i=0;i<2;++i){
    unsigned v = w[t + 64*i];
    unsigned e = (v >> 7) & 0xFFu;
    cnt += (e >= 110u && e <= 126u) ? 1.f : 0.f;
  }
  cnt = wred_sum(cnt);
  if (t==0) *flag = (cnt >= 64.f) ? 1 : 0;
}

// Blocks 0..350: canonicalize the 11 float inputs into the fp32 table cw.
// Block 351: prevec -- va2 = W2 @ a_src2 ; vd2 = W2 @ a_dst2 (reads RAW inputs).
// Arg mapping: p0=emb p1=W1 p2=as1 p3=ad1 p4=b1 p5=W2 p6=as2 p7=ad2 p8=b2 p9=Wfc p10=bfc.
__global__ __launch_bounds__(256) void k_setup(const void* p0, const void* p1, const void* p2, const void* p3,
    const void* p4, const void* p5, const void* p6, const void* p7, const void* p8,
    const void* p9, const void* p10, const int* __restrict__ flag, float* __restrict__ c,
    float* __restrict__ va2, float* __restrict__ vd2){
  int b = blockIdx.x;
  if (b == 351){
    int t = threadIdx.x;
    int r = t & 127;
    int f = *flag;
    const float* w2f = (const float*)p5;                 // p5 = W2
    const unsigned short* w2h = (const unsigned short*)p5;
    const float* af = (const float*)((t < 128) ? p6 : p7);              // as2 / ad2
    const unsigned short* ah = (const unsigned short*)((t < 128) ? p6 : p7);
    float s = 0.f;
    for (int j=0;j<D_H;++j){
      float wv = f ? us2f(w2h[r*D_H+j]) : w2f[r*D_H+j];
      float av = f ? us2f(ah[j]) : af[j];
      s = fmaf(wv, av, s);
    }
    if (t < 128) va2[r] = s; else vd2[r] = s;
    return;
  }
  int i = b*256 + threadIdx.x;
  if (i >= CO_TOTAL) return;
  const void* src; int off;
  if      (i < CO_W1 ){ src=p0;  off=i;          }
  else if (i < CO_AS1){ src=p1;  off=i-CO_W1;    }
  else if (i < CO_AD1){ src=p2;  off=i-CO_AS1;   }
  else if (i < CO_B1 ){ src=p3;  off=i-CO_AD1;   }
  else if (i < CO_W2 ){ src=p4;  off=i-CO_B1;    }
  else if (i < CO_AS2){ src=p5;  off=i-CO_W2;    }
  else if (i < CO_AD2){ src=p6;  off=i-CO_AS2;   }
  else if (i < CO_B2 ){ src=p7;  off=i-CO_AD2;   }
  else if (i < CO_WFC){ src=p8;  off=i-CO_B2;    }
  else if (i < CO_BFC){ src=p9;  off=i-CO_WFC;   }
  else               { src=p10; off=i-CO_BFC;   }
  float v = (*flag) ? us2f(((const unsigned short*)src)[off]) : ((const float*)src)[off];
  c[i] = v;
}

// table1[v][:] = emb[v] @ W1 ; as1[v]/ad1[v] = attention dots
__global__ __launch_bounds__(64) void k_table1(const float* __restrict__ cw,
    float* __restrict__ table1, float* __restrict__ as1, float* __restrict__ ad1){
  const float* emb = cw + CO_EMB;
  const float* W1  = cw + CO_W1;
  int v = blockIdx.x; int t = threadIdx.x;
  __shared__ float er[D_IN];
  er[t] = emb[v*D_IN + t];
  __syncthreads();
  int d0 = t, d1 = t + 64;
  float a0 = 0.f, a1 = 0.f;
  for (int k=0;k<D_IN;++k){
    float e = er[k];
    a0 = fmaf(e, W1[k*D_H+d0], a0);
    a1 = fmaf(e, W1[k*D_H+d1], a1);
  }
  table1[v*D_H+d0] = a0; table1[v*D_H+d1] = a1;
  float ps = a0*cw[CO_AS1+d0] + a1*cw[CO_AS1+d1];
  float pd = a0*cw[CO_AD1+d0] + a1*cw[CO_AD1+d1];
  ps = wred_sum(ps); pd = wred_sum(pd);
  if (t==0){ as1[v]=ps; ad1[v]=pd; }
}

__global__ void k_nodelog(const int* __restrict__ x, const float* __restrict__ as1,
    const float* __restrict__ ad1, float* __restrict__ sA1, float* __restrict__ dA1){
  int i = blockIdx.x*blockDim.x + threadIdx.x;
  if (i < N_NODES){ int xs = x[i]; sA1[i] = as1[xs]; dA1[i] = ad1[xs]; }
}

// ---- bucketed CSR build ----
// N_EDGES and CHUNK are multiples of 4, so every aligned int4 group is
// entirely real-edge or entirely self-loop.
__global__ __launch_bounds__(256) void k_bin(const int* __restrict__ src,
    const int* __restrict__ dst, int* __restrict__ gcur, unsigned* __restrict__ ebuf){
  __shared__ int hist[NB];
  __shared__ int cur[NB];
  int tid = threadIdx.x;
  int base0 = blockIdx.x * CHUNK;
  int n = N_ESL - base0; if (n > CHUNK) n = CHUNK;
  for (int i=tid; i<NB; i+=256) hist[i] = 0;
  __syncthreads();
  for (int k = tid*4; k < n; k += 1024){
    int e = base0 + k;
    int4 d4;
    if (e + 4 <= N_EDGES) d4 = *reinterpret_cast<const int4*>(dst + e);
    else d4 = make_int4(e-N_EDGES, e+1-N_EDGES, e+2-N_EDGES, e+3-N_EDGES);
    atomicAdd(&hist[d4.x>>BSH], 1);
    atomicAdd(&hist[d4.y>>BSH], 1);
    atomicAdd(&hist[d4.z>>BSH], 1);
    atomicAdd(&hist[d4.w>>BSH], 1);
  }
  __syncthreads();
  for (int b=tid; b<NB; b+=256){
    int c = hist[b];
    cur[b] = c ? atomicAdd(&gcur[b], c) : 0;
  }
  __syncthreads();
  for (int k = tid*4; k < n; k += 1024){
    int e = base0 + k;
    int4 d4, s4;
    if (e + 4 <= N_EDGES){
      d4 = *reinterpret_cast<const int4*>(dst + e);
      s4 = *reinterpret_cast<const int4*>(src + e);
    } else {
      d4 = make_int4(e-N_EDGES, e+1-N_EDGES, e+2-N_EDGES, e+3-N_EDGES);
      s4 = d4;
    }
    int p0 = atomicAdd(&cur[d4.x>>BSH], 1);
    if (p0 < CAP) ebuf[(size_t)(d4.x>>BSH)*CAP + p0] = (unsigned)(((d4.x & 127) << 17) | s4.x);
    int p1 = atomicAdd(&cur[d4.y>>BSH], 1);
    if (p1 < CAP) ebuf[(size_t)(d4.y>>BSH)*CAP + p1] = (unsigned)(((d4.y & 127) << 17) | s4.y);
    int p2 = atomicAdd(&cur[d4.z>>BSH], 1);
    if (p2 < CAP) ebuf[(size_t)(d4.z>>BSH)*CAP + p2] = (unsigned)(((d4.z & 127) << 17) | s4.z);
    int p3 = atomicAdd(&cur[d4.w>>BSH], 1);
    if (p3 < CAP) ebuf[(size_t)(d4.w>>BSH)*CAP + p3] = (unsigned)(((d4.w & 127) << 17) | s4.w);
  }
}

__global__ __launch_bounds__(1024) void k_bscan(const int* __restrict__ gcur, int* __restrict__ csrbase){
  int t = threadIdx.x, lane = t & 63, wid = t >> 6;
  int c = (t < NB) ? gcur[t] : 0;
  if (c > CAP) c = CAP;
  int v = c;
  #pragma unroll
  for (int m=1;m<64;m<<=1){ int u = __shfl_up(v,m,64); if (lane>=m) v += u; }
  __shared__ int wsum[16], woff[16];
  if (lane==63) wsum[wid] = v;
  __syncthreads();
  if (t==0){ int run=0; for (int w=0;w<16;++w){ woff[w]=run; run+=wsum[w]; } }
  __syncthreads();
  v += woff[wid];
  if (t < NB) csrbase[t] = v - c;
}

__global__ __launch_bounds__(256) void k_group(const unsigned* __restrict__ ebuf,
    const int* __restrict__ gcur, const int* __restrict__ csrbase,
    int* __restrict__ csr, int* __restrict__ rowoff, int* __restrict__ rowcnt){
  __shared__ unsigned stage[CAP];
  __shared__ int hist[128], cur[128];
  __shared__ int wtot;
  int b = blockIdx.x, tid = threadIdx.x;
  int n = gcur[b]; if (n > CAP) n = CAP;
  int nodeBase = b << BSH;
  int cbase = csrbase[b];
  if (tid < 128) hist[tid] = 0;
  __syncthreads();
  int nv = n & ~3;
  for (int k = tid*4; k < nv; k += 1024){
    uint4 q = *reinterpret_cast<const uint4*>(ebuf + (size_t)b*CAP + k);
    stage[k]   = q.x; atomicAdd(&hist[q.x >> 17], 1);
    stage[k+1] = q.y; atomicAdd(&hist[q.y >> 17], 1);
    stage[k+2] = q.z; atomicAdd(&hist[q.z >> 17], 1);
    stage[k+3] = q.w; atomicAdd(&hist[q.w >> 17], 1);
  }
  for (int k = nv + tid; k < n; k += 256){
    unsigned p = ebuf[(size_t)b*CAP + k];
    stage[k] = p;
    atomicAdd(&hist[p >> 17], 1);
  }
  __syncthreads();
  // parallel exclusive scan of hist[0..127] (two waves + carry)
  int v128 = 0;
  if (tid < 128){
    int lane = tid & 63;
    v128 = hist[tid];
    #pragma unroll
    for (int m=1;m<64;m<<=1){ int u = __shfl_up(v128,m,64); if (lane>=m) v128 += u; }
    if (tid == 63) wtot = v128;
  }
  __syncthreads();
  if (tid < 128){
    int incl = v128 + ((tid >= 64) ? wtot : 0);
    int excl = incl - hist[tid];
    int d = nodeBase + tid;
    if (d < N_NODES){ rowoff[d] = cbase + excl; rowcnt[d] = hist[tid]; }
    cur[tid] = excl;
  }
  __syncthreads();
  for (int k=tid; k<n; k+=256){
    unsigned p = stage[k];
    int pos = atomicAdd(&cur[p >> 17], 1);
    csr[cbase + pos] = (int)(p & 0x1FFFFu);
  }
}

// One wave per dst node. MODE 0: layer-1 (gather table1[x[s]]; store h1g + sA2/dA2 dots).
// MODE 1: layer-2 raw (gather hbuf[s]; store raw weighted sum). MODE 2: layer-2 direct.
// Fast path (deg<=64, ~100% of nodes): split max/sum softmax (ONE expf per lane),
// then (w,rb) staged in per-wave LDS scratch; weight loop = one broadcast
// ds_read_b64 per edge. Half-split point is a MULTIPLE OF 4 so the unguarded
// 4-wide tail never crosses into the other half (round-13 bug fix); overruns
// land on zero-weight entries ([nj,64)) or the 4 zero pads (64..67).
template<int MODE>
__global__ __launch_bounds__(256) void k_agg(const int* __restrict__ rowoff,
    const int* __restrict__ rowcnt, const int* __restrict__ csr_src, const int* __restrict__ x,
    const float* __restrict__ sa, const float* __restrict__ danode,
    const float* __restrict__ feat, const float* __restrict__ cw,
    const float* __restrict__ va2, const float* __restrict__ vd2,
    float* __restrict__ out_h, float* __restrict__ p_lo, float* __restrict__ p_hi){
  __shared__ float2 wrb[4][68];     // 64 entries + 4 zero pads per wave
  int lane = threadIdx.x & 63;
  int wid  = threadIdx.x >> 6;
  int node = blockIdx.x*4 + wid;
  if (node >= N_NODES) return;
  int start = rowoff[node];
  int nj = rowcnt[node];
  int end = start + nj;
  float dA = danode[node];

  int c0 = (lane & 31)*4, half = lane >> 5;
  float a0=0.f, a1=0.f, a2=0.f, a3=0.f;

  if (nj <= 64){
    // ---- fast path ----
    int p = start + lane;
    bool act = p < end;
    int s = 0; float l = -1e30f; int rb_sav = 0;
    if (act){
      s = csr_src[p];
      l = sa[s] + dA; l = (l > 0.f) ? l : NEG_SLOPE*l;
      rb_sav = (MODE == 0 ? x[s] : s) * D_H;
    }
    float mxv = l;
    #pragma unroll
    for (int off=32; off; off>>=1) mxv = fmaxf(mxv, __shfl_xor(mxv, off, 64));
    float e = act ? expf(l - mxv) : 0.f;
    float ssum = e;
    #pragma unroll
    for (int off=32; off; off>>=1) ssum += __shfl_xor(ssum, off, 64);
    float inv = 1.0f/(ssum + 1e-16f);
    wrb[wid][lane] = make_float2(e*inv, __int_as_float(rb_sav));
    if (lane < 4) wrb[wid][64+lane] = make_float2(0.f, 0.f);

    int mid = ((nj >> 1) + 2) & ~3;          // multiple of 4, 0 <= mid <= nj
    int lo = half ? mid : 0;
    int hi = half ? nj : mid;
    for (int j = lo; j < hi; j += 4){
      float2 q0 = wrb[wid][j],   q1 = wrb[wid][j+1];
      float2 q2 = wrb[wid][j+2], q3 = wrb[wid][j+3];
      float4 f0 = ldf4(feat + __float_as_int(q0.y) + c0);
      float4 f1 = ldf4(feat + __float_as_int(q1.y) + c0);
      float4 f2 = ldf4(feat + __float_as_int(q2.y) + c0);
      float4 f3 = ldf4(feat + __float_as_int(q3.y) + c0);
      a0 = fmaf(q0.x, f0.x, a0); a1 = fmaf(q0.x, f0.y, a1);
      a2 = fmaf(q0.x, f0.z, a2); a3 = fmaf(q0.x, f0.w, a3);
      a0 = fmaf(q1.x, f1.x, a0); a1 = fmaf(q1.x, f1.y, a1);
      a2 = fmaf(q1.x, f1.z, a2); a3 = fmaf(q1.x, f1.w, a3);
      a0 = fmaf(q2.x, f2.x, a0); a1 = fmaf(q2.x, f2.y, a1);
      a2 = fmaf(q2.x, f2.z, a2); a3 = fmaf(q2.x, f2.w, a3);
      a0 = fmaf(q3.x, f3.x, a0); a1 = fmaf(q3.x, f3.y, a1);
      a2 = fmaf(q3.x, f3.z, a2); a3 = fmaf(q3.x, f3.w, a3);
    }
  } else {
    // ---- slow path (deg > 64; essentially never for Poisson(17)) ----
    float m = -1e30f, ss = 0.f;
    for (int p = start + lane; p < end; p += 64){
      int s = csr_src[p];
      float l = sa[s] + dA; l = (l > 0.f) ? l : NEG_SLOPE*l;
      float mn = fmaxf(m, l);
      ss = ss*expf(m-mn) + expf(l-mn);
      m = mn;
    }
    #pragma unroll
    for (int off=32; off; off>>=1){
      float mo = __shfl_xor(m, off, 64);
      float so = __shfl_xor(ss, off, 64);
      float mn = fmaxf(m, mo);
      ss = ss*expf(m-mn) + so*expf(mo-mn);
      m = mn;
    }
    float mx = m;
    float inv = 1.0f/(ss + 1e-16f);

    for (int t0 = start; t0 < end; t0 += 64){
      int p = t0 + lane;
      float w = 0.f; int rb = 0;
      if (p < end){
        int s = csr_src[p];
        float l = sa[s] + dA; l = (l > 0.f) ? l : NEG_SLOPE*l;
        w = expf(l - mx)*inv;
        rb = (MODE == 0 ? x[s] : s) * D_H;
      }
      int cnt = end - t0; if (cnt > 64) cnt = 64;
      int mid = (cnt + 1) >> 1;
      int lo = half ? mid : 0;
      int hi = half ? cnt : mid;
      for (int j = lo; j < hi; j += 4){
        int nh = hi - j;
        float w0 = __shfl(w,  j,   64), w1 = __shfl(w,  j+1, 64);
        float w2 = __shfl(w,  j+2, 64), w3 = __shfl(w,  j+3, 64);
        int   r0 = __shfl(rb, j,   64), r1 = __shfl(rb, j+1, 64);
        int   r2 = __shfl(rb, j+2, 64), r3 = __shfl(rb, j+3, 64);
        float4 f0 = make_float4(0.f,0.f,0.f,0.f), f1 = f0, f2 = f0, f3 = f0;
        f0 = ldf4(feat + r0 + c0);
        if (nh > 1) f1 = ldf4(feat + r1 + c0);
        if (nh > 2) f2 = ldf4(feat + r2 + c0);
        if (nh > 3) f3 = ldf4(feat + r3 + c0);
        a0 = fmaf(w0, f0.x, a0); a1 = fmaf(w0, f0.y, a1);
        a2 = fmaf(w0, f0.z, a2); a3 = fmaf(w0, f0.w, a3);
        a0 = fmaf(w1, f1.x, a0); a1 = fmaf(w1, f1.y, a1);
        a2 = fmaf(w1, f1.z, a2); a3 = fmaf(w1, f1.w, a3);
        a0 = fmaf(w2, f2.x, a0); a1 = fmaf(w2, f2.y, a1);
        a2 = fmaf(w2, f2.z, a2); a3 = fmaf(w2, f2.w, a3);
        a0 = fmaf(w3, f3.x, a0); a1 = fmaf(w3, f3.y, a1);
        a2 = fmaf(w3, f3.z, a2); a3 = fmaf(w3, f3.w, a3);
      }
    }
  }

  a0 += __shfl_xor(a0,32,64); a1 += __shfl_xor(a1,32,64);
  a2 += __shfl_xor(a2,32,64); a3 += __shfl_xor(a3,32,64);

  if (MODE == 0){
    float o0 = gelu_f(a0 + cw[CO_B1+c0]);
    float o1 = gelu_f(a1 + cw[CO_B1+c0+1]);
    float o2 = gelu_f(a2 + cw[CO_B1+c0+2]);
    float o3 = gelu_f(a3 + cw[CO_B1+c0+3]);
    if (!half) stf4(out_h + (size_t)node*D_H + c0, make_float4(o0,o1,o2,o3));
    float pl = o0*va2[c0] + o1*va2[c0+1] + o2*va2[c0+2] + o3*va2[c0+3];
    float ph = o0*vd2[c0] + o1*vd2[c0+1] + o2*vd2[c0+2] + o3*vd2[c0+3];
    #pragma unroll
    for (int off=16; off; off>>=1){ pl += __shfl_xor(pl,off,64); ph += __shfl_xor(ph,off,64); }
    if (lane == 0){ p_lo[node] = pl; p_hi[node] = ph; }   // = sA2, dA2
  } else if (MODE == 1){
    if (!half) stf4(out_h + (size_t)node*D_H + c0, make_float4(a0,a1,a2,a3));
  } else {
    float o0 = gelu_f(a0 + cw[CO_B2+c0]);
    float o1 = gelu_f(a1 + cw[CO_B2+c0+1]);
    float o2 = gelu_f(a2 + cw[CO_B2+c0+2]);
    float o3 = gelu_f(a3 + cw[CO_B2+c0+3]);
    float pl = o0*cw[CO_WFC+c0]     + o1*cw[CO_WFC+c0+1]
             + o2*cw[CO_WFC+c0+2]   + o3*cw[CO_WFC+c0+3];
    float ph = o0*cw[CO_WFC+D_H+c0]   + o1*cw[CO_WFC+D_H+c0+1]
             + o2*cw[CO_WFC+D_H+c0+2] + o3*cw[CO_WFC+D_H+c0+3];
    #pragma unroll
    for (int off=16; off; off>>=1){ pl += __shfl_xor(pl,off,64); ph += __shfl_xor(ph,off,64); }
    if (lane == 0){ p_lo[node] = pl; p_hi[node] = ph; }
  }
}

// Path a: p_lo/p_hi = gelu(agg2@W2 + b2) . Wfc halves. (LDS-staged matmul)
__global__ __launch_bounds__(256) void k_post(const float* __restrict__ agg2,
    const float* __restrict__ cw, float* __restrict__ p_lo, float* __restrict__ p_hi){
  __shared__ float xr[64][D_H];   // 32 KB
  __shared__ float W[64][D_H];    // 32 KB
  const float* W2 = cw + CO_W2;
  int tid = threadIdx.x;
  int cg = tid & 31;
  int rg = tid >> 5;
  int base = blockIdx.x * 64;

  for (int i = tid; i < 64*D_H/4; i += 256){
    int row = i >> 5, c4 = (i & 31) * 4;
    int rr = base + row;
    float4 v = (rr < N_NODES) ? ldf4(agg2 + (size_t)rr*D_H + c4) : make_float4(0.f,0.f,0.f,0.f);
    stf4(&xr[row][c4], v);
  }

  float4 acc[8];
  #pragma unroll
  for (int rs=0; rs<8; ++rs) acc[rs] = make_float4(0.f,0.f,0.f,0.f);

  #pragma unroll
  for (int hk = 0; hk < 2; ++hk){
    __syncthreads();
    for (int i = tid; i < 64*D_H/4; i += 256){
      int k = i >> 5, c4 = (i & 31) * 4;
      stf4(&W[k][c4], ldf4(W2 + (size_t)(hk*64 + k)*D_H + c4));
    }
    __syncthreads();
    for (int k = 0; k < 64; ++k){
      float4 wv = ldf4(&W[k][cg*4]);
      int kk = hk*64 + k;
      #pragma unroll
      for (int rs = 0; rs < 8; ++rs){
        float xv = xr[rs*8 + rg][kk];
        acc[rs].x = fmaf(xv, wv.x, acc[rs].x);
        acc[rs].y = fmaf(xv, wv.y, acc[rs].y);
        acc[rs].z = fmaf(xv, wv.z, acc[rs].z);
        acc[rs].w = fmaf(xv, wv.w, acc[rs].w);
      }
    }
  }

  float4 b2v = ldf4(cw + CO_B2  + cg*4);
  float4 wlo = ldf4(cw + CO_WFC + cg*4);
  float4 whi = ldf4(cw + CO_WFC + D_H + cg*4);
  #pragma unroll
  for (int rs = 0; rs < 8; ++rs){
    int rr = base + rs*8 + rg;
    float o0 = gelu_f(acc[rs].x + b2v.x);
    float o1 = gelu_f(acc[rs].y + b2v.y);
    float o2 = gelu_f(acc[rs].z + b2v.z);
    float o3 = gelu_f(acc[rs].w + b2v.w);
    float pl = o0*wlo.x + o1*wlo.y + o2*wlo.z + o3*wlo.w;
    float ph = o0*whi.x + o1*whi.y + o2*whi.z + o3*whi.w;
    #pragma unroll
    for (int off=16; off; off>>=1){ pl += __shfl_xor(pl,off,64); ph += __shfl_xor(ph,off,64); }
    if (cg == 0 && rr < N_NODES){ p_lo[rr] = pl; p_hi[rr] = ph; }
  }
}

// Path b fallback: hbuf = hbuf @ W2 in place per 64-row block.
__global__ __launch_bounds__(256) void k_matmul2(float* __restrict__ hbuf, const float* __restrict__ cw){
  const float* W2 = cw + CO_W2;
  __shared__ float xr[16][D_H];
  int tid = threadIdx.x;
  int col = tid & 127, half = tid >> 7;
  int base = blockIdx.x * 64;
  for (int t0=0; t0<64; t0+=16){
    int r0 = base + t0;
    for (int i=tid; i<16*D_H; i+=256){
      int rr = r0 + (i>>7);
      xr[i>>7][i&127] = (rr < N_NODES) ? hbuf[(size_t)rr*D_H + (i&127)] : 0.f;
    }
    __syncthreads();
    float acc[8];
    #pragma unroll
    for (int r=0;r<8;++r) acc[r] = 0.f;
    int rb = half*8;
    for (int k=0;k<D_H;++k){
      float wv = W2[k*D_H + col];
      #pragma unroll
      for (int r=0;r<8;++r) acc[r] = fmaf(xr[rb+r][k], wv, acc[r]);
    }
    #pragma unroll
    for (int r=0;r<8;++r){
      int rr = r0 + rb + r;
      if (rr < N_NODES) hbuf[(size_t)rr*D_H + col] = acc[r];
    }
    __syncthreads();
  }
}

// 4 edges per thread, vectorized int4 reads of src/dst.
__global__ void k_final(const int* __restrict__ src, const int* __restrict__ dst,
    const float* __restrict__ p_lo, const float* __restrict__ p_hi,
    const float* __restrict__ cw, const int* __restrict__ flag, void* __restrict__ out){
  int q = blockIdx.x*blockDim.x + threadIdx.x;
  int e0 = q*4;
  if (e0 >= N_EDGES) return;
  float bfc = cw[CO_BFC];
  if (e0 + 4 <= N_EDGES){
    int4 s4 = *reinterpret_cast<const int4*>(src + e0);
    int4 d4 = *reinterpret_cast<const int4*>(dst + e0);
    float4 v;
    v.x = gelu_f(p_lo[s4.x] + p_hi[d4.x] + bfc);
    v.y = gelu_f(p_lo[s4.y] + p_hi[d4.y] + bfc);
    v.z = gelu_f(p_lo[s4.z] + p_hi[d4.z] + bfc);
    v.w = gelu_f(p_lo[s4.w] + p_hi[d4.w] + bfc);
    if (*flag){
      __hip_bfloat16* o = (__hip_bfloat16*)out + e0;
      o[0]=__float2bfloat16(v.x); o[1]=__float2bfloat16(v.y);
      o[2]=__float2bfloat16(v.z); o[3]=__float2bfloat16(v.w);
    } else {
      stf4((float*)out + e0, v);
    }
  } else {
    for (int e = e0; e < N_EDGES; ++e){
      float v = gelu_f(p_lo[src[e]] + p_hi[dst[e]] + bfc);
      if (*flag) ((__hip_bfloat16*)out)[e] = __float2bfloat16(v);
      else       ((float*)out)[e] = v;
    }
  }
}

extern "C" void kernel_launch(void* const* d_in, const int* in_sizes, int n_in,
                              void* d_out, int out_size, void* d_ws, size_t ws_size,
                              hipStream_t stream){
  (void)in_sizes; (void)n_in; (void)out_size;
  const int* x  = (const int*)d_in[0];
  const int* ei = (const int*)d_in[1];
  const int* src = ei;
  const int* dst = ei + N_EDGES;

  // ---- workspace layout ----
  char* base = (char*)d_ws;
  size_t off = 0;
  auto A = [&](size_t bytes)->size_t{ size_t r = off; off = (off + bytes + 255) & ~(size_t)255; return r; };
  size_t o_flag   = A(4);
  size_t o_cw     = A((size_t)CO_TOTAL*4);
  size_t o_va2    = A(D_H*4);
  size_t o_vd2    = A(D_H*4);
  size_t o_table1 = A((size_t)VOCAB*D_H*4);
  size_t o_as1    = A(VOCAB*4);
  size_t o_ad1    = A(VOCAB*4);
  size_t o_sA1    = A((size_t)N_NODES*4);
  size_t o_dA1    = A((size_t)N_NODES*4);
  size_t o_sA2    = A((size_t)N_NODES*4);
  size_t o_dA2    = A((size_t)N_NODES*4);
  size_t o_rowoff = A((size_t)N_NODES*4);
  size_t o_rowcnt = A((size_t)N_NODES*4);
  size_t o_plo    = A((size_t)N_NODES*4);
  size_t o_phi    = A((size_t)N_NODES*4);
  size_t o_gcur   = A((size_t)NB*4);
  size_t o_cbase  = A((size_t)NB*4);
  size_t o_csr    = A((size_t)N_ESL*4);
  size_t o_big    = A((size_t)N_NODES*D_H*4);   // ebuf (9.6MB) then hbuf (51.2MB)
  size_t need_b   = off;
  size_t o_agg2   = A((size_t)N_NODES*D_H*4);
  size_t need_a   = off;

  int*   flag   = (int*)(base + o_flag);
  float* cw     = (float*)(base + o_cw);
  float* va2    = (float*)(base + o_va2);
  float* vd2    = (float*)(base + o_vd2);
  float* table1 = (float*)(base + o_table1);
  float* as1    = (float*)(base + o_as1);
  float* ad1    = (float*)(base + o_ad1);
  float* sA1    = (float*)(base + o_sA1);
  float* dA1    = (float*)(base + o_dA1);
  float* sA2    = (float*)(base + o_sA2);
  float* dA2    = (float*)(base + o_dA2);
  int*   rowoff = (int*)(base + o_rowoff);
  int*   rowcnt = (int*)(base + o_rowcnt);
  float* plo    = (float*)(base + o_plo);
  float* phi    = (float*)(base + o_phi);
  int*   gcur   = (int*)(base + o_gcur);
  int*   cbase  = (int*)(base + o_cbase);
  int*   csr    = (int*)(base + o_csr);
  float* hbuf   = (float*)(base + o_big);
  unsigned* ebuf= (unsigned*)(base + o_big);    // dead before hbuf is written
  float* agg2   = (float*)(base + o_agg2);

  if (ws_size < need_b) return;         // signature: out stays 0
  bool patha = (ws_size >= need_a);

  k_detect<<<1, 64, 0, stream>>>((const unsigned*)d_in[2], flag);
  k_setup<<<352, 256, 0, stream>>>(d_in[2], d_in[3], d_in[4], d_in[5],
      d_in[6], d_in[7], d_in[8], d_in[9], d_in[10], d_in[11], d_in[12], flag, cw, va2, vd2);
  k_table1<<<VOCAB, 64, 0, stream>>>(cw, table1, as1, ad1);
  k_nodelog<<<(N_NODES+255)/256, 256, 0, stream>>>(x, as1, ad1, sA1, dA1);

  // bucketed CSR build
  hipMemsetAsync(gcur, 0, (size_t)NB*4, stream);
  k_bin<<<(N_ESL+CHUNK-1)/CHUNK, 256, 0, stream>>>(src, dst, gcur, ebuf);
  k_bscan<<<1, 1024, 0, stream>>>(gcur, cbase);
  k_group<<<NB, 256, 0, stream>>>(ebuf, gcur, cbase, csr, rowoff, rowcnt);

  int nagg = (N_NODES+3)/4;
  // layer 1: h1g -> hbuf (overwrites ebuf region), plus sA2/dA2 via va2/vd2
  k_agg<0><<<nagg, 256, 0, stream>>>(rowoff, rowcnt, csr, x, sA1, dA1, table1, cw, va2, vd2, hbuf, sA2, dA2);
  if (patha){
    k_agg<1><<<nagg, 256, 0, stream>>>(rowoff, rowcnt, csr, x, sA2, dA2, hbuf, cw, va2, vd2, agg2, nullptr, nullptr);
    k_post<<<(N_NODES+63)/64, 256, 0, stream>>>(agg2, cw, plo, phi);
  } else {
    k_matmul2<<<(N_NODES+63)/64, 256, 0, stream>>>(hbuf, cw);
    k_agg<2><<<nagg, 256, 0, stream>>>(rowoff, rowcnt, csr, x, sA2, dA2, hbuf, cw, va2, vd2, nullptr, plo, phi);
  }
  k_final<<<(N_EDGES/4+255)/256, 256, 0, stream>>>(src, dst, plo, phi, cw, flag, d_out);
}

// Round 15
// 354.066 us; speedup vs baseline: 1.0995x; 1.0254x over previous
//
#include <hip/hip_runtime.h>
#include <hip/hip_bf16.h>

#define N_NODES 100000
#define N_EDGES 1600000
#define N_ESL   1700000   // edges + self loops
#define VOCAB   1000
#define D_IN    64
#define D_H     128
#define NEG_SLOPE 0.2f

// dst-bucket binning
#define BSH   7
#define NB    782          // ceil(100000/128)
#define CAP   3072         // per-bucket capacity (mean 2174, sigma ~47)
#define CHUNK 16384

// canonical fp32 weight-table offsets (elements)
#define CO_EMB   0
#define CO_W1    64000
#define CO_AS1   72192
#define CO_AD1   72320
#define CO_B1    72448
#define CO_W2    72576
#define CO_AS2   88960
#define CO_AD2   89088
#define CO_B2    89216
#define CO_WFC   89344
#define CO_BFC   89600
#define CO_TOTAL 89601

__device__ __forceinline__ float us2f(unsigned short h){ union{unsigned v; float f;} c; c.v = ((unsigned)h)<<16; return c.f; }
__device__ __forceinline__ float gelu_f(float v){ return 0.5f*v*(1.0f + erff(v*0.7071067811865475f)); }
__device__ __forceinline__ float4 ldf4(const float* p){ return *reinterpret_cast<const float4*>(p); }
__device__ __forceinline__ void stf4(float* p, float4 v){ *reinterpret_cast<float4*>(p) = v; }

__device__ __forceinline__ float wred_sum(float v){
  #pragma unroll
  for (int m=32;m;m>>=1) v += __shfl_xor(v,m,64);
  return v;
}

// Detect bf16-packed (flag=1) vs fp32 (flag=0) inputs; also zero gcur.
__global__ __launch_bounds__(64) void k_detect(const unsigned* __restrict__ w, int* __restrict__ flag,
    int* __restrict__ gcur){
  int t = threadIdx.x;
  for (int i=t; i<NB; i+=64) gcur[i] = 0;
  float cnt = 0.f;
  #pragma unroll
  for (int i=0;i<2;++i){
    unsigned v = w[t + 64*i];
    unsigned e = (v >> 7) & 0xFFu;
    cnt += (e >= 110u && e <= 126u) ? 1.f : 0.f;
  }
  cnt = wred_sum(cnt);
  if (t==0) *flag = (cnt >= 64.f) ? 1 : 0;
}

// Blocks 0..350: canonicalize the 11 float inputs into the fp32 table cw.
// Block 351: prevec -- va2 = W2 @ a_src2 ; vd2 = W2 @ a_dst2 (reads RAW inputs).
// Arg mapping: p0=emb p1=W1 p2=as1 p3=ad1 p4=b1 p5=W2 p6=as2 p7=ad2 p8=b2 p9=Wfc p10=bfc.
__global__ __launch_bounds__(256) void k_setup(const void* p0, const void* p1, const void* p2, const void* p3,
    const void* p4, const void* p5, const void* p6, const void* p7, const void* p8,
    const void* p9, const void* p10, const int* __restrict__ flag, float* __restrict__ c,
    float* __restrict__ va2, float* __restrict__ vd2){
  int b = blockIdx.x;
  if (b == 351){
    int t = threadIdx.x;
    int r = t & 127;
    int f = *flag;
    const float* w2f = (const float*)p5;                 // p5 = W2
    const unsigned short* w2h = (const unsigned short*)p5;
    const float* af = (const float*)((t < 128) ? p6 : p7);              // as2 / ad2
    const unsigned short* ah = (const unsigned short*)((t < 128) ? p6 : p7);
    float s = 0.f;
    for (int j=0;j<D_H;++j){
      float wv = f ? us2f(w2h[r*D_H+j]) : w2f[r*D_H+j];
      float av = f ? us2f(ah[j]) : af[j];
      s = fmaf(wv, av, s);
    }
    if (t < 128) va2[r] = s; else vd2[r] = s;
    return;
  }
  int i = b*256 + threadIdx.x;
  if (i >= CO_TOTAL) return;
  const void* src; int off;
  if      (i < CO_W1 ){ src=p0;  off=i;          }
  else if (i < CO_AS1){ src=p1;  off=i-CO_W1;    }
  else if (i < CO_AD1){ src=p2;  off=i-CO_AS1;   }
  else if (i < CO_B1 ){ src=p3;  off=i-CO_AD1;   }
  else if (i < CO_W2 ){ src=p4;  off=i-CO_B1;    }
  else if (i < CO_AS2){ src=p5;  off=i-CO_W2;    }
  else if (i < CO_AD2){ src=p6;  off=i-CO_AS2;   }
  else if (i < CO_B2 ){ src=p7;  off=i-CO_AD2;   }
  else if (i < CO_WFC){ src=p8;  off=i-CO_B2;    }
  else if (i < CO_BFC){ src=p9;  off=i-CO_WFC;   }
  else               { src=p10; off=i-CO_BFC;   }
  float v = (*flag) ? us2f(((const unsigned short*)src)[off]) : ((const float*)src)[off];
  c[i] = v;
}

// table1[v][:] = emb[v] @ W1 ; as1[v]/ad1[v] = attention dots
__global__ __launch_bounds__(64) void k_table1(const float* __restrict__ cw,
    float* __restrict__ table1, float* __restrict__ as1, float* __restrict__ ad1){
  const float* emb = cw + CO_EMB;
  const float* W1  = cw + CO_W1;
  int v = blockIdx.x; int t = threadIdx.x;
  __shared__ float er[D_IN];
  er[t] = emb[v*D_IN + t];
  __syncthreads();
  int d0 = t, d1 = t + 64;
  float a0 = 0.f, a1 = 0.f;
  for (int k=0;k<D_IN;++k){
    float e = er[k];
    a0 = fmaf(e, W1[k*D_H+d0], a0);
    a1 = fmaf(e, W1[k*D_H+d1], a1);
  }
  table1[v*D_H+d0] = a0; table1[v*D_H+d1] = a1;
  float ps = a0*cw[CO_AS1+d0] + a1*cw[CO_AS1+d1];
  float pd = a0*cw[CO_AD1+d0] + a1*cw[CO_AD1+d1];
  ps = wred_sum(ps); pd = wred_sum(pd);
  if (t==0){ as1[v]=ps; ad1[v]=pd; }
}

// g1[i] = (as1[x[i]], bits(x[i]*D_H)); dA1[i] = ad1[x[i]]
__global__ void k_nodelog(const int* __restrict__ x, const float* __restrict__ as1,
    const float* __restrict__ ad1, float2* __restrict__ g1, float* __restrict__ dA1){
  int i = blockIdx.x*blockDim.x + threadIdx.x;
  if (i < N_NODES){
    int xs = x[i];
    g1[i] = make_float2(as1[xs], __int_as_float(xs * D_H));
    dA1[i] = ad1[xs];
  }
}

// ---- bucketed CSR build ----
__global__ __launch_bounds__(256) void k_bin(const int* __restrict__ src,
    const int* __restrict__ dst, int* __restrict__ gcur, unsigned* __restrict__ ebuf){
  __shared__ int hist[NB];
  __shared__ int cur[NB];
  int tid = threadIdx.x;
  int base0 = blockIdx.x * CHUNK;
  int n = N_ESL - base0; if (n > CHUNK) n = CHUNK;
  for (int i=tid; i<NB; i+=256) hist[i] = 0;
  __syncthreads();
  for (int k = tid*4; k < n; k += 1024){
    int e = base0 + k;
    int4 d4;
    if (e + 4 <= N_EDGES) d4 = *reinterpret_cast<const int4*>(dst + e);
    else d4 = make_int4(e-N_EDGES, e+1-N_EDGES, e+2-N_EDGES, e+3-N_EDGES);
    atomicAdd(&hist[d4.x>>BSH], 1);
    atomicAdd(&hist[d4.y>>BSH], 1);
    atomicAdd(&hist[d4.z>>BSH], 1);
    atomicAdd(&hist[d4.w>>BSH], 1);
  }
  __syncthreads();
  for (int b=tid; b<NB; b+=256){
    int c = hist[b];
    cur[b] = c ? atomicAdd(&gcur[b], c) : 0;
  }
  __syncthreads();
  for (int k = tid*4; k < n; k += 1024){
    int e = base0 + k;
    int4 d4, s4;
    if (e + 4 <= N_EDGES){
      d4 = *reinterpret_cast<const int4*>(dst + e);
      s4 = *reinterpret_cast<const int4*>(src + e);
    } else {
      d4 = make_int4(e-N_EDGES, e+1-N_EDGES, e+2-N_EDGES, e+3-N_EDGES);
      s4 = d4;
    }
    int p0 = atomicAdd(&cur[d4.x>>BSH], 1);
    if (p0 < CAP) ebuf[(size_t)(d4.x>>BSH)*CAP + p0] = (unsigned)(((d4.x & 127) << 17) | s4.x);
    int p1 = atomicAdd(&cur[d4.y>>BSH], 1);
    if (p1 < CAP) ebuf[(size_t)(d4.y>>BSH)*CAP + p1] = (unsigned)(((d4.y & 127) << 17) | s4.y);
    int p2 = atomicAdd(&cur[d4.z>>BSH], 1);
    if (p2 < CAP) ebuf[(size_t)(d4.z>>BSH)*CAP + p2] = (unsigned)(((d4.z & 127) << 17) | s4.z);
    int p3 = atomicAdd(&cur[d4.w>>BSH], 1);
    if (p3 < CAP) ebuf[(size_t)(d4.w>>BSH)*CAP + p3] = (unsigned)(((d4.w & 127) << 17) | s4.w);
  }
}

__global__ __launch_bounds__(1024) void k_bscan(const int* __restrict__ gcur, int* __restrict__ csrbase){
  int t = threadIdx.x, lane = t & 63, wid = t >> 6;
  int c = (t < NB) ? gcur[t] : 0;
  if (c > CAP) c = CAP;
  int v = c;
  #pragma unroll
  for (int m=1;m<64;m<<=1){ int u = __shfl_up(v,m,64); if (lane>=m) v += u; }
  __shared__ int wsum[16], woff[16];
  if (lane==63) wsum[wid] = v;
  __syncthreads();
  if (t==0){ int run=0; for (int w=0;w<16;++w){ woff[w]=run; run+=wsum[w]; } }
  __syncthreads();
  v += woff[wid];
  if (t < NB) csrbase[t] = v - c;
}

__global__ __launch_bounds__(256) void k_group(const unsigned* __restrict__ ebuf,
    const int* __restrict__ gcur, const int* __restrict__ csrbase,
    int* __restrict__ csr, int* __restrict__ rowoff, int* __restrict__ rowcnt){
  __shared__ unsigned stage[CAP];
  __shared__ int hist[128], cur[128];
  __shared__ int wtot;
  int b = blockIdx.x, tid = threadIdx.x;
  int n = gcur[b]; if (n > CAP) n = CAP;
  int nodeBase = b << BSH;
  int cbase = csrbase[b];
  if (tid < 128) hist[tid] = 0;
  __syncthreads();
  int nv = n & ~3;
  for (int k = tid*4; k < nv; k += 1024){
    uint4 q = *reinterpret_cast<const uint4*>(ebuf + (size_t)b*CAP + k);
    stage[k]   = q.x; atomicAdd(&hist[q.x >> 17], 1);
    stage[k+1] = q.y; atomicAdd(&hist[q.y >> 17], 1);
    stage[k+2] = q.z; atomicAdd(&hist[q.z >> 17], 1);
    stage[k+3] = q.w; atomicAdd(&hist[q.w >> 17], 1);
  }
  for (int k = nv + tid; k < n; k += 256){
    unsigned p = ebuf[(size_t)b*CAP + k];
    stage[k] = p;
    atomicAdd(&hist[p >> 17], 1);
  }
  __syncthreads();
  // parallel exclusive scan of hist[0..127] (two waves + carry)
  int v128 = 0;
  if (tid < 128){
    int lane = tid & 63;
    v128 = hist[tid];
    #pragma unroll
    for (int m=1;m<64;m<<=1){ int u = __shfl_up(v128,m,64); if (lane>=m) v128 += u; }
    if (tid == 63) wtot = v128;
  }
  __syncthreads();
  if (tid < 128){
    int incl = v128 + ((tid >= 64) ? wtot : 0);
    int excl = incl - hist[tid];
    int d = nodeBase + tid;
    if (d < N_NODES){ rowoff[d] = cbase + excl; rowcnt[d] = hist[tid]; }
    cur[tid] = excl;
  }
  __syncthreads();
  for (int k=tid; k<n; k+=256){
    unsigned p = stage[k];
    int pos = atomicAdd(&cur[p >> 17], 1);
    csr[cbase + pos] = (int)(p & 0x1FFFFu);
  }
}

// TWO nodes per wave: each 32-lane half owns one node entirely (full 512B row
// per float4 instruction, width-32 reduces, no cross-half combine, no segment
// splitting). gpk[i] = (sa_i, bits(rowbase_i)) packs the softmax gather into
// one 8B load. MODE 0: layer-1 (feat=table1; store h1g + packed g2/dA2).
// MODE 1: layer-2 raw (feat=hbuf; store raw sum). MODE 2: layer-2 direct.
template<int MODE>
__global__ __launch_bounds__(256) void k_agg(const int* __restrict__ rowoff,
    const int* __restrict__ rowcnt, const int* __restrict__ csr_src,
    const float2* __restrict__ gpk, const float* __restrict__ danode,
    const float* __restrict__ feat, const float* __restrict__ cw,
    const float* __restrict__ va2, const float* __restrict__ vd2,
    float* __restrict__ out_h, float* __restrict__ p_lo, float* __restrict__ p_hi){
  __shared__ float2 wrb[4][2][36];   // per wave, per half: 32 entries + 4 zero pads
  int lane = threadIdx.x & 63;
  int wid  = threadIdx.x >> 6;
  int half = lane >> 5;
  int hl   = lane & 31;
  int node = blockIdx.x*8 + wid*2 + half;   // grid covers exactly N_NODES
  int start = rowoff[node];
  int nj = rowcnt[node];
  int end = start + nj;
  float dA = danode[node];

  int c0 = hl*4;
  float a0=0.f, a1=0.f, a2=0.f, a3=0.f;

  // zero pads once
  if (hl < 4) wrb[wid][half][32+hl] = make_float2(0.f, 0.f);

  if (nj <= 32){
    // ---- fast path (~99.93% of nodes): split max/sum softmax, one expf/lane ----
    int p = start + hl;
    bool act = p < end;
    float l = -1e30f; float rbb = 0.f;
    if (act){
      float2 g = gpk[csr_src[p]];
      l = g.x + dA; l = (l > 0.f) ? l : NEG_SLOPE*l;
      rbb = g.y;
    }
    float mxv = l;
    #pragma unroll
    for (int off=16; off; off>>=1) mxv = fmaxf(mxv, __shfl_xor(mxv, off, 64));
    float e = act ? expf(l - mxv) : 0.f;
    float ssum = e;
    #pragma unroll
    for (int off=16; off; off>>=1) ssum += __shfl_xor(ssum, off, 64);
    float inv = 1.0f/(ssum + 1e-16f);
    wrb[wid][half][hl] = make_float2(e*inv, rbb);

    for (int j = 0; j < nj; j += 4){        // reads <= index nj+2 <= 34 (pads)
      float2 q0 = wrb[wid][half][j],   q1 = wrb[wid][half][j+1];
      float2 q2 = wrb[wid][half][j+2], q3 = wrb[wid][half][j+3];
      float4 f0 = ldf4(feat + __float_as_int(q0.y) + c0);
      float4 f1 = ldf4(feat + __float_as_int(q1.y) + c0);
      float4 f2 = ldf4(feat + __float_as_int(q2.y) + c0);
      float4 f3 = ldf4(feat + __float_as_int(q3.y) + c0);
      a0 = fmaf(q0.x, f0.x, a0); a1 = fmaf(q0.x, f0.y, a1);
      a2 = fmaf(q0.x, f0.z, a2); a3 = fmaf(q0.x, f0.w, a3);
      a0 = fmaf(q1.x, f1.x, a0); a1 = fmaf(q1.x, f1.y, a1);
      a2 = fmaf(q1.x, f1.z, a2); a3 = fmaf(q1.x, f1.w, a3);
      a0 = fmaf(q2.x, f2.x, a0); a1 = fmaf(q2.x, f2.y, a1);
      a2 = fmaf(q2.x, f2.z, a2); a3 = fmaf(q2.x, f2.w, a3);
      a0 = fmaf(q3.x, f3.x, a0); a1 = fmaf(q3.x, f3.y, a1);
      a2 = fmaf(q3.x, f3.z, a2); a3 = fmaf(q3.x, f3.w, a3);
    }
  } else {
    // ---- slow path (deg>32, rare): online softmax, tiled staging ----
    float m = -1e30f, ss = 0.f;
    for (int p = start + hl; p < end; p += 32){
      float2 g = gpk[csr_src[p]];
      float l = g.x + dA; l = (l > 0.f) ? l : NEG_SLOPE*l;
      float mn = fmaxf(m, l);
      ss = ss*expf(m-mn) + expf(l-mn);
      m = mn;
    }
    #pragma unroll
    for (int off=16; off; off>>=1){
      float mo = __shfl_xor(m, off, 64);
      float so = __shfl_xor(ss, off, 64);
      float mn = fmaxf(m, mo);
      ss = ss*expf(m-mn) + so*expf(mo-mn);
      m = mn;
    }
    float mx = m;
    float inv = 1.0f/(ss + 1e-16f);

    for (int t0 = start; t0 < end; t0 += 32){
      int p = t0 + hl;
      float w = 0.f, rbb = 0.f;
      if (p < end){
        float2 g = gpk[csr_src[p]];
        float l = g.x + dA; l = (l > 0.f) ? l : NEG_SLOPE*l;
        w = expf(l - mx)*inv;
        rbb = g.y;
      }
      wrb[wid][half][hl] = make_float2(w, rbb);
      int cn = end - t0; if (cn > 32) cn = 32;
      for (int j = 0; j < cn; j += 4){      // reads <= cn+2 <= 34 (zero-w entries/pads)
        float2 q0 = wrb[wid][half][j],   q1 = wrb[wid][half][j+1];
        float2 q2 = wrb[wid][half][j+2], q3 = wrb[wid][half][j+3];
        float4 f0 = ldf4(feat + __float_as_int(q0.y) + c0);
        float4 f1 = ldf4(feat + __float_as_int(q1.y) + c0);
        float4 f2 = ldf4(feat + __float_as_int(q2.y) + c0);
        float4 f3 = ldf4(feat + __float_as_int(q3.y) + c0);
        a0 = fmaf(q0.x, f0.x, a0); a1 = fmaf(q0.x, f0.y, a1);
        a2 = fmaf(q0.x, f0.z, a2); a3 = fmaf(q0.x, f0.w, a3);
        a0 = fmaf(q1.x, f1.x, a0); a1 = fmaf(q1.x, f1.y, a1);
        a2 = fmaf(q1.x, f1.z, a2); a3 = fmaf(q1.x, f1.w, a3);
        a0 = fmaf(q2.x, f2.x, a0); a1 = fmaf(q2.x, f2.y, a1);
        a2 = fmaf(q2.x, f2.z, a2); a3 = fmaf(q2.x, f2.w, a3);
        a0 = fmaf(q3.x, f3.x, a0); a1 = fmaf(q3.x, f3.y, a1);
        a2 = fmaf(q3.x, f3.z, a2); a3 = fmaf(q3.x, f3.w, a3);
      }
    }
  }

  if (MODE == 0){
    float o0 = gelu_f(a0 + cw[CO_B1+c0]);
    float o1 = gelu_f(a1 + cw[CO_B1+c0+1]);
    float o2 = gelu_f(a2 + cw[CO_B1+c0+2]);
    float o3 = gelu_f(a3 + cw[CO_B1+c0+3]);
    stf4(out_h + (size_t)node*D_H + c0, make_float4(o0,o1,o2,o3));
    float pl = o0*va2[c0] + o1*va2[c0+1] + o2*va2[c0+2] + o3*va2[c0+3];
    float ph = o0*vd2[c0] + o1*vd2[c0+1] + o2*vd2[c0+2] + o3*vd2[c0+3];
    #pragma unroll
    for (int off=16; off; off>>=1){ pl += __shfl_xor(pl,off,64); ph += __shfl_xor(ph,off,64); }
    if (hl == 0){
      ((float2*)p_lo)[node] = make_float2(pl, __int_as_float(node*D_H));  // g2 = (sA2, rowbase)
      p_hi[node] = ph;                                                     // dA2
    }
  } else if (MODE == 1){
    stf4(out_h + (size_t)node*D_H + c0, make_float4(a0,a1,a2,a3));
  } else {
    float o0 = gelu_f(a0 + cw[CO_B2+c0]);
    float o1 = gelu_f(a1 + cw[CO_B2+c0+1]);
    float o2 = gelu_f(a2 + cw[CO_B2+c0+2]);
    float o3 = gelu_f(a3 + cw[CO_B2+c0+3]);
    float pl = o0*cw[CO_WFC+c0]     + o1*cw[CO_WFC+c0+1]
             + o2*cw[CO_WFC+c0+2]   + o3*cw[CO_WFC+c0+3];
    float ph = o0*cw[CO_WFC+D_H+c0]   + o1*cw[CO_WFC+D_H+c0+1]
             + o2*cw[CO_WFC+D_H+c0+2] + o3*cw[CO_WFC+D_H+c0+3];
    #pragma unroll
    for (int off=16; off; off>>=1){ pl += __shfl_xor(pl,off,64); ph += __shfl_xor(ph,off,64); }
    if (hl == 0){ p_lo[node] = pl; p_hi[node] = ph; }
  }
}

// Path a: p_lo/p_hi = gelu(agg2@W2 + b2) . Wfc halves. (LDS-staged matmul)
__global__ __launch_bounds__(256) void k_post(const float* __restrict__ agg2,
    const float* __restrict__ cw, float* __restrict__ p_lo, float* __restrict__ p_hi){
  __shared__ float xr[64][D_H];   // 32 KB
  __shared__ float W[64][D_H];    // 32 KB
  const float* W2 = cw + CO_W2;
  int tid = threadIdx.x;
  int cg = tid & 31;
  int rg = tid >> 5;
  int base = blockIdx.x * 64;

  for (int i = tid; i < 64*D_H/4; i += 256){
    int row = i >> 5, c4 = (i & 31) * 4;
    int rr = base + row;
    float4 v = (rr < N_NODES) ? ldf4(agg2 + (size_t)rr*D_H + c4) : make_float4(0.f,0.f,0.f,0.f);
    stf4(&xr[row][c4], v);
  }

  float4 acc[8];
  #pragma unroll
  for (int rs=0; rs<8; ++rs) acc[rs] = make_float4(0.f,0.f,0.f,0.f);

  #pragma unroll
  for (int hk = 0; hk < 2; ++hk){
    __syncthreads();
    for (int i = tid; i < 64*D_H/4; i += 256){
      int k = i >> 5, c4 = (i & 31) * 4;
      stf4(&W[k][c4], ldf4(W2 + (size_t)(hk*64 + k)*D_H + c4));
    }
    __syncthreads();
    for (int k = 0; k < 64; ++k){
      float4 wv = ldf4(&W[k][cg*4]);
      int kk = hk*64 + k;
      #pragma unroll
      for (int rs = 0; rs < 8; ++rs){
        float xv = xr[rs*8 + rg][kk];
        acc[rs].x = fmaf(xv, wv.x, acc[rs].x);
        acc[rs].y = fmaf(xv, wv.y, acc[rs].y);
        acc[rs].z = fmaf(xv, wv.z, acc[rs].z);
        acc[rs].w = fmaf(xv, wv.w, acc[rs].w);
      }
    }
  }

  float4 b2v = ldf4(cw + CO_B2  + cg*4);
  float4 wlo = ldf4(cw + CO_WFC + cg*4);
  float4 whi = ldf4(cw + CO_WFC + D_H + cg*4);
  #pragma unroll
  for (int rs = 0; rs < 8; ++rs){
    int rr = base + rs*8 + rg;
    float o0 = gelu_f(acc[rs].x + b2v.x);
    float o1 = gelu_f(acc[rs].y + b2v.y);
    float o2 = gelu_f(acc[rs].z + b2v.z);
    float o3 = gelu_f(acc[rs].w + b2v.w);
    float pl = o0*wlo.x + o1*wlo.y + o2*wlo.z + o3*wlo.w;
    float ph = o0*whi.x + o1*whi.y + o2*whi.z + o3*whi.w;
    #pragma unroll
    for (int off=16; off; off>>=1){ pl += __shfl_xor(pl,off,64); ph += __shfl_xor(ph,off,64); }
    if (cg == 0 && rr < N_NODES){ p_lo[rr] = pl; p_hi[rr] = ph; }
  }
}

// Path b fallback: hbuf = hbuf @ W2 in place per 64-row block.
__global__ __launch_bounds__(256) void k_matmul2(float* __restrict__ hbuf, const float* __restrict__ cw){
  const float* W2 = cw + CO_W2;
  __shared__ float xr[16][D_H];
  int tid = threadIdx.x;
  int col = tid & 127, half = tid >> 7;
  int base = blockIdx.x * 64;
  for (int t0=0; t0<64; t0+=16){
    int r0 = base + t0;
    for (int i=tid; i<16*D_H; i+=256){
      int rr = r0 + (i>>7);
      xr[i>>7][i&127] = (rr < N_NODES) ? hbuf[(size_t)rr*D_H + (i&127)] : 0.f;
    }
    __syncthreads();
    float acc[8];
    #pragma unroll
    for (int r=0;r<8;++r) acc[r] = 0.f;
    int rb = half*8;
    for (int k=0;k<D_H;++k){
      float wv = W2[k*D_H + col];
      #pragma unroll
      for (int r=0;r<8;++r) acc[r] = fmaf(xr[rb+r][k], wv, acc[r]);
    }
    #pragma unroll
    for (int r=0;r<8;++r){
      int rr = r0 + rb + r;
      if (rr < N_NODES) hbuf[(size_t)rr*D_H + col] = acc[r];
    }
    __syncthreads();
  }
}

// 4 edges per thread, vectorized int4 reads of src/dst.
__global__ void k_final(const int* __restrict__ src, const int* __restrict__ dst,
    const float* __restrict__ p_lo, const float* __restrict__ p_hi,
    const float* __restrict__ cw, const int* __restrict__ flag, void* __restrict__ out){
  int q = blockIdx.x*blockDim.x + threadIdx.x;
  int e0 = q*4;
  if (e0 >= N_EDGES) return;
  float bfc = cw[CO_BFC];
  if (e0 + 4 <= N_EDGES){
    int4 s4 = *reinterpret_cast<const int4*>(src + e0);
    int4 d4 = *reinterpret_cast<const int4*>(dst + e0);
    float4 v;
    v.x = gelu_f(p_lo[s4.x] + p_hi[d4.x] + bfc);
    v.y = gelu_f(p_lo[s4.y] + p_hi[d4.y] + bfc);
    v.z = gelu_f(p_lo[s4.z] + p_hi[d4.z] + bfc);
    v.w = gelu_f(p_lo[s4.w] + p_hi[d4.w] + bfc);
    if (*flag){
      __hip_bfloat16* o = (__hip_bfloat16*)out + e0;
      o[0]=__float2bfloat16(v.x); o[1]=__float2bfloat16(v.y);
      o[2]=__float2bfloat16(v.z); o[3]=__float2bfloat16(v.w);
    } else {
      stf4((float*)out + e0, v);
    }
  } else {
    for (int e = e0; e < N_EDGES; ++e){
      float v = gelu_f(p_lo[src[e]] + p_hi[dst[e]] + bfc);
      if (*flag) ((__hip_bfloat16*)out)[e] = __float2bfloat16(v);
      else       ((float*)out)[e] = v;
    }
  }
}

extern "C" void kernel_launch(void* const* d_in, const int* in_sizes, int n_in,
                              void* d_out, int out_size, void* d_ws, size_t ws_size,
                              hipStream_t stream){
  (void)in_sizes; (void)n_in; (void)out_size;
  const int* x  = (const int*)d_in[0];
  const int* ei = (const int*)d_in[1];
  const int* src = ei;
  const int* dst = ei + N_EDGES;

  // ---- workspace layout ----
  char* base = (char*)d_ws;
  size_t off = 0;
  auto A = [&](size_t bytes)->size_t{ size_t r = off; off = (off + bytes + 255) & ~(size_t)255; return r; };
  size_t o_flag   = A(4);
  size_t o_cw     = A((size_t)CO_TOTAL*4);
  size_t o_va2    = A(D_H*4);
  size_t o_vd2    = A(D_H*4);
  size_t o_table1 = A((size_t)VOCAB*D_H*4);
  size_t o_as1    = A(VOCAB*4);
  size_t o_ad1    = A(VOCAB*4);
  size_t o_g1     = A((size_t)N_NODES*8);    // packed (sA1, rowbase)
  size_t o_dA1    = A((size_t)N_NODES*4);
  size_t o_g2     = A((size_t)N_NODES*8);    // packed (sA2, rowbase)
  size_t o_dA2    = A((size_t)N_NODES*4);
  size_t o_rowoff = A((size_t)N_NODES*4);
  size_t o_rowcnt = A((size_t)N_NODES*4);
  size_t o_plo    = A((size_t)N_NODES*4);
  size_t o_phi    = A((size_t)N_NODES*4);
  size_t o_gcur   = A((size_t)NB*4);
  size_t o_cbase  = A((size_t)NB*4);
  size_t o_csr    = A((size_t)N_ESL*4);
  size_t o_big    = A((size_t)N_NODES*D_H*4);   // ebuf (9.6MB) then hbuf (51.2MB)
  size_t need_b   = off;
  size_t o_agg2   = A((size_t)N_NODES*D_H*4);
  size_t need_a   = off;

  int*    flag   = (int*)(base + o_flag);
  float*  cw     = (float*)(base + o_cw);
  float*  va2    = (float*)(base + o_va2);
  float*  vd2    = (float*)(base + o_vd2);
  float*  table1 = (float*)(base + o_table1);
  float*  as1    = (float*)(base + o_as1);
  float*  ad1    = (float*)(base + o_ad1);
  float2* g1     = (float2*)(base + o_g1);
  float*  dA1    = (float*)(base + o_dA1);
  float2* g2     = (float2*)(base + o_g2);
  float*  dA2    = (float*)(base + o_dA2);
  int*    rowoff = (int*)(base + o_rowoff);
  int*    rowcnt = (int*)(base + o_rowcnt);
  float*  plo    = (float*)(base + o_plo);
  float*  phi    = (float*)(base + o_phi);
  int*    gcur   = (int*)(base + o_gcur);
  int*    cbase  = (int*)(base + o_cbase);
  int*    csr    = (int*)(base + o_csr);
  float*  hbuf   = (float*)(base + o_big);
  unsigned* ebuf = (unsigned*)(base + o_big);   // dead before hbuf is written
  float*  agg2   = (float*)(base + o_agg2);

  if (ws_size < need_b) return;         // signature: out stays 0
  bool patha = (ws_size >= need_a);

  k_detect<<<1, 64, 0, stream>>>((const unsigned*)d_in[2], flag, gcur);
  k_setup<<<352, 256, 0, stream>>>(d_in[2], d_in[3], d_in[4], d_in[5],
      d_in[6], d_in[7], d_in[8], d_in[9], d_in[10], d_in[11], d_in[12], flag, cw, va2, vd2);
  k_table1<<<VOCAB, 64, 0, stream>>>(cw, table1, as1, ad1);
  k_nodelog<<<(N_NODES+255)/256, 256, 0, stream>>>(x, as1, ad1, g1, dA1);

  // bucketed CSR build
  k_bin<<<(N_ESL+CHUNK-1)/CHUNK, 256, 0, stream>>>(src, dst, gcur, ebuf);
  k_bscan<<<1, 1024, 0, stream>>>(gcur, cbase);
  k_group<<<NB, 256, 0, stream>>>(ebuf, gcur, cbase, csr, rowoff, rowcnt);

  int nagg = N_NODES/8;   // 12500, exact
  // layer 1: h1g -> hbuf (overwrites ebuf region), plus packed g2/dA2
  k_agg<0><<<nagg, 256, 0, stream>>>(rowoff, rowcnt, csr, g1, dA1, table1, cw, va2, vd2, hbuf, (float*)g2, dA2);
  if (patha){
    k_agg<1><<<nagg, 256, 0, stream>>>(rowoff, rowcnt, csr, g2, dA2, hbuf, cw, va2, vd2, agg2, nullptr, nullptr);
    k_post<<<(N_NODES+63)/64, 256, 0, stream>>>(agg2, cw, plo, phi);
  } else {
    k_matmul2<<<(N_NODES+63)/64, 256, 0, stream>>>(hbuf, cw);
    k_agg<2><<<nagg, 256, 0, stream>>>(rowoff, rowcnt, csr, g2, dA2, hbuf, cw, va2, vd2, nullptr, plo, phi);
  }
  k_final<<<(N_EDGES/4+255)/256, 256, 0, stream>>>(src, dst, plo, phi, cw, flag, d_out);
}

// Round 16
// 347.339 us; speedup vs baseline: 1.1208x; 1.0194x over previous
//
#include <hip/hip_runtime.h>
#include <hip/hip_bf16.h>

#define N_NODES 100000
#define N_EDGES 1600000
#define N_ESL   1700000   // edges + self loops
#define VOCAB   1000
#define D_IN    64
#define D_H     128
#define NEG_SLOPE 0.2f

// dst-bucket binning
#define BSH   7
#define NB    782          // ceil(100000/128)
#define CAP   3072         // per-bucket capacity (mean 2174, sigma ~47)
#define CHUNK 16384

// canonical fp32 weight-table offsets (elements)
#define CO_EMB   0
#define CO_W1    64000
#define CO_AS1   72192
#define CO_AD1   72320
#define CO_B1    72448
#define CO_W2    72576
#define CO_AS2   88960
#define CO_AD2   89088
#define CO_B2    89216
#define CO_WFC   89344
#define CO_BFC   89600
#define CO_TOTAL 89601

__device__ __forceinline__ float us2f(unsigned short h){ union{unsigned v; float f;} c; c.v = ((unsigned)h)<<16; return c.f; }
__device__ __forceinline__ float gelu_f(float v){ return 0.5f*v*(1.0f + erff(v*0.7071067811865475f)); }
__device__ __forceinline__ float4 ldf4(const float* p){ return *reinterpret_cast<const float4*>(p); }
__device__ __forceinline__ void stf4(float* p, float4 v){ *reinterpret_cast<float4*>(p) = v; }

__device__ __forceinline__ float wred_sum(float v){
  #pragma unroll
  for (int m=32;m;m>>=1) v += __shfl_xor(v,m,64);
  return v;
}

// Detect bf16-packed (flag=1) vs fp32 (flag=0) inputs; also zero gcur.
__global__ __launch_bounds__(64) void k_detect(const unsigned* __restrict__ w, int* __restrict__ flag,
    int* __restrict__ gcur){
  int t = threadIdx.x;
  for (int i=t; i<NB; i+=64) gcur[i] = 0;
  float cnt = 0.f;
  #pragma unroll
  for (int i=0;i<2;++i){
    unsigned v = w[t + 64*i];
    unsigned e = (v >> 7) & 0xFFu;
    cnt += (e >= 110u && e <= 126u) ? 1.f : 0.f;
  }
  cnt = wred_sum(cnt);
  if (t==0) *flag = (cnt >= 64.f) ? 1 : 0;
}

// Blocks 0..350: canonicalize the 11 float inputs into the fp32 table cw.
// Block 351: prevec -- va2 = W2 @ a_src2 ; vd2 = W2 @ a_dst2 (reads RAW inputs).
// Arg mapping: p0=emb p1=W1 p2=as1 p3=ad1 p4=b1 p5=W2 p6=as2 p7=ad2 p8=b2 p9=Wfc p10=bfc.
__global__ __launch_bounds__(256) void k_setup(const void* p0, const void* p1, const void* p2, const void* p3,
    const void* p4, const void* p5, const void* p6, const void* p7, const void* p8,
    const void* p9, const void* p10, const int* __restrict__ flag, float* __restrict__ c,
    float* __restrict__ va2, float* __restrict__ vd2){
  int b = blockIdx.x;
  if (b == 351){
    int t = threadIdx.x;
    int r = t & 127;
    int f = *flag;
    const float* w2f = (const float*)p5;                 // p5 = W2
    const unsigned short* w2h = (const unsigned short*)p5;
    const float* af = (const float*)((t < 128) ? p6 : p7);              // as2 / ad2
    const unsigned short* ah = (const unsigned short*)((t < 128) ? p6 : p7);
    float s = 0.f;
    for (int j=0;j<D_H;++j){
      float wv = f ? us2f(w2h[r*D_H+j]) : w2f[r*D_H+j];
      float av = f ? us2f(ah[j]) : af[j];
      s = fmaf(wv, av, s);
    }
    if (t < 128) va2[r] = s; else vd2[r] = s;
    return;
  }
  int i = b*256 + threadIdx.x;
  if (i >= CO_TOTAL) return;
  const void* src; int off;
  if      (i < CO_W1 ){ src=p0;  off=i;          }
  else if (i < CO_AS1){ src=p1;  off=i-CO_W1;    }
  else if (i < CO_AD1){ src=p2;  off=i-CO_AS1;   }
  else if (i < CO_B1 ){ src=p3;  off=i-CO_AD1;   }
  else if (i < CO_W2 ){ src=p4;  off=i-CO_B1;    }
  else if (i < CO_AS2){ src=p5;  off=i-CO_W2;    }
  else if (i < CO_AD2){ src=p6;  off=i-CO_AS2;   }
  else if (i < CO_B2 ){ src=p7;  off=i-CO_AD2;   }
  else if (i < CO_WFC){ src=p8;  off=i-CO_B2;    }
  else if (i < CO_BFC){ src=p9;  off=i-CO_WFC;   }
  else               { src=p10; off=i-CO_BFC;   }
  float v = (*flag) ? us2f(((const unsigned short*)src)[off]) : ((const float*)src)[off];
  c[i] = v;
}

// table1[v][:] = emb[v] @ W1 ; as1[v]/ad1[v] = attention dots
__global__ __launch_bounds__(64) void k_table1(const float* __restrict__ cw,
    float* __restrict__ table1, float* __restrict__ as1, float* __restrict__ ad1){
  const float* emb = cw + CO_EMB;
  const float* W1  = cw + CO_W1;
  int v = blockIdx.x; int t = threadIdx.x;
  __shared__ float er[D_IN];
  er[t] = emb[v*D_IN + t];
  __syncthreads();
  int d0 = t, d1 = t + 64;
  float a0 = 0.f, a1 = 0.f;
  for (int k=0;k<D_IN;++k){
    float e = er[k];
    a0 = fmaf(e, W1[k*D_H+d0], a0);
    a1 = fmaf(e, W1[k*D_H+d1], a1);
  }
  table1[v*D_H+d0] = a0; table1[v*D_H+d1] = a1;
  float ps = a0*cw[CO_AS1+d0] + a1*cw[CO_AS1+d1];
  float pd = a0*cw[CO_AD1+d0] + a1*cw[CO_AD1+d1];
  ps = wred_sum(ps); pd = wred_sum(pd);
  if (t==0){ as1[v]=ps; ad1[v]=pd; }
}

// g1[i] = (as1[x[i]], bits(x[i]*D_H)); dA1[i] = ad1[x[i]]
__global__ void k_nodelog(const int* __restrict__ x, const float* __restrict__ as1,
    const float* __restrict__ ad1, float2* __restrict__ g1, float* __restrict__ dA1){
  int i = blockIdx.x*blockDim.x + threadIdx.x;
  if (i < N_NODES){
    int xs = x[i];
    g1[i] = make_float2(as1[xs], __int_as_float(xs * D_H));
    dA1[i] = ad1[xs];
  }
}

// ---- bucketed CSR build ----
__global__ __launch_bounds__(256) void k_bin(const int* __restrict__ src,
    const int* __restrict__ dst, int* __restrict__ gcur, unsigned* __restrict__ ebuf){
  __shared__ int hist[NB];
  __shared__ int cur[NB];
  int tid = threadIdx.x;
  int base0 = blockIdx.x * CHUNK;
  int n = N_ESL - base0; if (n > CHUNK) n = CHUNK;
  for (int i=tid; i<NB; i+=256) hist[i] = 0;
  __syncthreads();
  for (int k = tid*4; k < n; k += 1024){
    int e = base0 + k;
    int4 d4;
    if (e + 4 <= N_EDGES) d4 = *reinterpret_cast<const int4*>(dst + e);
    else d4 = make_int4(e-N_EDGES, e+1-N_EDGES, e+2-N_EDGES, e+3-N_EDGES);
    atomicAdd(&hist[d4.x>>BSH], 1);
    atomicAdd(&hist[d4.y>>BSH], 1);
    atomicAdd(&hist[d4.z>>BSH], 1);
    atomicAdd(&hist[d4.w>>BSH], 1);
  }
  __syncthreads();
  for (int b=tid; b<NB; b+=256){
    int c = hist[b];
    cur[b] = c ? atomicAdd(&gcur[b], c) : 0;
  }
  __syncthreads();
  for (int k = tid*4; k < n; k += 1024){
    int e = base0 + k;
    int4 d4, s4;
    if (e + 4 <= N_EDGES){
      d4 = *reinterpret_cast<const int4*>(dst + e);
      s4 = *reinterpret_cast<const int4*>(src + e);
    } else {
      d4 = make_int4(e-N_EDGES, e+1-N_EDGES, e+2-N_EDGES, e+3-N_EDGES);
      s4 = d4;
    }
    int p0 = atomicAdd(&cur[d4.x>>BSH], 1);
    if (p0 < CAP) ebuf[(size_t)(d4.x>>BSH)*CAP + p0] = (unsigned)(((d4.x & 127) << 17) | s4.x);
    int p1 = atomicAdd(&cur[d4.y>>BSH], 1);
    if (p1 < CAP) ebuf[(size_t)(d4.y>>BSH)*CAP + p1] = (unsigned)(((d4.y & 127) << 17) | s4.y);
    int p2 = atomicAdd(&cur[d4.z>>BSH], 1);
    if (p2 < CAP) ebuf[(size_t)(d4.z>>BSH)*CAP + p2] = (unsigned)(((d4.z & 127) << 17) | s4.z);
    int p3 = atomicAdd(&cur[d4.w>>BSH], 1);
    if (p3 < CAP) ebuf[(size_t)(d4.w>>BSH)*CAP + p3] = (unsigned)(((d4.w & 127) << 17) | s4.w);
  }
}

__global__ __launch_bounds__(1024) void k_bscan(const int* __restrict__ gcur, int* __restrict__ csrbase){
  int t = threadIdx.x, lane = t & 63, wid = t >> 6;
  int c = (t < NB) ? gcur[t] : 0;
  if (c > CAP) c = CAP;
  int v = c;
  #pragma unroll
  for (int m=1;m<64;m<<=1){ int u = __shfl_up(v,m,64); if (lane>=m) v += u; }
  __shared__ int wsum[16], woff[16];
  if (lane==63) wsum[wid] = v;
  __syncthreads();
  if (t==0){ int run=0; for (int w=0;w<16;++w){ woff[w]=run; run+=wsum[w]; } }
  __syncthreads();
  v += woff[wid];
  if (t < NB) csrbase[t] = v - c;
}

__global__ __launch_bounds__(256) void k_group(const unsigned* __restrict__ ebuf,
    const int* __restrict__ gcur, const int* __restrict__ csrbase,
    int* __restrict__ csr, int* __restrict__ rowoff, int* __restrict__ rowcnt){
  __shared__ unsigned stage[CAP];
  __shared__ int hist[128], cur[128];
  __shared__ int wtot;
  int b = blockIdx.x, tid = threadIdx.x;
  int n = gcur[b]; if (n > CAP) n = CAP;
  int nodeBase = b << BSH;
  int cbase = csrbase[b];
  if (tid < 128) hist[tid] = 0;
  __syncthreads();
  int nv = n & ~3;
  for (int k = tid*4; k < nv; k += 1024){
    uint4 q = *reinterpret_cast<const uint4*>(ebuf + (size_t)b*CAP + k);
    stage[k]   = q.x; atomicAdd(&hist[q.x >> 17], 1);
    stage[k+1] = q.y; atomicAdd(&hist[q.y >> 17], 1);
    stage[k+2] = q.z; atomicAdd(&hist[q.z >> 17], 1);
    stage[k+3] = q.w; atomicAdd(&hist[q.w >> 17], 1);
  }
  for (int k = nv + tid; k < n; k += 256){
    unsigned p = ebuf[(size_t)b*CAP + k];
    stage[k] = p;
    atomicAdd(&hist[p >> 17], 1);
  }
  __syncthreads();
  // parallel exclusive scan of hist[0..127] (two waves + carry)
  int v128 = 0;
  if (tid < 128){
    int lane = tid & 63;
    v128 = hist[tid];
    #pragma unroll
    for (int m=1;m<64;m<<=1){ int u = __shfl_up(v128,m,64); if (lane>=m) v128 += u; }
    if (tid == 63) wtot = v128;
  }
  __syncthreads();
  if (tid < 128){
    int incl = v128 + ((tid >= 64) ? wtot : 0);
    int excl = incl - hist[tid];
    int d = nodeBase + tid;
    if (d < N_NODES){ rowoff[d] = cbase + excl; rowcnt[d] = hist[tid]; }
    cur[tid] = excl;
  }
  __syncthreads();
  for (int k=tid; k<n; k+=256){
    unsigned p = stage[k];
    int pos = atomicAdd(&cur[p >> 17], 1);
    csr[cbase + pos] = (int)(p & 0x1FFFFu);
  }
}

// ---- MODE-1 aggregation (layer-2 raw gather from the 51MB hbuf) ----
// Round-14 form, measured best at the BW floor: ONE node per 64-lane wave
// (VGPR 28, occupancy ~75%), scalar sa gather, rb = s*D_H, LDS (w,rb) staging,
// half-split at a multiple of 4.
__global__ __launch_bounds__(256) void k_agg1n(const int* __restrict__ rowoff,
    const int* __restrict__ rowcnt, const int* __restrict__ csr_src,
    const float* __restrict__ sa, const float* __restrict__ danode,
    const float* __restrict__ feat, float* __restrict__ out_h){
  __shared__ float2 wrb[4][68];     // 64 entries + 4 zero pads per wave
  int lane = threadIdx.x & 63;
  int wid  = threadIdx.x >> 6;
  int node = blockIdx.x*4 + wid;
  if (node >= N_NODES) return;
  int start = rowoff[node];
  int nj = rowcnt[node];
  int end = start + nj;
  float dA = danode[node];

  int c0 = (lane & 31)*4, half = lane >> 5;
  float a0=0.f, a1=0.f, a2=0.f, a3=0.f;

  if (nj <= 64){
    int p = start + lane;
    bool act = p < end;
    float l = -1e30f; int rb_sav = 0;
    if (act){
      int s = csr_src[p];
      l = sa[s] + dA; l = (l > 0.f) ? l : NEG_SLOPE*l;
      rb_sav = s * D_H;
    }
    float mxv = l;
    #pragma unroll
    for (int off=32; off; off>>=1) mxv = fmaxf(mxv, __shfl_xor(mxv, off, 64));
    float e = act ? expf(l - mxv) : 0.f;
    float ssum = e;
    #pragma unroll
    for (int off=32; off; off>>=1) ssum += __shfl_xor(ssum, off, 64);
    float inv = 1.0f/(ssum + 1e-16f);
    wrb[wid][lane] = make_float2(e*inv, __int_as_float(rb_sav));
    if (lane < 4) wrb[wid][64+lane] = make_float2(0.f, 0.f);

    int mid = ((nj >> 1) + 2) & ~3;          // multiple of 4, 0 <= mid <= nj
    int lo = half ? mid : 0;
    int hi = half ? nj : mid;
    for (int j = lo; j < hi; j += 4){
      float2 q0 = wrb[wid][j],   q1 = wrb[wid][j+1];
      float2 q2 = wrb[wid][j+2], q3 = wrb[wid][j+3];
      float4 f0 = ldf4(feat + __float_as_int(q0.y) + c0);
      float4 f1 = ldf4(feat + __float_as_int(q1.y) + c0);
      float4 f2 = ldf4(feat + __float_as_int(q2.y) + c0);
      float4 f3 = ldf4(feat + __float_as_int(q3.y) + c0);
      a0 = fmaf(q0.x, f0.x, a0); a1 = fmaf(q0.x, f0.y, a1);
      a2 = fmaf(q0.x, f0.z, a2); a3 = fmaf(q0.x, f0.w, a3);
      a0 = fmaf(q1.x, f1.x, a0); a1 = fmaf(q1.x, f1.y, a1);
      a2 = fmaf(q1.x, f1.z, a2); a3 = fmaf(q1.x, f1.w, a3);
      a0 = fmaf(q2.x, f2.x, a0); a1 = fmaf(q2.x, f2.y, a1);
      a2 = fmaf(q2.x, f2.z, a2); a3 = fmaf(q2.x, f2.w, a3);
      a0 = fmaf(q3.x, f3.x, a0); a1 = fmaf(q3.x, f3.y, a1);
      a2 = fmaf(q3.x, f3.z, a2); a3 = fmaf(q3.x, f3.w, a3);
    }
  } else {
    float m = -1e30f, ss = 0.f;
    for (int p = start + lane; p < end; p += 64){
      int s = csr_src[p];
      float l = sa[s] + dA; l = (l > 0.f) ? l : NEG_SLOPE*l;
      float mn = fmaxf(m, l);
      ss = ss*expf(m-mn) + expf(l-mn);
      m = mn;
    }
    #pragma unroll
    for (int off=32; off; off>>=1){
      float mo = __shfl_xor(m, off, 64);
      float so = __shfl_xor(ss, off, 64);
      float mn = fmaxf(m, mo);
      ss = ss*expf(m-mn) + so*expf(mo-mn);
      m = mn;
    }
    float mx = m;
    float inv = 1.0f/(ss + 1e-16f);

    for (int t0 = start; t0 < end; t0 += 64){
      int p = t0 + lane;
      float w = 0.f; int rb = 0;
      if (p < end){
        int s = csr_src[p];
        float l = sa[s] + dA; l = (l > 0.f) ? l : NEG_SLOPE*l;
        w = expf(l - mx)*inv;
        rb = s * D_H;
      }
      int cnt = end - t0; if (cnt > 64) cnt = 64;
      int mid = (cnt + 1) >> 1;
      int lo = half ? mid : 0;
      int hi = half ? cnt : mid;
      for (int j = lo; j < hi; j += 4){
        int nh = hi - j;
        float w0 = __shfl(w,  j,   64), w1 = __shfl(w,  j+1, 64);
        float w2 = __shfl(w,  j+2, 64), w3 = __shfl(w,  j+3, 64);
        int   r0 = __shfl(rb, j,   64), r1 = __shfl(rb, j+1, 64);
        int   r2 = __shfl(rb, j+2, 64), r3 = __shfl(rb, j+3, 64);
        float4 f0 = make_float4(0.f,0.f,0.f,0.f), f1 = f0, f2 = f0, f3 = f0;
        f0 = ldf4(feat + r0 + c0);
        if (nh > 1) f1 = ldf4(feat + r1 + c0);
        if (nh > 2) f2 = ldf4(feat + r2 + c0);
        if (nh > 3) f3 = ldf4(feat + r3 + c0);
        a0 = fmaf(w0, f0.x, a0); a1 = fmaf(w0, f0.y, a1);
        a2 = fmaf(w0, f0.z, a2); a3 = fmaf(w0, f0.w, a3);
        a0 = fmaf(w1, f1.x, a0); a1 = fmaf(w1, f1.y, a1);
        a2 = fmaf(w1, f1.z, a2); a3 = fmaf(w1, f1.w, a3);
        a0 = fmaf(w2, f2.x, a0); a1 = fmaf(w2, f2.y, a1);
        a2 = fmaf(w2, f2.z, a2); a3 = fmaf(w2, f2.w, a3);
        a0 = fmaf(w3, f3.x, a0); a1 = fmaf(w3, f3.y, a1);
        a2 = fmaf(w3, f3.z, a2); a3 = fmaf(w3, f3.w, a3);
      }
    }
  }

  a0 += __shfl_xor(a0,32,64); a1 += __shfl_xor(a1,32,64);
  a2 += __shfl_xor(a2,32,64); a3 += __shfl_xor(a3,32,64);
  if (!half) stf4(out_h + (size_t)node*D_H + c0, make_float4(a0,a1,a2,a3));
}

// ---- MODE-0 / MODE-2 aggregation: TWO nodes per wave (round-15 form, best
// for the L2-resident table gather). MODE 0: feat=table1 via packed g1;
// epilogue writes h1g + plain sA2/dA2. MODE 2 (fallback): feat=h2, scalar sa.
template<int MODE>
__global__ __launch_bounds__(256) void k_agg2n(const int* __restrict__ rowoff,
    const int* __restrict__ rowcnt, const int* __restrict__ csr_src,
    const float2* __restrict__ gpk, const float* __restrict__ saplain,
    const float* __restrict__ danode,
    const float* __restrict__ feat, const float* __restrict__ cw,
    const float* __restrict__ va2, const float* __restrict__ vd2,
    float* __restrict__ out_h, float* __restrict__ p_lo, float* __restrict__ p_hi){
  __shared__ float2 wrb[4][2][36];   // per wave, per half: 32 entries + 4 zero pads
  int lane = threadIdx.x & 63;
  int wid  = threadIdx.x >> 6;
  int half = lane >> 5;
  int hl   = lane & 31;
  int node = blockIdx.x*8 + wid*2 + half;   // grid covers exactly N_NODES
  int start = rowoff[node];
  int nj = rowcnt[node];
  int end = start + nj;
  float dA = danode[node];

  int c0 = hl*4;
  float a0=0.f, a1=0.f, a2=0.f, a3=0.f;

  if (hl < 4) wrb[wid][half][32+hl] = make_float2(0.f, 0.f);

  if (nj <= 32){
    int p = start + hl;
    bool act = p < end;
    float l = -1e30f; float rbb = 0.f;
    if (act){
      int s = csr_src[p];
      if (MODE == 0){
        float2 g = gpk[s];
        l = g.x + dA; rbb = g.y;
      } else {
        l = saplain[s] + dA; rbb = __int_as_float(s * D_H);
      }
      l = (l > 0.f) ? l : NEG_SLOPE*l;
    }
    float mxv = l;
    #pragma unroll
    for (int off=16; off; off>>=1) mxv = fmaxf(mxv, __shfl_xor(mxv, off, 64));
    float e = act ? expf(l - mxv) : 0.f;
    float ssum = e;
    #pragma unroll
    for (int off=16; off; off>>=1) ssum += __shfl_xor(ssum, off, 64);
    float inv = 1.0f/(ssum + 1e-16f);
    wrb[wid][half][hl] = make_float2(e*inv, rbb);

    for (int j = 0; j < nj; j += 4){        // reads <= index nj+2 <= 34 (pads)
      float2 q0 = wrb[wid][half][j],   q1 = wrb[wid][half][j+1];
      float2 q2 = wrb[wid][half][j+2], q3 = wrb[wid][half][j+3];
      float4 f0 = ldf4(feat + __float_as_int(q0.y) + c0);
      float4 f1 = ldf4(feat + __float_as_int(q1.y) + c0);
      float4 f2 = ldf4(feat + __float_as_int(q2.y) + c0);
      float4 f3 = ldf4(feat + __float_as_int(q3.y) + c0);
      a0 = fmaf(q0.x, f0.x, a0); a1 = fmaf(q0.x, f0.y, a1);
      a2 = fmaf(q0.x, f0.z, a2); a3 = fmaf(q0.x, f0.w, a3);
      a0 = fmaf(q1.x, f1.x, a0); a1 = fmaf(q1.x, f1.y, a1);
      a2 = fmaf(q1.x, f1.z, a2); a3 = fmaf(q1.x, f1.w, a3);
      a0 = fmaf(q2.x, f2.x, a0); a1 = fmaf(q2.x, f2.y, a1);
      a2 = fmaf(q2.x, f2.z, a2); a3 = fmaf(q2.x, f2.w, a3);
      a0 = fmaf(q3.x, f3.x, a0); a1 = fmaf(q3.x, f3.y, a1);
      a2 = fmaf(q3.x, f3.z, a2); a3 = fmaf(q3.x, f3.w, a3);
    }
  } else {
    // slow path (deg>32, rare): online softmax, tiled staging
    float m = -1e30f, ss = 0.f;
    for (int p = start + hl; p < end; p += 32){
      int s = csr_src[p];
      float l;
      if (MODE == 0) l = gpk[s].x + dA; else l = saplain[s] + dA;
      l = (l > 0.f) ? l : NEG_SLOPE*l;
      float mn = fmaxf(m, l);
      ss = ss*expf(m-mn) + expf(l-mn);
      m = mn;
    }
    #pragma unroll
    for (int off=16; off; off>>=1){
      float mo = __shfl_xor(m, off, 64);
      float so = __shfl_xor(ss, off, 64);
      float mn = fmaxf(m, mo);
      ss = ss*expf(m-mn) + so*expf(mo-mn);
      m = mn;
    }
    float mx = m;
    float inv = 1.0f/(ss + 1e-16f);

    for (int t0 = start; t0 < end; t0 += 32){
      int p = t0 + hl;
      float w = 0.f, rbb = 0.f;
      if (p < end){
        int s = csr_src[p];
        float l;
        if (MODE == 0){ float2 g = gpk[s]; l = g.x + dA; rbb = g.y; }
        else          { l = saplain[s] + dA; rbb = __int_as_float(s * D_H); }
        l = (l > 0.f) ? l : NEG_SLOPE*l;
        w = expf(l - mx)*inv;
      }
      wrb[wid][half][hl] = make_float2(w, rbb);
      int cn = end - t0; if (cn > 32) cn = 32;
      for (int j = 0; j < cn; j += 4){
        float2 q0 = wrb[wid][half][j],   q1 = wrb[wid][half][j+1];
        float2 q2 = wrb[wid][half][j+2], q3 = wrb[wid][half][j+3];
        float4 f0 = ldf4(feat + __float_as_int(q0.y) + c0);
        float4 f1 = ldf4(feat + __float_as_int(q1.y) + c0);
        float4 f2 = ldf4(feat + __float_as_int(q2.y) + c0);
        float4 f3 = ldf4(feat + __float_as_int(q3.y) + c0);
        a0 = fmaf(q0.x, f0.x, a0); a1 = fmaf(q0.x, f0.y, a1);
        a2 = fmaf(q0.x, f0.z, a2); a3 = fmaf(q0.x, f0.w, a3);
        a0 = fmaf(q1.x, f1.x, a0); a1 = fmaf(q1.x, f1.y, a1);
        a2 = fmaf(q1.x, f1.z, a2); a3 = fmaf(q1.x, f1.w, a3);
        a0 = fmaf(q2.x, f2.x, a0); a1 = fmaf(q2.x, f2.y, a1);
        a2 = fmaf(q2.x, f2.z, a2); a3 = fmaf(q2.x, f2.w, a3);
        a0 = fmaf(q3.x, f3.x, a0); a1 = fmaf(q3.x, f3.y, a1);
        a2 = fmaf(q3.x, f3.z, a2); a3 = fmaf(q3.x, f3.w, a3);
      }
    }
  }

  if (MODE == 0){
    float o0 = gelu_f(a0 + cw[CO_B1+c0]);
    float o1 = gelu_f(a1 + cw[CO_B1+c0+1]);
    float o2 = gelu_f(a2 + cw[CO_B1+c0+2]);
    float o3 = gelu_f(a3 + cw[CO_B1+c0+3]);
    stf4(out_h + (size_t)node*D_H + c0, make_float4(o0,o1,o2,o3));
    float pl = o0*va2[c0] + o1*va2[c0+1] + o2*va2[c0+2] + o3*va2[c0+3];
    float ph = o0*vd2[c0] + o1*vd2[c0+1] + o2*vd2[c0+2] + o3*vd2[c0+3];
    #pragma unroll
    for (int off=16; off; off>>=1){ pl += __shfl_xor(pl,off,64); ph += __shfl_xor(ph,off,64); }
    if (hl == 0){ p_lo[node] = pl; p_hi[node] = ph; }   // sA2, dA2 (plain)
  } else {
    float o0 = gelu_f(a0 + cw[CO_B2+c0]);
    float o1 = gelu_f(a1 + cw[CO_B2+c0+1]);
    float o2 = gelu_f(a2 + cw[CO_B2+c0+2]);
    float o3 = gelu_f(a3 + cw[CO_B2+c0+3]);
    float pl = o0*cw[CO_WFC+c0]     + o1*cw[CO_WFC+c0+1]
             + o2*cw[CO_WFC+c0+2]   + o3*cw[CO_WFC+c0+3];
    float ph = o0*cw[CO_WFC+D_H+c0]   + o1*cw[CO_WFC+D_H+c0+1]
             + o2*cw[CO_WFC+D_H+c0+2] + o3*cw[CO_WFC+D_H+c0+3];
    #pragma unroll
    for (int off=16; off; off>>=1){ pl += __shfl_xor(pl,off,64); ph += __shfl_xor(ph,off,64); }
    if (hl == 0){ p_lo[node] = pl; p_hi[node] = ph; }
  }
}

// Path a: p_lo/p_hi = gelu(agg2@W2 + b2) . Wfc halves. (LDS-staged matmul)
__global__ __launch_bounds__(256) void k_post(const float* __restrict__ agg2,
    const float* __restrict__ cw, float* __restrict__ p_lo, float* __restrict__ p_hi){
  __shared__ float xr[64][D_H];   // 32 KB
  __shared__ float W[64][D_H];    // 32 KB
  const float* W2 = cw + CO_W2;
  int tid = threadIdx.x;
  int cg = tid & 31;
  int rg = tid >> 5;
  int base = blockIdx.x * 64;

  for (int i = tid; i < 64*D_H/4; i += 256){
    int row = i >> 5, c4 = (i & 31) * 4;
    int rr = base + row;
    float4 v = (rr < N_NODES) ? ldf4(agg2 + (size_t)rr*D_H + c4) : make_float4(0.f,0.f,0.f,0.f);
    stf4(&xr[row][c4], v);
  }

  float4 acc[8];
  #pragma unroll
  for (int rs=0; rs<8; ++rs) acc[rs] = make_float4(0.f,0.f,0.f,0.f);

  #pragma unroll
  for (int hk = 0; hk < 2; ++hk){
    __syncthreads();
    for (int i = tid; i < 64*D_H/4; i += 256){
      int k = i >> 5, c4 = (i & 31) * 4;
      stf4(&W[k][c4], ldf4(W2 + (size_t)(hk*64 + k)*D_H + c4));
    }
    __syncthreads();
    for (int k = 0; k < 64; ++k){
      float4 wv = ldf4(&W[k][cg*4]);
      int kk = hk*64 + k;
      #pragma unroll
      for (int rs = 0; rs < 8; ++rs){
        float xv = xr[rs*8 + rg][kk];
        acc[rs].x = fmaf(xv, wv.x, acc[rs].x);
        acc[rs].y = fmaf(xv, wv.y, acc[rs].y);
        acc[rs].z = fmaf(xv, wv.z, acc[rs].z);
        acc[rs].w = fmaf(xv, wv.w, acc[rs].w);
      }
    }
  }

  float4 b2v = ldf4(cw + CO_B2  + cg*4);
  float4 wlo = ldf4(cw + CO_WFC + cg*4);
  float4 whi = ldf4(cw + CO_WFC + D_H + cg*4);
  #pragma unroll
  for (int rs = 0; rs < 8; ++rs){
    int rr = base + rs*8 + rg;
    float o0 = gelu_f(acc[rs].x + b2v.x);
    float o1 = gelu_f(acc[rs].y + b2v.y);
    float o2 = gelu_f(acc[rs].z + b2v.z);
    float o3 = gelu_f(acc[rs].w + b2v.w);
    float pl = o0*wlo.x + o1*wlo.y + o2*wlo.z + o3*wlo.w;
    float ph = o0*whi.x + o1*whi.y + o2*whi.z + o3*whi.w;
    #pragma unroll
    for (int off=16; off; off>>=1){ pl += __shfl_xor(pl,off,64); ph += __shfl_xor(ph,off,64); }
    if (cg == 0 && rr < N_NODES){ p_lo[rr] = pl; p_hi[rr] = ph; }
  }
}

// Path b fallback: hbuf = hbuf @ W2 in place per 64-row block.
__global__ __launch_bounds__(256) void k_matmul2(float* __restrict__ hbuf, const float* __restrict__ cw){
  const float* W2 = cw + CO_W2;
  __shared__ float xr[16][D_H];
  int tid = threadIdx.x;
  int col = tid & 127, half = tid >> 7;
  int base = blockIdx.x * 64;
  for (int t0=0; t0<64; t0+=16){
    int r0 = base + t0;
    for (int i=tid; i<16*D_H; i+=256){
      int rr = r0 + (i>>7);
      xr[i>>7][i&127] = (rr < N_NODES) ? hbuf[(size_t)rr*D_H + (i&127)] : 0.f;
    }
    __syncthreads();
    float acc[8];
    #pragma unroll
    for (int r=0;r<8;++r) acc[r] = 0.f;
    int rb = half*8;
    for (int k=0;k<D_H;++k){
      float wv = W2[k*D_H + col];
      #pragma unroll
      for (int r=0;r<8;++r) acc[r] = fmaf(xr[rb+r][k], wv, acc[r]);
    }
    #pragma unroll
    for (int r=0;r<8;++r){
      int rr = r0 + rb + r;
      if (rr < N_NODES) hbuf[(size_t)rr*D_H + col] = acc[r];
    }
    __syncthreads();
  }
}

// 4 edges per thread, vectorized int4 reads of src/dst.
__global__ void k_final(const int* __restrict__ src, const int* __restrict__ dst,
    const float* __restrict__ p_lo, const float* __restrict__ p_hi,
    const float* __restrict__ cw, const int* __restrict__ flag, void* __restrict__ out){
  int q = blockIdx.x*blockDim.x + threadIdx.x;
  int e0 = q*4;
  if (e0 >= N_EDGES) return;
  float bfc = cw[CO_BFC];
  if (e0 + 4 <= N_EDGES){
    int4 s4 = *reinterpret_cast<const int4*>(src + e0);
    int4 d4 = *reinterpret_cast<const int4*>(dst + e0);
    float4 v;
    v.x = gelu_f(p_lo[s4.x] + p_hi[d4.x] + bfc);
    v.y = gelu_f(p_lo[s4.y] + p_hi[d4.y] + bfc);
    v.z = gelu_f(p_lo[s4.z] + p_hi[d4.z] + bfc);
    v.w = gelu_f(p_lo[s4.w] + p_hi[d4.w] + bfc);
    if (*flag){
      __hip_bfloat16* o = (__hip_bfloat16*)out + e0;
      o[0]=__float2bfloat16(v.x); o[1]=__float2bfloat16(v.y);
      o[2]=__float2bfloat16(v.z); o[3]=__float2bfloat16(v.w);
    } else {
      stf4((float*)out + e0, v);
    }
  } else {
    for (int e = e0; e < N_EDGES; ++e){
      float v = gelu_f(p_lo[src[e]] + p_hi[dst[e]] + bfc);
      if (*flag) ((__hip_bfloat16*)out)[e] = __float2bfloat16(v);
      else       ((float*)out)[e] = v;
    }
  }
}

extern "C" void kernel_launch(void* const* d_in, const int* in_sizes, int n_in,
                              void* d_out, int out_size, void* d_ws, size_t ws_size,
                              hipStream_t stream){
  (void)in_sizes; (void)n_in; (void)out_size;
  const int* x  = (const int*)d_in[0];
  const int* ei = (const int*)d_in[1];
  const int* src = ei;
  const int* dst = ei + N_EDGES;

  // ---- workspace layout ----
  char* base = (char*)d_ws;
  size_t off = 0;
  auto A = [&](size_t bytes)->size_t{ size_t r = off; off = (off + bytes + 255) & ~(size_t)255; return r; };
  size_t o_flag   = A(4);
  size_t o_cw     = A((size_t)CO_TOTAL*4);
  size_t o_va2    = A(D_H*4);
  size_t o_vd2    = A(D_H*4);
  size_t o_table1 = A((size_t)VOCAB*D_H*4);
  size_t o_as1    = A(VOCAB*4);
  size_t o_ad1    = A(VOCAB*4);
  size_t o_g1     = A((size_t)N_NODES*8);    // packed (sA1, rowbase)
  size_t o_dA1    = A((size_t)N_NODES*4);
  size_t o_sA2    = A((size_t)N_NODES*4);
  size_t o_dA2    = A((size_t)N_NODES*4);
  size_t o_rowoff = A((size_t)N_NODES*4);
  size_t o_rowcnt = A((size_t)N_NODES*4);
  size_t o_plo    = A((size_t)N_NODES*4);
  size_t o_phi    = A((size_t)N_NODES*4);
  size_t o_gcur   = A((size_t)NB*4);
  size_t o_cbase  = A((size_t)NB*4);
  size_t o_csr    = A((size_t)N_ESL*4);
  size_t o_big    = A((size_t)N_NODES*D_H*4);   // ebuf (9.6MB) then hbuf (51.2MB)
  size_t need_b   = off;
  size_t o_agg2   = A((size_t)N_NODES*D_H*4);
  size_t need_a   = off;

  int*    flag   = (int*)(base + o_flag);
  float*  cw     = (float*)(base + o_cw);
  float*  va2    = (float*)(base + o_va2);
  float*  vd2    = (float*)(base + o_vd2);
  float*  table1 = (float*)(base + o_table1);
  float*  as1    = (float*)(base + o_as1);
  float*  ad1    = (float*)(base + o_ad1);
  float2* g1     = (float2*)(base + o_g1);
  float*  dA1    = (float*)(base + o_dA1);
  float*  sA2    = (float*)(base + o_sA2);
  float*  dA2    = (float*)(base + o_dA2);
  int*    rowoff = (int*)(base + o_rowoff);
  int*    rowcnt = (int*)(base + o_rowcnt);
  float*  plo    = (float*)(base + o_plo);
  float*  phi    = (float*)(base + o_phi);
  int*    gcur   = (int*)(base + o_gcur);
  int*    cbase  = (int*)(base + o_cbase);
  int*    csr    = (int*)(base + o_csr);
  float*  hbuf   = (float*)(base + o_big);
  unsigned* ebuf = (unsigned*)(base + o_big);   // dead before hbuf is written
  float*  agg2   = (float*)(base + o_agg2);

  if (ws_size < need_b) return;         // signature: out stays 0
  bool patha = (ws_size >= need_a);

  k_detect<<<1, 64, 0, stream>>>((const unsigned*)d_in[2], flag, gcur);
  k_setup<<<352, 256, 0, stream>>>(d_in[2], d_in[3], d_in[4], d_in[5],
      d_in[6], d_in[7], d_in[8], d_in[9], d_in[10], d_in[11], d_in[12], flag, cw, va2, vd2);
  k_table1<<<VOCAB, 64, 0, stream>>>(cw, table1, as1, ad1);
  k_nodelog<<<(N_NODES+255)/256, 256, 0, stream>>>(x, as1, ad1, g1, dA1);

  // bucketed CSR build
  k_bin<<<(N_ESL+CHUNK-1)/CHUNK, 256, 0, stream>>>(src, dst, gcur, ebuf);
  k_bscan<<<1, 1024, 0, stream>>>(gcur, cbase);
  k_group<<<NB, 256, 0, stream>>>(ebuf, gcur, cbase, csr, rowoff, rowcnt);

  // layer 1 (2-node/wave): h1g -> hbuf, plus plain sA2/dA2
  k_agg2n<0><<<N_NODES/8, 256, 0, stream>>>(rowoff, rowcnt, csr, g1, nullptr, dA1,
      table1, cw, va2, vd2, hbuf, sA2, dA2);
  if (patha){
    // layer 2 (1-node/wave, measured-best at the BW floor)
    k_agg1n<<<(N_NODES+3)/4, 256, 0, stream>>>(rowoff, rowcnt, csr, sA2, dA2, hbuf, agg2);
    k_post<<<(N_NODES+63)/64, 256, 0, stream>>>(agg2, cw, plo, phi);
  } else {
    k_matmul2<<<(N_NODES+63)/64, 256, 0, stream>>>(hbuf, cw);
    k_agg2n<2><<<N_NODES/8, 256, 0, stream>>>(rowoff, rowcnt, csr, nullptr, sA2, dA2,
        hbuf, cw, va2, vd2, nullptr, plo, phi);
  }
  k_final<<<(N_EDGES/4+255)/256, 256, 0, stream>>>(src, dst, plo, phi, cw, flag, d_out);
}

// Round 17
// 345.474 us; speedup vs baseline: 1.1268x; 1.0054x over previous
//
#include <hip/hip_runtime.h>
#include <hip/hip_bf16.h>

#define N_NODES 100000
#define N_EDGES 1600000
#define N_ESL   1700000   // edges + self loops
#define VOCAB   1000
#define D_IN    64
#define D_H     128
#define NEG_SLOPE 0.2f

// dst-bucket binning
#define BSH   7
#define NB    782          // ceil(100000/128)
#define CAP   3072         // per-bucket capacity (mean 2174, sigma ~47)
#define CHUNK 16384

// canonical fp32 weight-table offsets (elements)
#define CO_EMB   0
#define CO_W1    64000
#define CO_AS1   72192
#define CO_AD1   72320
#define CO_B1    72448
#define CO_W2    72576
#define CO_AS2   88960
#define CO_AD2   89088
#define CO_B2    89216
#define CO_WFC   89344
#define CO_BFC   89600
#define CO_TOTAL 89601

__device__ __forceinline__ float us2f(unsigned short h){ union{unsigned v; float f;} c; c.v = ((unsigned)h)<<16; return c.f; }
__device__ __forceinline__ float gelu_f(float v){ return 0.5f*v*(1.0f + erff(v*0.7071067811865475f)); }
__device__ __forceinline__ float4 ldf4(const float* p){ return *reinterpret_cast<const float4*>(p); }
__device__ __forceinline__ void stf4(float* p, float4 v){ *reinterpret_cast<float4*>(p) = v; }

__device__ __forceinline__ float wred_sum(float v){
  #pragma unroll
  for (int m=32;m;m>>=1) v += __shfl_xor(v,m,64);
  return v;
}

// Detect bf16-packed (flag=1) vs fp32 (flag=0) inputs; also zero gcur.
__global__ __launch_bounds__(64) void k_detect(const unsigned* __restrict__ w, int* __restrict__ flag,
    int* __restrict__ gcur){
  int t = threadIdx.x;
  for (int i=t; i<NB; i+=64) gcur[i] = 0;
  float cnt = 0.f;
  #pragma unroll
  for (int i=0;i<2;++i){
    unsigned v = w[t + 64*i];
    unsigned e = (v >> 7) & 0xFFu;
    cnt += (e >= 110u && e <= 126u) ? 1.f : 0.f;
  }
  cnt = wred_sum(cnt);
  if (t==0) *flag = (cnt >= 64.f) ? 1 : 0;
}

// Blocks 0..350: canonicalize the 11 float inputs into the fp32 table cw.
// Block 351: prevec -- va2 = W2 @ a_src2 ; vd2 = W2 @ a_dst2 (reads RAW inputs).
// Arg mapping: p0=emb p1=W1 p2=as1 p3=ad1 p4=b1 p5=W2 p6=as2 p7=ad2 p8=b2 p9=Wfc p10=bfc.
__global__ __launch_bounds__(256) void k_setup(const void* p0, const void* p1, const void* p2, const void* p3,
    const void* p4, const void* p5, const void* p6, const void* p7, const void* p8,
    const void* p9, const void* p10, const int* __restrict__ flag, float* __restrict__ c,
    float* __restrict__ va2, float* __restrict__ vd2){
  int b = blockIdx.x;
  if (b == 351){
    int t = threadIdx.x;
    int r = t & 127;
    int f = *flag;
    const float* w2f = (const float*)p5;                 // p5 = W2
    const unsigned short* w2h = (const unsigned short*)p5;
    const float* af = (const float*)((t < 128) ? p6 : p7);              // as2 / ad2
    const unsigned short* ah = (const unsigned short*)((t < 128) ? p6 : p7);
    float s = 0.f;
    for (int j=0;j<D_H;++j){
      float wv = f ? us2f(w2h[r*D_H+j]) : w2f[r*D_H+j];
      float av = f ? us2f(ah[j]) : af[j];
      s = fmaf(wv, av, s);
    }
    if (t < 128) va2[r] = s; else vd2[r] = s;
    return;
  }
  int i = b*256 + threadIdx.x;
  if (i >= CO_TOTAL) return;
  const void* src; int off;
  if      (i < CO_W1 ){ src=p0;  off=i;          }
  else if (i < CO_AS1){ src=p1;  off=i-CO_W1;    }
  else if (i < CO_AD1){ src=p2;  off=i-CO_AS1;   }
  else if (i < CO_B1 ){ src=p3;  off=i-CO_AD1;   }
  else if (i < CO_W2 ){ src=p4;  off=i-CO_B1;    }
  else if (i < CO_AS2){ src=p5;  off=i-CO_W2;    }
  else if (i < CO_AD2){ src=p6;  off=i-CO_AS2;   }
  else if (i < CO_B2 ){ src=p7;  off=i-CO_AD2;   }
  else if (i < CO_WFC){ src=p8;  off=i-CO_B2;    }
  else if (i < CO_BFC){ src=p9;  off=i-CO_WFC;   }
  else               { src=p10; off=i-CO_BFC;   }
  float v = (*flag) ? us2f(((const unsigned short*)src)[off]) : ((const float*)src)[off];
  c[i] = v;
}

// table1[v][:] = emb[v] @ W1 ; as1[v]/ad1[v] = attention dots
__global__ __launch_bounds__(64) void k_table1(const float* __restrict__ cw,
    float* __restrict__ table1, float* __restrict__ as1, float* __restrict__ ad1){
  const float* emb = cw + CO_EMB;
  const float* W1  = cw + CO_W1;
  int v = blockIdx.x; int t = threadIdx.x;
  __shared__ float er[D_IN];
  er[t] = emb[v*D_IN + t];
  __syncthreads();
  int d0 = t, d1 = t + 64;
  float a0 = 0.f, a1 = 0.f;
  for (int k=0;k<D_IN;++k){
    float e = er[k];
    a0 = fmaf(e, W1[k*D_H+d0], a0);
    a1 = fmaf(e, W1[k*D_H+d1], a1);
  }
  table1[v*D_H+d0] = a0; table1[v*D_H+d1] = a1;
  float ps = a0*cw[CO_AS1+d0] + a1*cw[CO_AS1+d1];
  float pd = a0*cw[CO_AD1+d0] + a1*cw[CO_AD1+d1];
  ps = wred_sum(ps); pd = wred_sum(pd);
  if (t==0){ as1[v]=ps; ad1[v]=pd; }
}

// g1[i] = (as1[x[i]], bits(x[i]*D_H)); dA1[i] = ad1[x[i]]
__global__ void k_nodelog(const int* __restrict__ x, const float* __restrict__ as1,
    const float* __restrict__ ad1, float2* __restrict__ g1, float* __restrict__ dA1){
  int i = blockIdx.x*blockDim.x + threadIdx.x;
  if (i < N_NODES){
    int xs = x[i];
    g1[i] = make_float2(as1[xs], __int_as_float(xs * D_H));
    dA1[i] = ad1[xs];
  }
}

// ---- bucketed CSR build ----
__global__ __launch_bounds__(256) void k_bin(const int* __restrict__ src,
    const int* __restrict__ dst, int* __restrict__ gcur, unsigned* __restrict__ ebuf){
  __shared__ int hist[NB];
  __shared__ int cur[NB];
  int tid = threadIdx.x;
  int base0 = blockIdx.x * CHUNK;
  int n = N_ESL - base0; if (n > CHUNK) n = CHUNK;
  for (int i=tid; i<NB; i+=256) hist[i] = 0;
  __syncthreads();
  for (int k = tid*4; k < n; k += 1024){
    int e = base0 + k;
    int4 d4;
    if (e + 4 <= N_EDGES) d4 = *reinterpret_cast<const int4*>(dst + e);
    else d4 = make_int4(e-N_EDGES, e+1-N_EDGES, e+2-N_EDGES, e+3-N_EDGES);
    atomicAdd(&hist[d4.x>>BSH], 1);
    atomicAdd(&hist[d4.y>>BSH], 1);
    atomicAdd(&hist[d4.z>>BSH], 1);
    atomicAdd(&hist[d4.w>>BSH], 1);
  }
  __syncthreads();
  for (int b=tid; b<NB; b+=256){
    int c = hist[b];
    cur[b] = c ? atomicAdd(&gcur[b], c) : 0;
  }
  __syncthreads();
  for (int k = tid*4; k < n; k += 1024){
    int e = base0 + k;
    int4 d4, s4;
    if (e + 4 <= N_EDGES){
      d4 = *reinterpret_cast<const int4*>(dst + e);
      s4 = *reinterpret_cast<const int4*>(src + e);
    } else {
      d4 = make_int4(e-N_EDGES, e+1-N_EDGES, e+2-N_EDGES, e+3-N_EDGES);
      s4 = d4;
    }
    int p0 = atomicAdd(&cur[d4.x>>BSH], 1);
    if (p0 < CAP) ebuf[(size_t)(d4.x>>BSH)*CAP + p0] = (unsigned)(((d4.x & 127) << 17) | s4.x);
    int p1 = atomicAdd(&cur[d4.y>>BSH], 1);
    if (p1 < CAP) ebuf[(size_t)(d4.y>>BSH)*CAP + p1] = (unsigned)(((d4.y & 127) << 17) | s4.y);
    int p2 = atomicAdd(&cur[d4.z>>BSH], 1);
    if (p2 < CAP) ebuf[(size_t)(d4.z>>BSH)*CAP + p2] = (unsigned)(((d4.z & 127) << 17) | s4.z);
    int p3 = atomicAdd(&cur[d4.w>>BSH], 1);
    if (p3 < CAP) ebuf[(size_t)(d4.w>>BSH)*CAP + p3] = (unsigned)(((d4.w & 127) << 17) | s4.w);
  }
}

__global__ __launch_bounds__(1024) void k_bscan(const int* __restrict__ gcur, int* __restrict__ csrbase){
  int t = threadIdx.x, lane = t & 63, wid = t >> 6;
  int c = (t < NB) ? gcur[t] : 0;
  if (c > CAP) c = CAP;
  int v = c;
  #pragma unroll
  for (int m=1;m<64;m<<=1){ int u = __shfl_up(v,m,64); if (lane>=m) v += u; }
  __shared__ int wsum[16], woff[16];
  if (lane==63) wsum[wid] = v;
  __syncthreads();
  if (t==0){ int run=0; for (int w=0;w<16;++w){ woff[w]=run; run+=wsum[w]; } }
  __syncthreads();
  v += woff[wid];
  if (t < NB) csrbase[t] = v - c;
}

__global__ __launch_bounds__(256) void k_group(const unsigned* __restrict__ ebuf,
    const int* __restrict__ gcur, const int* __restrict__ csrbase,
    int* __restrict__ csr, int* __restrict__ rowoff, int* __restrict__ rowcnt){
  __shared__ unsigned stage[CAP];
  __shared__ int hist[128], cur[128];
  __shared__ int wtot;
  int b = blockIdx.x, tid = threadIdx.x;
  int n = gcur[b]; if (n > CAP) n = CAP;
  int nodeBase = b << BSH;
  int cbase = csrbase[b];
  if (tid < 128) hist[tid] = 0;
  __syncthreads();
  int nv = n & ~3;
  for (int k = tid*4; k < nv; k += 1024){
    uint4 q = *reinterpret_cast<const uint4*>(ebuf + (size_t)b*CAP + k);
    stage[k]   = q.x; atomicAdd(&hist[q.x >> 17], 1);
    stage[k+1] = q.y; atomicAdd(&hist[q.y >> 17], 1);
    stage[k+2] = q.z; atomicAdd(&hist[q.z >> 17], 1);
    stage[k+3] = q.w; atomicAdd(&hist[q.w >> 17], 1);
  }
  for (int k = nv + tid; k < n; k += 256){
    unsigned p = ebuf[(size_t)b*CAP + k];
    stage[k] = p;
    atomicAdd(&hist[p >> 17], 1);
  }
  __syncthreads();
  // parallel exclusive scan of hist[0..127] (two waves + carry)
  int v128 = 0;
  if (tid < 128){
    int lane = tid & 63;
    v128 = hist[tid];
    #pragma unroll
    for (int m=1;m<64;m<<=1){ int u = __shfl_up(v128,m,64); if (lane>=m) v128 += u; }
    if (tid == 63) wtot = v128;
  }
  __syncthreads();
  if (tid < 128){
    int incl = v128 + ((tid >= 64) ? wtot : 0);
    int excl = incl - hist[tid];
    int d = nodeBase + tid;
    if (d < N_NODES){ rowoff[d] = cbase + excl; rowcnt[d] = hist[tid]; }
    cur[tid] = excl;
  }
  __syncthreads();
  for (int k=tid; k<n; k+=256){
    unsigned p = stage[k];
    int pos = atomicAdd(&cur[p >> 17], 1);
    csr[cbase + pos] = (int)(p & 0x1FFFFu);
  }
}

// ---- MODE-1 aggregation (layer-2 raw gather from the 51MB hbuf) ----
// Round-14 form, measured best at the BW floor: ONE node per 64-lane wave
// (VGPR 28, occupancy ~75%). DO NOT TOUCH: 9 structural variants all pin at
// FETCH/dur ~3.8 TB/s; this form minimizes FETCH (421MB) at max occupancy.
__global__ __launch_bounds__(256) void k_agg1n(const int* __restrict__ rowoff,
    const int* __restrict__ rowcnt, const int* __restrict__ csr_src,
    const float* __restrict__ sa, const float* __restrict__ danode,
    const float* __restrict__ feat, float* __restrict__ out_h){
  __shared__ float2 wrb[4][68];     // 64 entries + 4 zero pads per wave
  int lane = threadIdx.x & 63;
  int wid  = threadIdx.x >> 6;
  int node = blockIdx.x*4 + wid;
  if (node >= N_NODES) return;
  int start = rowoff[node];
  int nj = rowcnt[node];
  int end = start + nj;
  float dA = danode[node];

  int c0 = (lane & 31)*4, half = lane >> 5;
  float a0=0.f, a1=0.f, a2=0.f, a3=0.f;

  if (nj <= 64){
    int p = start + lane;
    bool act = p < end;
    float l = -1e30f; int rb_sav = 0;
    if (act){
      int s = csr_src[p];
      l = sa[s] + dA; l = (l > 0.f) ? l : NEG_SLOPE*l;
      rb_sav = s * D_H;
    }
    float mxv = l;
    #pragma unroll
    for (int off=32; off; off>>=1) mxv = fmaxf(mxv, __shfl_xor(mxv, off, 64));
    float e = act ? expf(l - mxv) : 0.f;
    float ssum = e;
    #pragma unroll
    for (int off=32; off; off>>=1) ssum += __shfl_xor(ssum, off, 64);
    float inv = 1.0f/(ssum + 1e-16f);
    wrb[wid][lane] = make_float2(e*inv, __int_as_float(rb_sav));
    if (lane < 4) wrb[wid][64+lane] = make_float2(0.f, 0.f);

    int mid = ((nj >> 1) + 2) & ~3;          // multiple of 4, 0 <= mid <= nj
    int lo = half ? mid : 0;
    int hi = half ? nj : mid;
    for (int j = lo; j < hi; j += 4){
      float2 q0 = wrb[wid][j],   q1 = wrb[wid][j+1];
      float2 q2 = wrb[wid][j+2], q3 = wrb[wid][j+3];
      float4 f0 = ldf4(feat + __float_as_int(q0.y) + c0);
      float4 f1 = ldf4(feat + __float_as_int(q1.y) + c0);
      float4 f2 = ldf4(feat + __float_as_int(q2.y) + c0);
      float4 f3 = ldf4(feat + __float_as_int(q3.y) + c0);
      a0 = fmaf(q0.x, f0.x, a0); a1 = fmaf(q0.x, f0.y, a1);
      a2 = fmaf(q0.x, f0.z, a2); a3 = fmaf(q0.x, f0.w, a3);
      a0 = fmaf(q1.x, f1.x, a0); a1 = fmaf(q1.x, f1.y, a1);
      a2 = fmaf(q1.x, f1.z, a2); a3 = fmaf(q1.x, f1.w, a3);
      a0 = fmaf(q2.x, f2.x, a0); a1 = fmaf(q2.x, f2.y, a1);
      a2 = fmaf(q2.x, f2.z, a2); a3 = fmaf(q2.x, f2.w, a3);
      a0 = fmaf(q3.x, f3.x, a0); a1 = fmaf(q3.x, f3.y, a1);
      a2 = fmaf(q3.x, f3.z, a2); a3 = fmaf(q3.x, f3.w, a3);
    }
  } else {
    float m = -1e30f, ss = 0.f;
    for (int p = start + lane; p < end; p += 64){
      int s = csr_src[p];
      float l = sa[s] + dA; l = (l > 0.f) ? l : NEG_SLOPE*l;
      float mn = fmaxf(m, l);
      ss = ss*expf(m-mn) + expf(l-mn);
      m = mn;
    }
    #pragma unroll
    for (int off=32; off; off>>=1){
      float mo = __shfl_xor(m, off, 64);
      float so = __shfl_xor(ss, off, 64);
      float mn = fmaxf(m, mo);
      ss = ss*expf(m-mn) + so*expf(mo-mn);
      m = mn;
    }
    float mx = m;
    float inv = 1.0f/(ss + 1e-16f);

    for (int t0 = start; t0 < end; t0 += 64){
      int p = t0 + lane;
      float w = 0.f; int rb = 0;
      if (p < end){
        int s = csr_src[p];
        float l = sa[s] + dA; l = (l > 0.f) ? l : NEG_SLOPE*l;
        w = expf(l - mx)*inv;
        rb = s * D_H;
      }
      int cnt = end - t0; if (cnt > 64) cnt = 64;
      int mid = (cnt + 1) >> 1;
      int lo = half ? mid : 0;
      int hi = half ? cnt : mid;
      for (int j = lo; j < hi; j += 4){
        int nh = hi - j;
        float w0 = __shfl(w,  j,   64), w1 = __shfl(w,  j+1, 64);
        float w2 = __shfl(w,  j+2, 64), w3 = __shfl(w,  j+3, 64);
        int   r0 = __shfl(rb, j,   64), r1 = __shfl(rb, j+1, 64);
        int   r2 = __shfl(rb, j+2, 64), r3 = __shfl(rb, j+3, 64);
        float4 f0 = make_float4(0.f,0.f,0.f,0.f), f1 = f0, f2 = f0, f3 = f0;
        f0 = ldf4(feat + r0 + c0);
        if (nh > 1) f1 = ldf4(feat + r1 + c0);
        if (nh > 2) f2 = ldf4(feat + r2 + c0);
        if (nh > 3) f3 = ldf4(feat + r3 + c0);
        a0 = fmaf(w0, f0.x, a0); a1 = fmaf(w0, f0.y, a1);
        a2 = fmaf(w0, f0.z, a2); a3 = fmaf(w0, f0.w, a3);
        a0 = fmaf(w1, f1.x, a0); a1 = fmaf(w1, f1.y, a1);
        a2 = fmaf(w1, f1.z, a2); a3 = fmaf(w1, f1.w, a3);
        a0 = fmaf(w2, f2.x, a0); a1 = fmaf(w2, f2.y, a1);
        a2 = fmaf(w2, f2.z, a2); a3 = fmaf(w2, f2.w, a3);
        a0 = fmaf(w3, f3.x, a0); a1 = fmaf(w3, f3.y, a1);
        a2 = fmaf(w3, f3.z, a2); a3 = fmaf(w3, f3.w, a3);
      }
    }
  }

  a0 += __shfl_xor(a0,32,64); a1 += __shfl_xor(a1,32,64);
  a2 += __shfl_xor(a2,32,64); a3 += __shfl_xor(a3,32,64);
  if (!half) stf4(out_h + (size_t)node*D_H + c0, make_float4(a0,a1,a2,a3));
}

// ---- MODE-0 / MODE-2 aggregation: TWO nodes per wave (best for the
// L2-resident table gather). Fast path now keeps 8 independent float4 loads
// in flight (LDS-staged, unguarded; pads extended to 8 so max read index
// nj+6 <= 38 < 40). MODE 0: feat=table1 via packed g1; writes h1g + sA2/dA2.
template<int MODE>
__global__ __launch_bounds__(256) void k_agg2n(const int* __restrict__ rowoff,
    const int* __restrict__ rowcnt, const int* __restrict__ csr_src,
    const float2* __restrict__ gpk, const float* __restrict__ saplain,
    const float* __restrict__ danode,
    const float* __restrict__ feat, const float* __restrict__ cw,
    const float* __restrict__ va2, const float* __restrict__ vd2,
    float* __restrict__ out_h, float* __restrict__ p_lo, float* __restrict__ p_hi){
  __shared__ float2 wrb[4][2][40];   // per wave, per half: 32 entries + 8 zero pads
  int lane = threadIdx.x & 63;
  int wid  = threadIdx.x >> 6;
  int half = lane >> 5;
  int hl   = lane & 31;
  int node = blockIdx.x*8 + wid*2 + half;   // grid covers exactly N_NODES
  int start = rowoff[node];
  int nj = rowcnt[node];
  int end = start + nj;
  float dA = danode[node];

  int c0 = hl*4;
  float a0=0.f, a1=0.f, a2=0.f, a3=0.f;

  if (hl < 8) wrb[wid][half][32+hl] = make_float2(0.f, 0.f);

  if (nj <= 32){
    int p = start + hl;
    bool act = p < end;
    float l = -1e30f; float rbb = 0.f;
    if (act){
      int s = csr_src[p];
      if (MODE == 0){
        float2 g = gpk[s];
        l = g.x + dA; rbb = g.y;
      } else {
        l = saplain[s] + dA; rbb = __int_as_float(s * D_H);
      }
      l = (l > 0.f) ? l : NEG_SLOPE*l;
    }
    float mxv = l;
    #pragma unroll
    for (int off=16; off; off>>=1) mxv = fmaxf(mxv, __shfl_xor(mxv, off, 64));
    float e = act ? expf(l - mxv) : 0.f;
    float ssum = e;
    #pragma unroll
    for (int off=16; off; off>>=1) ssum += __shfl_xor(ssum, off, 64);
    float inv = 1.0f/(ssum + 1e-16f);
    wrb[wid][half][hl] = make_float2(e*inv, rbb);

    for (int j = 0; j < nj; j += 8){        // reads <= index nj+6 <= 38 (pads)
      float2 q0 = wrb[wid][half][j],   q1 = wrb[wid][half][j+1];
      float2 q2 = wrb[wid][half][j+2], q3 = wrb[wid][half][j+3];
      float2 q4 = wrb[wid][half][j+4], q5 = wrb[wid][half][j+5];
      float2 q6 = wrb[wid][half][j+6], q7 = wrb[wid][half][j+7];
      float4 f0 = ldf4(feat + __float_as_int(q0.y) + c0);
      float4 f1 = ldf4(feat + __float_as_int(q1.y) + c0);
      float4 f2 = ldf4(feat + __float_as_int(q2.y) + c0);
      float4 f3 = ldf4(feat + __float_as_int(q3.y) + c0);
      float4 f4 = ldf4(feat + __float_as_int(q4.y) + c0);
      float4 f5 = ldf4(feat + __float_as_int(q5.y) + c0);
      float4 f6 = ldf4(feat + __float_as_int(q6.y) + c0);
      float4 f7 = ldf4(feat + __float_as_int(q7.y) + c0);
      a0 = fmaf(q0.x, f0.x, a0); a1 = fmaf(q0.x, f0.y, a1);
      a2 = fmaf(q0.x, f0.z, a2); a3 = fmaf(q0.x, f0.w, a3);
      a0 = fmaf(q1.x, f1.x, a0); a1 = fmaf(q1.x, f1.y, a1);
      a2 = fmaf(q1.x, f1.z, a2); a3 = fmaf(q1.x, f1.w, a3);
      a0 = fmaf(q2.x, f2.x, a0); a1 = fmaf(q2.x, f2.y, a1);
      a2 = fmaf(q2.x, f2.z, a2); a3 = fmaf(q2.x, f2.w, a3);
      a0 = fmaf(q3.x, f3.x, a0); a1 = fmaf(q3.x, f3.y, a1);
      a2 = fmaf(q3.x, f3.z, a2); a3 = fmaf(q3.x, f3.w, a3);
      a0 = fmaf(q4.x, f4.x, a0); a1 = fmaf(q4.x, f4.y, a1);
      a2 = fmaf(q4.x, f4.z, a2); a3 = fmaf(q4.x, f4.w, a3);
      a0 = fmaf(q5.x, f5.x, a0); a1 = fmaf(q5.x, f5.y, a1);
      a2 = fmaf(q5.x, f5.z, a2); a3 = fmaf(q5.x, f5.w, a3);
      a0 = fmaf(q6.x, f6.x, a0); a1 = fmaf(q6.x, f6.y, a1);
      a2 = fmaf(q6.x, f6.z, a2); a3 = fmaf(q6.x, f6.w, a3);
      a0 = fmaf(q7.x, f7.x, a0); a1 = fmaf(q7.x, f7.y, a1);
      a2 = fmaf(q7.x, f7.z, a2); a3 = fmaf(q7.x, f7.w, a3);
    }
  } else {
    // slow path (deg>32, rare): online softmax, tiled staging
    float m = -1e30f, ss = 0.f;
    for (int p = start + hl; p < end; p += 32){
      int s = csr_src[p];
      float l;
      if (MODE == 0) l = gpk[s].x + dA; else l = saplain[s] + dA;
      l = (l > 0.f) ? l : NEG_SLOPE*l;
      float mn = fmaxf(m, l);
      ss = ss*expf(m-mn) + expf(l-mn);
      m = mn;
    }
    #pragma unroll
    for (int off=16; off; off>>=1){
      float mo = __shfl_xor(m, off, 64);
      float so = __shfl_xor(ss, off, 64);
      float mn = fmaxf(m, mo);
      ss = ss*expf(m-mn) + so*expf(mo-mn);
      m = mn;
    }
    float mx = m;
    float inv = 1.0f/(ss + 1e-16f);

    for (int t0 = start; t0 < end; t0 += 32){
      int p = t0 + hl;
      float w = 0.f, rbb = 0.f;
      if (p < end){
        int s = csr_src[p];
        float l;
        if (MODE == 0){ float2 g = gpk[s]; l = g.x + dA; rbb = g.y; }
        else          { l = saplain[s] + dA; rbb = __int_as_float(s * D_H); }
        l = (l > 0.f) ? l : NEG_SLOPE*l;
        w = expf(l - mx)*inv;
      }
      wrb[wid][half][hl] = make_float2(w, rbb);
      int cn = end - t0; if (cn > 32) cn = 32;
      for (int j = 0; j < cn; j += 4){
        float2 q0 = wrb[wid][half][j],   q1 = wrb[wid][half][j+1];
        float2 q2 = wrb[wid][half][j+2], q3 = wrb[wid][half][j+3];
        float4 f0 = ldf4(feat + __float_as_int(q0.y) + c0);
        float4 f1 = ldf4(feat + __float_as_int(q1.y) + c0);
        float4 f2 = ldf4(feat + __float_as_int(q2.y) + c0);
        float4 f3 = ldf4(feat + __float_as_int(q3.y) + c0);
        a0 = fmaf(q0.x, f0.x, a0); a1 = fmaf(q0.x, f0.y, a1);
        a2 = fmaf(q0.x, f0.z, a2); a3 = fmaf(q0.x, f0.w, a3);
        a0 = fmaf(q1.x, f1.x, a0); a1 = fmaf(q1.x, f1.y, a1);
        a2 = fmaf(q1.x, f1.z, a2); a3 = fmaf(q1.x, f1.w, a3);
        a0 = fmaf(q2.x, f2.x, a0); a1 = fmaf(q2.x, f2.y, a1);
        a2 = fmaf(q2.x, f2.z, a2); a3 = fmaf(q2.x, f2.w, a3);
        a0 = fmaf(q3.x, f3.x, a0); a1 = fmaf(q3.x, f3.y, a1);
        a2 = fmaf(q3.x, f3.z, a2); a3 = fmaf(q3.x, f3.w, a3);
      }
    }
  }

  if (MODE == 0){
    float o0 = gelu_f(a0 + cw[CO_B1+c0]);
    float o1 = gelu_f(a1 + cw[CO_B1+c0+1]);
    float o2 = gelu_f(a2 + cw[CO_B1+c0+2]);
    float o3 = gelu_f(a3 + cw[CO_B1+c0+3]);
    stf4(out_h + (size_t)node*D_H + c0, make_float4(o0,o1,o2,o3));
    float pl = o0*va2[c0] + o1*va2[c0+1] + o2*va2[c0+2] + o3*va2[c0+3];
    float ph = o0*vd2[c0] + o1*vd2[c0+1] + o2*vd2[c0+2] + o3*vd2[c0+3];
    #pragma unroll
    for (int off=16; off; off>>=1){ pl += __shfl_xor(pl,off,64); ph += __shfl_xor(ph,off,64); }
    if (hl == 0){ p_lo[node] = pl; p_hi[node] = ph; }   // sA2, dA2 (plain)
  } else {
    float o0 = gelu_f(a0 + cw[CO_B2+c0]);
    float o1 = gelu_f(a1 + cw[CO_B2+c0+1]);
    float o2 = gelu_f(a2 + cw[CO_B2+c0+2]);
    float o3 = gelu_f(a3 + cw[CO_B2+c0+3]);
    float pl = o0*cw[CO_WFC+c0]     + o1*cw[CO_WFC+c0+1]
             + o2*cw[CO_WFC+c0+2]   + o3*cw[CO_WFC+c0+3];
    float ph = o0*cw[CO_WFC+D_H+c0]   + o1*cw[CO_WFC+D_H+c0+1]
             + o2*cw[CO_WFC+D_H+c0+2] + o3*cw[CO_WFC+D_H+c0+3];
    #pragma unroll
    for (int off=16; off; off>>=1){ pl += __shfl_xor(pl,off,64); ph += __shfl_xor(ph,off,64); }
    if (hl == 0){ p_lo[node] = pl; p_hi[node] = ph; }
  }
}

// Path a: p_lo/p_hi = gelu(agg2@W2 + b2) . Wfc halves. (LDS-staged matmul)
__global__ __launch_bounds__(256) void k_post(const float* __restrict__ agg2,
    const float* __restrict__ cw, float* __restrict__ p_lo, float* __restrict__ p_hi){
  __shared__ float xr[64][D_H];   // 32 KB
  __shared__ float W[64][D_H];    // 32 KB
  const float* W2 = cw + CO_W2;
  int tid = threadIdx.x;
  int cg = tid & 31;
  int rg = tid >> 5;
  int base = blockIdx.x * 64;

  for (int i = tid; i < 64*D_H/4; i += 256){
    int row = i >> 5, c4 = (i & 31) * 4;
    int rr = base + row;
    float4 v = (rr < N_NODES) ? ldf4(agg2 + (size_t)rr*D_H + c4) : make_float4(0.f,0.f,0.f,0.f);
    stf4(&xr[row][c4], v);
  }

  float4 acc[8];
  #pragma unroll
  for (int rs=0; rs<8; ++rs) acc[rs] = make_float4(0.f,0.f,0.f,0.f);

  #pragma unroll
  for (int hk = 0; hk < 2; ++hk){
    __syncthreads();
    for (int i = tid; i < 64*D_H/4; i += 256){
      int k = i >> 5, c4 = (i & 31) * 4;
      stf4(&W[k][c4], ldf4(W2 + (size_t)(hk*64 + k)*D_H + c4));
    }
    __syncthreads();
    for (int k = 0; k < 64; ++k){
      float4 wv = ldf4(&W[k][cg*4]);
      int kk = hk*64 + k;
      #pragma unroll
      for (int rs = 0; rs < 8; ++rs){
        float xv = xr[rs*8 + rg][kk];
        acc[rs].x = fmaf(xv, wv.x, acc[rs].x);
        acc[rs].y = fmaf(xv, wv.y, acc[rs].y);
        acc[rs].z = fmaf(xv, wv.z, acc[rs].z);
        acc[rs].w = fmaf(xv, wv.w, acc[rs].w);
      }
    }
  }

  float4 b2v = ldf4(cw + CO_B2  + cg*4);
  float4 wlo = ldf4(cw + CO_WFC + cg*4);
  float4 whi = ldf4(cw + CO_WFC + D_H + cg*4);
  #pragma unroll
  for (int rs = 0; rs < 8; ++rs){
    int rr = base + rs*8 + rg;
    float o0 = gelu_f(acc[rs].x + b2v.x);
    float o1 = gelu_f(acc[rs].y + b2v.y);
    float o2 = gelu_f(acc[rs].z + b2v.z);
    float o3 = gelu_f(acc[rs].w + b2v.w);
    float pl = o0*wlo.x + o1*wlo.y + o2*wlo.z + o3*wlo.w;
    float ph = o0*whi.x + o1*whi.y + o2*whi.z + o3*whi.w;
    #pragma unroll
    for (int off=16; off; off>>=1){ pl += __shfl_xor(pl,off,64); ph += __shfl_xor(ph,off,64); }
    if (cg == 0 && rr < N_NODES){ p_lo[rr] = pl; p_hi[rr] = ph; }
  }
}

// Path b fallback: hbuf = hbuf @ W2 in place per 64-row block.
__global__ __launch_bounds__(256) void k_matmul2(float* __restrict__ hbuf, const float* __restrict__ cw){
  const float* W2 = cw + CO_W2;
  __shared__ float xr[16][D_H];
  int tid = threadIdx.x;
  int col = tid & 127, half = tid >> 7;
  int base = blockIdx.x * 64;
  for (int t0=0; t0<64; t0+=16){
    int r0 = base + t0;
    for (int i=tid; i<16*D_H; i+=256){
      int rr = r0 + (i>>7);
      xr[i>>7][i&127] = (rr < N_NODES) ? hbuf[(size_t)rr*D_H + (i&127)] : 0.f;
    }
    __syncthreads();
    float acc[8];
    #pragma unroll
    for (int r=0;r<8;++r) acc[r] = 0.f;
    int rb = half*8;
    for (int k=0;k<D_H;++k){
      float wv = W2[k*D_H + col];
      #pragma unroll
      for (int r=0;r<8;++r) acc[r] = fmaf(xr[rb+r][k], wv, acc[r]);
    }
    #pragma unroll
    for (int r=0;r<8;++r){
      int rr = r0 + rb + r;
      if (rr < N_NODES) hbuf[(size_t)rr*D_H + col] = acc[r];
    }
    __syncthreads();
  }
}

// 4 edges per thread, vectorized int4 reads of src/dst.
__global__ void k_final(const int* __restrict__ src, const int* __restrict__ dst,
    const float* __restrict__ p_lo, const float* __restrict__ p_hi,
    const float* __restrict__ cw, const int* __restrict__ flag, void* __restrict__ out){
  int q = blockIdx.x*blockDim.x + threadIdx.x;
  int e0 = q*4;
  if (e0 >= N_EDGES) return;
  float bfc = cw[CO_BFC];
  if (e0 + 4 <= N_EDGES){
    int4 s4 = *reinterpret_cast<const int4*>(src + e0);
    int4 d4 = *reinterpret_cast<const int4*>(dst + e0);
    float4 v;
    v.x = gelu_f(p_lo[s4.x] + p_hi[d4.x] + bfc);
    v.y = gelu_f(p_lo[s4.y] + p_hi[d4.y] + bfc);
    v.z = gelu_f(p_lo[s4.z] + p_hi[d4.z] + bfc);
    v.w = gelu_f(p_lo[s4.w] + p_hi[d4.w] + bfc);
    if (*flag){
      __hip_bfloat16* o = (__hip_bfloat16*)out + e0;
      o[0]=__float2bfloat16(v.x); o[1]=__float2bfloat16(v.y);
      o[2]=__float2bfloat16(v.z); o[3]=__float2bfloat16(v.w);
    } else {
      stf4((float*)out + e0, v);
    }
  } else {
    for (int e = e0; e < N_EDGES; ++e){
      float v = gelu_f(p_lo[src[e]] + p_hi[dst[e]] + bfc);
      if (*flag) ((__hip_bfloat16*)out)[e] = __float2bfloat16(v);
      else       ((float*)out)[e] = v;
    }
  }
}

extern "C" void kernel_launch(void* const* d_in, const int* in_sizes, int n_in,
                              void* d_out, int out_size, void* d_ws, size_t ws_size,
                              hipStream_t stream){
  (void)in_sizes; (void)n_in; (void)out_size;
  const int* x  = (const int*)d_in[0];
  const int* ei = (const int*)d_in[1];
  const int* src = ei;
  const int* dst = ei + N_EDGES;

  // ---- workspace layout ----
  char* base = (char*)d_ws;
  size_t off = 0;
  auto A = [&](size_t bytes)->size_t{ size_t r = off; off = (off + bytes + 255) & ~(size_t)255; return r; };
  size_t o_flag   = A(4);
  size_t o_cw     = A((size_t)CO_TOTAL*4);
  size_t o_va2    = A(D_H*4);
  size_t o_vd2    = A(D_H*4);
  size_t o_table1 = A((size_t)VOCAB*D_H*4);
  size_t o_as1    = A(VOCAB*4);
  size_t o_ad1    = A(VOCAB*4);
  size_t o_g1     = A((size_t)N_NODES*8);    // packed (sA1, rowbase)
  size_t o_dA1    = A((size_t)N_NODES*4);
  size_t o_sA2    = A((size_t)N_NODES*4);
  size_t o_dA2    = A((size_t)N_NODES*4);
  size_t o_rowoff = A((size_t)N_NODES*4);
  size_t o_rowcnt = A((size_t)N_NODES*4);
  size_t o_plo    = A((size_t)N_NODES*4);
  size_t o_phi    = A((size_t)N_NODES*4);
  size_t o_gcur   = A((size_t)NB*4);
  size_t o_cbase  = A((size_t)NB*4);
  size_t o_csr    = A((size_t)N_ESL*4);
  size_t o_big    = A((size_t)N_NODES*D_H*4);   // ebuf (9.6MB) then hbuf (51.2MB)
  size_t need_b   = off;
  size_t o_agg2   = A((size_t)N_NODES*D_H*4);
  size_t need_a   = off;

  int*    flag   = (int*)(base + o_flag);
  float*  cw     = (float*)(base + o_cw);
  float*  va2    = (float*)(base + o_va2);
  float*  vd2    = (float*)(base + o_vd2);
  float*  table1 = (float*)(base + o_table1);
  float*  as1    = (float*)(base + o_as1);
  float*  ad1    = (float*)(base + o_ad1);
  float2* g1     = (float2*)(base + o_g1);
  float*  dA1    = (float*)(base + o_dA1);
  float*  sA2    = (float*)(base + o_sA2);
  float*  dA2    = (float*)(base + o_dA2);
  int*    rowoff = (int*)(base + o_rowoff);
  int*    rowcnt = (int*)(base + o_rowcnt);
  float*  plo    = (float*)(base + o_plo);
  float*  phi    = (float*)(base + o_phi);
  int*    gcur   = (int*)(base + o_gcur);
  int*    cbase  = (int*)(base + o_cbase);
  int*    csr    = (int*)(base + o_csr);
  float*  hbuf   = (float*)(base + o_big);
  unsigned* ebuf = (unsigned*)(base + o_big);   // dead before hbuf is written
  float*  agg2   = (float*)(base + o_agg2);

  if (ws_size < need_b) return;         // signature: out stays 0
  bool patha = (ws_size >= need_a);

  k_detect<<<1, 64, 0, stream>>>((const unsigned*)d_in[2], flag, gcur);
  k_setup<<<352, 256, 0, stream>>>(d_in[2], d_in[3], d_in[4], d_in[5],
      d_in[6], d_in[7], d_in[8], d_in[9], d_in[10], d_in[11], d_in[12], flag, cw, va2, vd2);
  k_table1<<<VOCAB, 64, 0, stream>>>(cw, table1, as1, ad1);
  k_nodelog<<<(N_NODES+255)/256, 256, 0, stream>>>(x, as1, ad1, g1, dA1);

  // bucketed CSR build
  k_bin<<<(N_ESL+CHUNK-1)/CHUNK, 256, 0, stream>>>(src, dst, gcur, ebuf);
  k_bscan<<<1, 1024, 0, stream>>>(gcur, cbase);
  k_group<<<NB, 256, 0, stream>>>(ebuf, gcur, cbase, csr, rowoff, rowcnt);

  // layer 1 (2-node/wave, 8-deep MLP): h1g -> hbuf, plus plain sA2/dA2
  k_agg2n<0><<<N_NODES/8, 256, 0, stream>>>(rowoff, rowcnt, csr, g1, nullptr, dA1,
      table1, cw, va2, vd2, hbuf, sA2, dA2);
  if (patha){
    // layer 2 (1-node/wave, measured-best at the BW floor)
    k_agg1n<<<(N_NODES+3)/4, 256, 0, stream>>>(rowoff, rowcnt, csr, sA2, dA2, hbuf, agg2);
    k_post<<<(N_NODES+63)/64, 256, 0, stream>>>(agg2, cw, plo, phi);
  } else {
    k_matmul2<<<(N_NODES+63)/64, 256, 0, stream>>>(hbuf, cw);
    k_agg2n<2><<<N_NODES/8, 256, 0, stream>>>(rowoff, rowcnt, csr, nullptr, sA2, dA2,
        hbuf, cw, va2, vd2, nullptr, plo, phi);
  }
  k_final<<<(N_EDGES/4+255)/256, 256, 0, stream>>>(src, dst, plo, phi, cw, flag, d_out);
}